// Round 1
// baseline (690.020 us; speedup 1.0000x reference)
//
#include <hip/hip_runtime.h>
#include <hip/hip_bf16.h>

// Problem constants (B=2, L=2048, D=1024, NH=16, HD=64, H_GATE=256)
constexpr int Bn  = 2;
constexpr int Ln  = 2048;
constexpr int Dn  = 1024;
constexpr int NH  = 16;
constexpr int HGn = 256;
constexpr long BLD = (long)Bn * Ln * Dn;   // 4194304
constexpr long BLL = (long)Bn * Ln * Ln;   // 8388608

typedef float f32x4 __attribute__((ext_vector_type(4)));
typedef float f32x2 __attribute__((ext_vector_type(2)));
typedef short s16x8 __attribute__((ext_vector_type(8)));
typedef short s16x4 __attribute__((ext_vector_type(4)));
typedef short s16x2 __attribute__((ext_vector_type(2)));

#define DEVI static __device__ __forceinline__

DEVI float bf2f(short u) {
  union { float f; unsigned int i; } v; v.i = ((unsigned int)(unsigned short)u) << 16; return v.f;
}
DEVI short f2bf(float f) {
  union { float f; unsigned int i; } v; v.f = f;
  unsigned int r = v.i + 0x7FFFu + ((v.i >> 16) & 1u);
  return (short)(r >> 16);
}
DEVI void gl_lds16(const void* g, void* l) {
  __builtin_amdgcn_global_load_lds((const __attribute__((address_space(1))) unsigned int*)g,
                                   (__attribute__((address_space(3))) unsigned int*)l, 16, 0, 0);
}

// ---------------- cast f32 -> bf16 ----------------
__global__ void k_cast(const float* __restrict__ s, short* __restrict__ d, int n) {
  int i = (blockIdx.x * 256 + threadIdx.x) * 4;
  if (i >= n) return;
  f32x4 v = *(const f32x4*)(s + i);
  s16x4 o; o[0] = f2bf(v[0]); o[1] = f2bf(v[1]); o[2] = f2bf(v[2]); o[3] = f2bf(v[3]);
  *(s16x4*)(d + i) = o;
}

// ---------------- GEMM: C[m,n] = act(alpha * sum_k A[m,k]*B[n,k] + bias[n]) ----------------
// A: (M,K) bf16 row-major, B: (N,K) bf16 row-major. 128x128 tile, BK=32, 4 waves.
template<bool HAS_BIAS, bool GELU, bool OUT_BF16, bool CAUSAL, bool SCALE>
__global__ __launch_bounds__(256)
void k_gemm(const short* __restrict__ A, const short* __restrict__ B,
            const float* __restrict__ bias, const float* __restrict__ gamma,
            void* __restrict__ C, int N, int K, long sA, long sB, long sC) {
  int bz = blockIdx.z;
  const short* Ap = A + (long)bz * sA;
  const short* Bp = B + (long)bz * sB;
  int m0 = blockIdx.y * 128, n0 = blockIdx.x * 128;
  if (CAUSAL && n0 > m0 + 127) return;   // whole tile above diagonal: never read
  __shared__ short smA[128 * 32];
  __shared__ short smB[128 * 32];
  int tid = threadIdx.x;
  int lane = tid & 63, wid = tid >> 6;
  int wr = wid >> 1, wc = wid & 1;
  int lr = lane & 15, lg = lane >> 4;
  int r_in = lane >> 2, c_in = (lane & 3) * 8;
  f32x4 acc[4][4] = {};
  for (int k0 = 0; k0 < K; k0 += 32) {
#pragma unroll
    for (int i = 0; i < 2; ++i) {
      int row = wid * 32 + i * 16 + r_in;
      gl_lds16(Ap + (long)(m0 + row) * K + k0 + c_in, smA + row * 32 + c_in);
      gl_lds16(Bp + (long)(n0 + row) * K + k0 + c_in, smB + row * 32 + c_in);
    }
    __syncthreads();
    s16x8 af[4], bf[4];
#pragma unroll
    for (int m = 0; m < 4; m++) af[m] = *(const s16x8*)(smA + (wr * 64 + m * 16 + lr) * 32 + lg * 8);
#pragma unroll
    for (int n = 0; n < 4; n++) bf[n] = *(const s16x8*)(smB + (wc * 64 + n * 16 + lr) * 32 + lg * 8);
#pragma unroll
    for (int m = 0; m < 4; m++)
#pragma unroll
      for (int n = 0; n < 4; n++)
        acc[m][n] = __builtin_amdgcn_mfma_f32_16x16x32_bf16(af[m], bf[n], acc[m][n], 0, 0, 0);
    __syncthreads();
  }
  float alpha = 1.0f;
  if (SCALE) alpha = tanhf(gamma[0]) * 0.03125f;   // tanh(gamma) * d^-0.5
#pragma unroll
  for (int n = 0; n < 4; n++) {
    int col = n0 + wc * 64 + n * 16 + lr;
    float bv = HAS_BIAS ? bias[col] : 0.0f;
#pragma unroll
    for (int m = 0; m < 4; m++) {
#pragma unroll
      for (int r = 0; r < 4; r++) {
        long row = m0 + wr * 64 + m * 16 + lg * 4 + r;
        float v = acc[m][n][r] * alpha + bv;
        if (GELU) v = 0.5f * v * (1.0f + erff(v * 0.70710678118f));
        long off = (long)bz * sC + row * (long)N + col;
        if (OUT_BF16) ((short*)C)[off] = f2bf(v);
        else          ((float*)C)[off] = v;
      }
    }
  }
}

// ---------------- RoPE cos/sin tables: [L][512] for both bases ----------------
__global__ void k_rope_tables(float* __restrict__ ctf, float* __restrict__ stf,
                              float* __restrict__ cts, float* __restrict__ sts) {
  int idx = blockIdx.x * 256 + threadIdx.x;   // L*512 total
  int l = idx >> 9, j = idx & 511;
  float e = (float)j * (1.0f / 512.0f);
  float invf = powf(1.6180339887498949f, -e);
  float invs = powf(1618.0f, -e);
  float af = (float)l * invf, as = (float)l * invs;
  float sf, cf, ss, cs;
  sincosf(af, &sf, &cf);
  sincosf(as, &ss, &cs);
  ctf[idx] = cf; stf[idx] = sf; cts[idx] = cs; sts[idx] = ss;
}

// ---------------- gate = sigmoid(h . Wg2 + bg2), one wave per row ----------------
__global__ void k_gate(const float* __restrict__ Hf, const float* __restrict__ Wg2,
                       const float* __restrict__ bg2, float* __restrict__ gate) {
  int lane = threadIdx.x & 63, wid = threadIdx.x >> 6;
  int row = blockIdx.x * 4 + wid;
  f32x4 h = *(const f32x4*)(Hf + (long)row * HGn + lane * 4);
  f32x4 w = *(const f32x4*)(Wg2 + lane * 4);
  float s = h[0] * w[0] + h[1] * w[1] + h[2] * w[2] + h[3] * w[3];
#pragma unroll
  for (int m = 1; m < 64; m <<= 1) s += __shfl_xor(s, m);
  if (lane == 0) gate[row] = 1.0f / (1.0f + __expf(-(s + bg2[0])));
}

// ---------------- RoPE apply (in place, Q and K), one block per (b,l) ----------------
__global__ void k_rope(short* __restrict__ Q, short* __restrict__ Kx,
                       const float* __restrict__ gate,
                       const float* __restrict__ ctf, const float* __restrict__ stf,
                       const float* __restrict__ cts, const float* __restrict__ sts) {
  int bl = blockIdx.x;
  int l = bl & (Ln - 1);
  int t = threadIdx.x;
  float g = gate[bl];
  int j = t * 2;
  f32x2 vcf = *(const f32x2*)(ctf + l * 512 + j);
  f32x2 vsf = *(const f32x2*)(stf + l * 512 + j);
  f32x2 vcs = *(const f32x2*)(cts + l * 512 + j);
  f32x2 vss = *(const f32x2*)(sts + l * 512 + j);
  float c0 = g * vcf[0] + (1.f - g) * vcs[0];
  float c1 = g * vcf[1] + (1.f - g) * vcs[1];
  float s0 = g * vsf[0] + (1.f - g) * vss[0];
  float s1 = g * vsf[1] + (1.f - g) * vss[1];
  long base = (long)bl * Dn + j;
  {
    s16x2 xa = *(const s16x2*)(Q + base);
    s16x2 xb = *(const s16x2*)(Q + base + 512);
    float a0 = bf2f(xa[0]), a1 = bf2f(xa[1]), b0 = bf2f(xb[0]), b1 = bf2f(xb[1]);
    s16x2 o0, o1;
    o0[0] = f2bf(a0 * c0 - b0 * s0); o0[1] = f2bf(a1 * c1 - b1 * s1);
    o1[0] = f2bf(b0 * c0 + a0 * s0); o1[1] = f2bf(b1 * c1 + a1 * s1);
    *(s16x2*)(Q + base) = o0;
    *(s16x2*)(Q + base + 512) = o1;
  }
  {
    s16x2 xa = *(const s16x2*)(Kx + base);
    s16x2 xb = *(const s16x2*)(Kx + base + 512);
    float a0 = bf2f(xa[0]), a1 = bf2f(xa[1]), b0 = bf2f(xb[0]), b1 = bf2f(xb[1]);
    s16x2 o0, o1;
    o0[0] = f2bf(a0 * c0 - b0 * s0); o0[1] = f2bf(a1 * c1 - b1 * s1);
    o1[0] = f2bf(b0 * c0 + a0 * s0); o1[1] = f2bf(b1 * c1 + a1 * s1);
    *(s16x2*)(Kx + base) = o0;
    *(s16x2*)(Kx + base + 512) = o1;
  }
}

// ---------------- zero the strict upper triangle of attn_w ----------------
__global__ void k_fill_upper(float* __restrict__ aw) {
  int q = blockIdx.x, b = blockIdx.y;
  float* row = aw + ((long)b * Ln + q) * Ln;
  for (int k = q + 1 + threadIdx.x; k < Ln; k += 256) row[k] = 0.0f;
}

// ---------------- attention pass 1: out + 1/Z. one wave per (b,h,16 q-rows) ----------------
__global__ __launch_bounds__(64)
void k_attn1(const short* __restrict__ Q, const short* __restrict__ Kx,
             const short* __restrict__ V, const float* __restrict__ gb,
             float* __restrict__ outp, float* __restrict__ zinv) {
  int qt = blockIdx.x, h = blockIdx.y, b = blockIdx.z;
  int lane = threadIdx.x;
  int lr = lane & 15, lg = lane >> 4;
  int q0 = qt * 16;
  __shared__ short smP[16 * 32];
  __shared__ short smV[32 * 64];
  const short* qb = Q + ((long)(b * Ln) + q0 + lr) * Dn + h * 64 + lg * 8;
  s16x8 qf0 = *(const s16x8*)(qb);
  s16x8 qf1 = *(const s16x8*)(qb + 32);
  f32x4 acc[4] = {};
  float az[4] = {0.f, 0.f, 0.f, 0.f};
  for (int k0 = 0; k0 <= q0 + 15; k0 += 32) {
    // stage V rows [k0,k0+32) for this head into LDS (zero rows past L)
#pragma unroll
    for (int it = 0; it < 4; ++it) {
      int r = it * 8 + (lane >> 3);
      int c = (lane & 7) * 8;
      int kr = k0 + r;
      s16x8 v = {};
      if (kr < Ln) v = *(const s16x8*)(V + ((long)(b * Ln) + kr) * Dn + h * 64 + c);
      *(s16x8*)(smV + r * 64 + c) = v;
    }
#pragma unroll
    for (int kk = 0; kk < 2; ++kk) {
      int kc = k0 + kk * 16;
      int kidx = kc + lr; if (kidx > Ln - 1) kidx = Ln - 1;   // clamp (masked anyway)
      const short* kb = Kx + ((long)(b * Ln) + kidx) * Dn + h * 64 + lg * 8;
      s16x8 kf0 = *(const s16x8*)(kb);
      s16x8 kf1 = *(const s16x8*)(kb + 32);
      f32x4 S = {};
      S = __builtin_amdgcn_mfma_f32_16x16x32_bf16(qf0, kf0, S, 0, 0, 0);
      S = __builtin_amdgcn_mfma_f32_16x16x32_bf16(qf1, kf1, S, 0, 0, 0);
#pragma unroll
      for (int r = 0; r < 4; r++) {
        int q = q0 + lg * 4 + r;
        int k = kc + lr;
        float p = 0.0f;
        if (k <= q) {
          float gv = gb[((long)b * Ln + q) * Ln + k];
          p = __expf(S[r] * 0.125f + gv);   // logits bounded ~|4|: no max needed
        }
        az[r] += p;
        smP[(lg * 4 + r) * 32 + kk * 16 + lr] = f2bf(p);
      }
    }
    __syncthreads();
    s16x8 pf = *(const s16x8*)(smP + lr * 32 + lg * 8);
#pragma unroll
    for (int n = 0; n < 4; n++) {
      s16x8 vf;
#pragma unroll
      for (int e = 0; e < 8; e++) vf[e] = smV[(lg * 8 + e) * 64 + n * 16 + lr];
      acc[n] = __builtin_amdgcn_mfma_f32_16x16x32_bf16(pf, vf, acc[n], 0, 0, 0);
    }
    __syncthreads();
  }
#pragma unroll
  for (int r = 0; r < 4; r++) {
    float z = az[r];
    z += __shfl_xor(z, 1); z += __shfl_xor(z, 2); z += __shfl_xor(z, 4); z += __shfl_xor(z, 8);
    az[r] = 1.0f / z;
  }
  if (lr == 0) {
#pragma unroll
    for (int r = 0; r < 4; r++)
      zinv[((long)(b * NH + h)) * Ln + q0 + lg * 4 + r] = az[r];
  }
#pragma unroll
  for (int n = 0; n < 4; n++) {
#pragma unroll
    for (int r = 0; r < 4; r++) {
      int q = q0 + lg * 4 + r;
      outp[((long)(b * Ln) + q) * Dn + h * 64 + n * 16 + lr] = acc[n][r] * az[r];
    }
  }
}

// ---------------- attention pass 2: attn_w = mean_h softmax. gb and aw alias! ----------------
__global__ __launch_bounds__(256)
void k_attn2(const short* __restrict__ Q, const short* __restrict__ Kx,
             const float* gb, const float* __restrict__ zinv, float* aw) {
  int qt = blockIdx.x, b = blockIdx.y;
  int tid = threadIdx.x, lane = tid & 63, wid = tid >> 6;
  int lr = lane & 15, lg = lane >> 4;
  int q0 = qt * 16;
  __shared__ float smZ[NH * 16];
  if (tid < NH * 16) {
    int h = tid >> 4, r = tid & 15;
    smZ[tid] = zinv[((long)(b * NH + h)) * Ln + q0 + r];
  }
  s16x8 qf[NH][2];
  const short* qb = Q + ((long)(b * Ln) + q0 + lr) * Dn + lg * 8;
#pragma unroll
  for (int h = 0; h < NH; ++h) {
    qf[h][0] = *(const s16x8*)(qb + h * 64);
    qf[h][1] = *(const s16x8*)(qb + h * 64 + 32);
  }
  __syncthreads();
  for (int kt = wid; kt <= qt; kt += 4) {
    int k = kt * 16 + lr;
    float gv[4];
    bool msk[4];
#pragma unroll
    for (int r = 0; r < 4; r++) {
      int q = q0 + lg * 4 + r;
      msk[r] = (k <= q);
      gv[r] = gb[((long)b * Ln + q) * Ln + k];   // upper part is zero-filled, safe to read
    }
    f32x4 wa = {};
#pragma unroll
    for (int h = 0; h < NH; ++h) {
      const short* kb = Kx + ((long)(b * Ln) + k) * Dn + h * 64 + lg * 8;
      s16x8 kf0 = *(const s16x8*)(kb);
      s16x8 kf1 = *(const s16x8*)(kb + 32);
      f32x4 S = {};
      S = __builtin_amdgcn_mfma_f32_16x16x32_bf16(qf[h][0], kf0, S, 0, 0, 0);
      S = __builtin_amdgcn_mfma_f32_16x16x32_bf16(qf[h][1], kf1, S, 0, 0, 0);
#pragma unroll
      for (int r = 0; r < 4; r++)
        wa[r] += __expf(S[r] * 0.125f + gv[r]) * smZ[h * 16 + lg * 4 + r];
    }
#pragma unroll
    for (int r = 0; r < 4; r++) {
      int q = q0 + lg * 4 + r;
      aw[((long)b * Ln + q) * Ln + k] = msk[r] ? wa[r] * (1.0f / 16.0f) : 0.0f;
    }
  }
}

extern "C" void kernel_launch(void* const* d_in, const int* in_sizes, int n_in,
                              void* d_out, int out_size, void* d_ws, size_t ws_size,
                              hipStream_t stream) {
  const float* z    = (const float*)d_in[0];
  const float* ps   = (const float*)d_in[1];
  const float* Wq   = (const float*)d_in[2];
  const float* bq   = (const float*)d_in[3];
  const float* Wk   = (const float*)d_in[4];
  const float* bk   = (const float*)d_in[5];
  const float* Wv   = (const float*)d_in[6];
  const float* bv   = (const float*)d_in[7];
  const float* Wc   = (const float*)d_in[8];
  const float* gamma= (const float*)d_in[9];
  const float* Wg1  = (const float*)d_in[10];
  const float* bg1  = (const float*)d_in[11];
  const float* Wg2  = (const float*)d_in[12];
  const float* bg2  = (const float*)d_in[13];

  char* w = (char*)d_ws;
  auto alloc = [&](long bytes) { void* p = (void*)w; w += (bytes + 255) & ~255L; return p; };
  short* zb   = (short*)alloc(BLD * 2);
  short* pb   = (short*)alloc(BLD * 2);
  short* Wqb  = (short*)alloc((long)Dn * Dn * 2);
  short* Wkb  = (short*)alloc((long)Dn * Dn * 2);
  short* Wvb  = (short*)alloc((long)Dn * Dn * 2);
  short* Wcb  = (short*)alloc((long)Dn * Dn * 2);
  short* Wg1b = (short*)alloc((long)HGn * Dn * 2);
  short* Qp   = (short*)alloc(BLD * 2);
  short* Kp   = (short*)alloc(BLD * 2);
  short* Vp   = (short*)alloc(BLD * 2);
  short* Gk   = (short*)alloc(BLD * 2);
  float* Hf   = (float*)alloc((long)Bn * Ln * HGn * 4);
  float* gate = (float*)alloc((long)Bn * Ln * 4);
  float* ctf  = (float*)alloc((long)Ln * 512 * 4);
  float* stf  = (float*)alloc((long)Ln * 512 * 4);
  float* cts  = (float*)alloc((long)Ln * 512 * 4);
  float* sts  = (float*)alloc((long)Ln * 512 * 4);
  float* zv   = (float*)alloc((long)Bn * NH * Ln * 4);
  // total ws: ~80.5 MB

  float* outp = (float*)d_out;
  float* aw   = outp + BLD;   // attn_w region; doubles as gb scratch before pass 2

  // 1) casts to bf16
  k_cast<<<(int)(BLD / 4 / 256), 256, 0, stream>>>(z,  zb, (int)BLD);
  k_cast<<<(int)(BLD / 4 / 256), 256, 0, stream>>>(ps, pb, (int)BLD);
  k_cast<<<Dn * Dn / 4 / 256, 256, 0, stream>>>(Wq, Wqb, Dn * Dn);
  k_cast<<<Dn * Dn / 4 / 256, 256, 0, stream>>>(Wk, Wkb, Dn * Dn);
  k_cast<<<Dn * Dn / 4 / 256, 256, 0, stream>>>(Wv, Wvb, Dn * Dn);
  k_cast<<<Dn * Dn / 4 / 256, 256, 0, stream>>>(Wc, Wcb, Dn * Dn);
  k_cast<<<HGn * Dn / 4 / 256, 256, 0, stream>>>(Wg1, Wg1b, HGn * Dn);

  // 2) projections (M=4096): Q,K,V (bias), gk (no bias), h (bias+gelu, N=256)
  dim3 pg(Dn / 128, (Bn * Ln) / 128, 1);
  k_gemm<true,  false, true,  false, false><<<pg, 256, 0, stream>>>(zb, Wqb, bq, nullptr, Qp, Dn, Dn, 0, 0, 0);
  k_gemm<true,  false, true,  false, false><<<pg, 256, 0, stream>>>(zb, Wkb, bk, nullptr, Kp, Dn, Dn, 0, 0, 0);
  k_gemm<true,  false, true,  false, false><<<pg, 256, 0, stream>>>(zb, Wvb, bv, nullptr, Vp, Dn, Dn, 0, 0, 0);
  k_gemm<false, false, true,  false, false><<<pg, 256, 0, stream>>>(pb, Wcb, nullptr, nullptr, Gk, Dn, Dn, 0, 0, 0);
  dim3 hg(HGn / 128, (Bn * Ln) / 128, 1);
  k_gemm<true,  true,  false, false, false><<<hg, 256, 0, stream>>>(pb, Wg1b, bg1, nullptr, Hf, HGn, Dn, 0, 0, 0);

  // 3) gb = tanh(gamma)/32 * gk . K_raw^T  (written into attn_w region, causal blocks only)
  dim3 gbg(Ln / 128, Ln / 128, Bn);
  k_gemm<false, false, false, true,  true ><<<gbg, 256, 0, stream>>>(Gk, Kp, nullptr, gamma, aw, Ln, Dn,
                                                                     (long)Ln * Dn, (long)Ln * Dn, (long)Ln * Ln);

  // 4) RoPE tables, gate, in-place rotation of Q/K (K raw already consumed by gb)
  k_rope_tables<<<(Ln * 512) / 256, 256, 0, stream>>>(ctf, stf, cts, sts);
  k_gate<<<(Bn * Ln) / 4, 256, 0, stream>>>(Hf, Wg2, bg2, gate);
  k_rope<<<Bn * Ln, 256, 0, stream>>>(Qp, Kp, gate, ctf, stf, cts, sts);

  // 5) attention
  k_fill_upper<<<dim3(Ln, Bn), 256, 0, stream>>>(aw);
  k_attn1<<<dim3(Ln / 16, NH, Bn), 64, 0, stream>>>(Qp, Kp, Vp, aw, outp, zv);
  k_attn2<<<dim3(Ln / 16, Bn), 256, 0, stream>>>(Qp, Kp, aw, zv, aw);
}

// Round 2
// 549.622 us; speedup vs baseline: 1.2554x; 1.2554x over previous
//
#include <hip/hip_runtime.h>
#include <hip/hip_bf16.h>

// Problem constants (B=2, L=2048, D=1024, NH=16, HD=64, H_GATE=256)
constexpr int Bn  = 2;
constexpr int Ln  = 2048;
constexpr int Dn  = 1024;
constexpr int NH  = 16;
constexpr int HGn = 256;
constexpr long BLD = (long)Bn * Ln * Dn;   // 4194304

typedef float f32x4 __attribute__((ext_vector_type(4)));
typedef float f32x2 __attribute__((ext_vector_type(2)));
typedef short s16x8 __attribute__((ext_vector_type(8)));
typedef short s16x4 __attribute__((ext_vector_type(4)));
typedef short s16x2 __attribute__((ext_vector_type(2)));

#define DEVI static __device__ __forceinline__

DEVI float bf2f(short u) {
  union { float f; unsigned int i; } v; v.i = ((unsigned int)(unsigned short)u) << 16; return v.f;
}
DEVI short f2bf(float f) {
  union { float f; unsigned int i; } v; v.f = f;
  unsigned int r = v.i + 0x7FFFu + ((v.i >> 16) & 1u);
  return (short)(r >> 16);
}
DEVI void gl_lds16(const void* g, void* l) {
  __builtin_amdgcn_global_load_lds((const __attribute__((address_space(1))) unsigned int*)g,
                                   (__attribute__((address_space(3))) unsigned int*)l, 16, 0, 0);
}

// ---------------- cast f32 -> bf16 ----------------
__global__ void k_cast(const float* __restrict__ s, short* __restrict__ d, int n) {
  int i = (blockIdx.x * 256 + threadIdx.x) * 4;
  if (i >= n) return;
  f32x4 v = *(const f32x4*)(s + i);
  s16x4 o; o[0] = f2bf(v[0]); o[1] = f2bf(v[1]); o[2] = f2bf(v[2]); o[3] = f2bf(v[3]);
  *(s16x4*)(d + i) = o;
}

// ---------------- GEMM: C[m,n] = act(alpha * sum_k A[m,k]*B[n,k] + bias[n]) ----------------
// A: (M,K) bf16 row-major, B: (N,K) bf16 row-major. 128x128 tile, BK=32, 4 waves.
// OUT_VT: write bf16 transposed as Vt[((b*NH+h)*64+dh)*Ln + l]  (row=b*Ln+l, col=h*64+dh)
template<bool HAS_BIAS, bool GELU, bool OUT_BF16, bool CAUSAL, bool SCALE, bool OUT_VT>
__global__ __launch_bounds__(256)
void k_gemm(const short* __restrict__ A, const short* __restrict__ B,
            const float* __restrict__ bias, const float* __restrict__ gamma,
            void* __restrict__ C, int N, int K, long sA, long sB, long sC) {
  int bz = blockIdx.z;
  const short* Ap = A + (long)bz * sA;
  const short* Bp = B + (long)bz * sB;
  int m0 = blockIdx.y * 128, n0 = blockIdx.x * 128;
  if (CAUSAL && n0 > m0 + 127) return;   // whole tile above diagonal: never read
  __shared__ short smA[128 * 32];
  __shared__ short smB[128 * 32];
  int tid = threadIdx.x;
  int lane = tid & 63, wid = tid >> 6;
  int wr = wid >> 1, wc = wid & 1;
  int lr = lane & 15, lg = lane >> 4;
  int r_in = lane >> 2, c_in = (lane & 3) * 8;
  f32x4 acc[4][4] = {};
  for (int k0 = 0; k0 < K; k0 += 32) {
#pragma unroll
    for (int i = 0; i < 2; ++i) {
      int row = wid * 32 + i * 16 + r_in;
      gl_lds16(Ap + (long)(m0 + row) * K + k0 + c_in, smA + row * 32 + c_in);
      gl_lds16(Bp + (long)(n0 + row) * K + k0 + c_in, smB + row * 32 + c_in);
    }
    __syncthreads();
    s16x8 af[4], bf[4];
#pragma unroll
    for (int m = 0; m < 4; m++) af[m] = *(const s16x8*)(smA + (wr * 64 + m * 16 + lr) * 32 + lg * 8);
#pragma unroll
    for (int n = 0; n < 4; n++) bf[n] = *(const s16x8*)(smB + (wc * 64 + n * 16 + lr) * 32 + lg * 8);
#pragma unroll
    for (int m = 0; m < 4; m++)
#pragma unroll
      for (int n = 0; n < 4; n++)
        acc[m][n] = __builtin_amdgcn_mfma_f32_16x16x32_bf16(af[m], bf[n], acc[m][n], 0, 0, 0);
    __syncthreads();
  }
  float alpha = 1.0f;
  if (SCALE) alpha = tanhf(gamma[0]) * 0.03125f;   // tanh(gamma) * d^-0.5
#pragma unroll
  for (int n = 0; n < 4; n++) {
    int col = n0 + wc * 64 + n * 16 + lr;
    float bv = HAS_BIAS ? bias[col] : 0.0f;
#pragma unroll
    for (int m = 0; m < 4; m++) {
#pragma unroll
      for (int r = 0; r < 4; r++) {
        long row = m0 + wr * 64 + m * 16 + lg * 4 + r;
        float v = acc[m][n][r] * alpha + bv;
        if (GELU) v = 0.5f * v * (1.0f + erff(v * 0.70710678118f));
        if (OUT_VT) {
          long off = (((row >> 11) * (long)NH + (col >> 6)) * 64 + (col & 63)) * Ln + (row & (Ln - 1));
          ((short*)C)[off] = f2bf(v);
        } else {
          long off = (long)bz * sC + row * (long)N + col;
          if (OUT_BF16) ((short*)C)[off] = f2bf(v);
          else          ((float*)C)[off] = v;
        }
      }
    }
  }
}

// ---------------- RoPE cos/sin tables: [L][512] for both bases ----------------
__global__ void k_rope_tables(float* __restrict__ ctf, float* __restrict__ stf,
                              float* __restrict__ cts, float* __restrict__ sts) {
  int idx = blockIdx.x * 256 + threadIdx.x;   // L*512 total
  int l = idx >> 9, j = idx & 511;
  float e = (float)j * (1.0f / 512.0f);
  float invf = powf(1.6180339887498949f, -e);
  float invs = powf(1618.0f, -e);
  float af = (float)l * invf, as = (float)l * invs;
  float sf, cf, ss, cs;
  sincosf(af, &sf, &cf);
  sincosf(as, &ss, &cs);
  ctf[idx] = cf; stf[idx] = sf; cts[idx] = cs; sts[idx] = ss;
}

// ---------------- gate = sigmoid(h . Wg2 + bg2), one wave per row ----------------
__global__ void k_gate(const float* __restrict__ Hf, const float* __restrict__ Wg2,
                       const float* __restrict__ bg2, float* __restrict__ gate) {
  int lane = threadIdx.x & 63, wid = threadIdx.x >> 6;
  int row = blockIdx.x * 4 + wid;
  f32x4 h = *(const f32x4*)(Hf + (long)row * HGn + lane * 4);
  f32x4 w = *(const f32x4*)(Wg2 + lane * 4);
  float s = h[0] * w[0] + h[1] * w[1] + h[2] * w[2] + h[3] * w[3];
#pragma unroll
  for (int m = 1; m < 64; m <<= 1) s += __shfl_xor(s, m);
  if (lane == 0) gate[row] = 1.0f / (1.0f + __expf(-(s + bg2[0])));
}

// ---------------- RoPE apply (in place, Q and K), one block per (b,l) ----------------
__global__ void k_rope(short* __restrict__ Q, short* __restrict__ Kx,
                       const float* __restrict__ gate,
                       const float* __restrict__ ctf, const float* __restrict__ stf,
                       const float* __restrict__ cts, const float* __restrict__ sts) {
  int bl = blockIdx.x;
  int l = bl & (Ln - 1);
  int t = threadIdx.x;
  float g = gate[bl];
  int j = t * 2;
  f32x2 vcf = *(const f32x2*)(ctf + l * 512 + j);
  f32x2 vsf = *(const f32x2*)(stf + l * 512 + j);
  f32x2 vcs = *(const f32x2*)(cts + l * 512 + j);
  f32x2 vss = *(const f32x2*)(sts + l * 512 + j);
  float c0 = g * vcf[0] + (1.f - g) * vcs[0];
  float c1 = g * vcf[1] + (1.f - g) * vcs[1];
  float s0 = g * vsf[0] + (1.f - g) * vss[0];
  float s1 = g * vsf[1] + (1.f - g) * vss[1];
  long base = (long)bl * Dn + j;
  {
    s16x2 xa = *(const s16x2*)(Q + base);
    s16x2 xb = *(const s16x2*)(Q + base + 512);
    float a0 = bf2f(xa[0]), a1 = bf2f(xa[1]), b0 = bf2f(xb[0]), b1 = bf2f(xb[1]);
    s16x2 o0, o1;
    o0[0] = f2bf(a0 * c0 - b0 * s0); o0[1] = f2bf(a1 * c1 - b1 * s1);
    o1[0] = f2bf(b0 * c0 + a0 * s0); o1[1] = f2bf(b1 * c1 + a1 * s1);
    *(s16x2*)(Q + base) = o0;
    *(s16x2*)(Q + base + 512) = o1;
  }
  {
    s16x2 xa = *(const s16x2*)(Kx + base);
    s16x2 xb = *(const s16x2*)(Kx + base + 512);
    float a0 = bf2f(xa[0]), a1 = bf2f(xa[1]), b0 = bf2f(xb[0]), b1 = bf2f(xb[1]);
    s16x2 o0, o1;
    o0[0] = f2bf(a0 * c0 - b0 * s0); o0[1] = f2bf(a1 * c1 - b1 * s1);
    o1[0] = f2bf(b0 * c0 + a0 * s0); o1[1] = f2bf(b1 * c1 + a1 * s1);
    *(s16x2*)(Kx + base) = o0;
    *(s16x2*)(Kx + base + 512) = o1;
  }
}

// ---------------- zero the strict upper triangle of attn_w ----------------
__global__ void k_fill_upper(float* __restrict__ aw) {
  int q = blockIdx.x, b = blockIdx.y;
  float* row = aw + ((long)b * Ln + q) * Ln;
  for (int k = q + 1 + threadIdx.x; k < Ln; k += 256) row[k] = 0.0f;
}

// ---------------- attention pass 1: 4 waves, 64 q-rows, one (b,h) per block ----------------
// K staged [64k][64d], Vt staged [64d][64k]; both via global_load_lds with
// source-pre-swizzled XOR layout: LDS(row, slot16B) holds logical chunk (slot ^ (row&7)).
__global__ __launch_bounds__(256)
void k_attn1(const short* __restrict__ Q, const short* __restrict__ Kx,
             const short* __restrict__ Vt, const float* __restrict__ gb,
             float* __restrict__ outp, float* __restrict__ zinv) {
  int qb = blockIdx.x, h = blockIdx.y, b = blockIdx.z;
  int tid = threadIdx.x;
  int lane = tid & 63, w = tid >> 6;
  int lr = lane & 15, lg = lane >> 4;
  int q0w = qb * 64 + w * 16;
  __shared__ short smK[64 * 64];
  __shared__ short smV[64 * 64];
  __shared__ short smP[4 * 16 * 64];
  short* pw = smP + w * 1024;
  // Q frags (16 q rows per wave, d = h*64 .. +63)
  const short* qbp = Q + ((long)(b * Ln) + q0w + lr) * Dn + h * 64 + lg * 8;
  s16x8 qf0 = *(const s16x8*)(qbp);
  s16x8 qf1 = *(const s16x8*)(qbp + 32);
  f32x4 acc[4] = {};
  float az[4] = {0.f, 0.f, 0.f, 0.f};
  // staging geometry (per lane)
  int r0 = w * 16 + (lane >> 3);                 // t=0 row in tile (0..63)
  int scol = ((lane & 7) ^ (lane >> 3)) * 8;     // pre-swizzled source col (elems)
  const short* Kg = Kx + (long)(b * Ln) * Dn + h * 64;
  const short* Vg = Vt + (long)(b * NH + h) * 64 * Ln;
  short* ldsK0 = smK + (w * 2 + 0) * 512;
  short* ldsK1 = smK + (w * 2 + 1) * 512;
  short* ldsV0 = smV + (w * 2 + 0) * 512;
  short* ldsV1 = smV + (w * 2 + 1) * 512;
  int sw = (lr & 7) << 3;                        // read-side XOR (elems)

  for (int k0 = 0; k0 <= qb * 64; k0 += 64) {
    gl_lds16(Kg + (long)(k0 + r0)     * Dn + scol, ldsK0);
    gl_lds16(Kg + (long)(k0 + r0 + 8) * Dn + scol, ldsK1);
    gl_lds16(Vg + (long)(r0)     * Ln + k0 + scol, ldsV0);
    gl_lds16(Vg + (long)(r0 + 8) * Ln + k0 + scol, ldsV1);
    __syncthreads();
    // ---- QK^T + exp into smP ----
#pragma unroll
    for (int kk = 0; kk < 4; ++kk) {
      int row = kk * 16 + lr;
      const short* kr = smK + row * 64;
      s16x8 kf0 = *(const s16x8*)(kr + ((lg * 8) ^ sw));
      s16x8 kf1 = *(const s16x8*)(kr + ((32 + lg * 8) ^ sw));
      f32x4 S = {};
      S = __builtin_amdgcn_mfma_f32_16x16x32_bf16(qf0, kf0, S, 0, 0, 0);
      S = __builtin_amdgcn_mfma_f32_16x16x32_bf16(qf1, kf1, S, 0, 0, 0);
      int k = k0 + kk * 16 + lr;
      int kp = kk * 16 + lr;
      const float* gbp = gb + ((long)b * Ln + q0w + lg * 4) * Ln + k;
#pragma unroll
      for (int r = 0; r < 4; r++) {
        int q = q0w + lg * 4 + r;
        float gv = gbp[(long)r * Ln];
        float arg = (k <= q) ? (S[r] * 0.125f + gv) : -80.0f;
        float p = __expf(arg);
        az[r] += p;
        int qq = lg * 4 + r;
        pw[qq * 64 + (kp ^ ((qq & 7) << 3))] = f2bf(p);
      }
    }
    // ---- P @ V ----
#pragma unroll
    for (int c = 0; c < 2; ++c) {
      s16x8 pf = *(const s16x8*)(pw + lr * 64 + ((c * 32 + lg * 8) ^ sw));
#pragma unroll
      for (int n = 0; n < 4; n++) {
        int row = n * 16 + lr;
        s16x8 vf = *(const s16x8*)(smV + row * 64 + ((c * 32 + lg * 8) ^ sw));
        acc[n] = __builtin_amdgcn_mfma_f32_16x16x32_bf16(pf, vf, acc[n], 0, 0, 0);
      }
    }
    __syncthreads();
  }
#pragma unroll
  for (int r = 0; r < 4; r++) {
    float z = az[r];
    z += __shfl_xor(z, 1); z += __shfl_xor(z, 2); z += __shfl_xor(z, 4); z += __shfl_xor(z, 8);
    az[r] = 1.0f / z;
  }
  if (lr == 0) {
#pragma unroll
    for (int r = 0; r < 4; r++)
      zinv[((long)(b * NH + h)) * Ln + q0w + lg * 4 + r] = az[r];
  }
#pragma unroll
  for (int n = 0; n < 4; n++) {
#pragma unroll
    for (int r = 0; r < 4; r++) {
      int q = q0w + lg * 4 + r;
      outp[((long)(b * Ln) + q) * Dn + h * 64 + n * 16 + lr] = acc[n][r] * az[r];
    }
  }
}

// ---------------- attention pass 2: attn_w = mean_h softmax. gb and aw alias! ----------------
__global__ __launch_bounds__(256)
void k_attn2(const short* __restrict__ Q, const short* __restrict__ Kx,
             const float* gb, const float* __restrict__ zinv, float* aw) {
  int qt = blockIdx.x, b = blockIdx.y;
  int tid = threadIdx.x, lane = tid & 63, wid = tid >> 6;
  int lr = lane & 15, lg = lane >> 4;
  int q0 = qt * 16;
  __shared__ float smZ[NH * 16];
  if (tid < NH * 16) {
    int h = tid >> 4, r = tid & 15;
    smZ[tid] = zinv[((long)(b * NH + h)) * Ln + q0 + r];
  }
  s16x8 qf[NH][2];
  const short* qb = Q + ((long)(b * Ln) + q0 + lr) * Dn + lg * 8;
#pragma unroll
  for (int h = 0; h < NH; ++h) {
    qf[h][0] = *(const s16x8*)(qb + h * 64);
    qf[h][1] = *(const s16x8*)(qb + h * 64 + 32);
  }
  __syncthreads();
  for (int kt = wid; kt <= qt; kt += 4) {
    int k = kt * 16 + lr;
    float gv[4];
    bool msk[4];
#pragma unroll
    for (int r = 0; r < 4; r++) {
      int q = q0 + lg * 4 + r;
      msk[r] = (k <= q);
      gv[r] = gb[((long)b * Ln + q) * Ln + k];   // upper part is zero-filled, safe to read
    }
    f32x4 wa = {};
#pragma unroll
    for (int h = 0; h < NH; ++h) {
      const short* kb = Kx + ((long)(b * Ln) + k) * Dn + h * 64 + lg * 8;
      s16x8 kf0 = *(const s16x8*)(kb);
      s16x8 kf1 = *(const s16x8*)(kb + 32);
      f32x4 S = {};
      S = __builtin_amdgcn_mfma_f32_16x16x32_bf16(qf[h][0], kf0, S, 0, 0, 0);
      S = __builtin_amdgcn_mfma_f32_16x16x32_bf16(qf[h][1], kf1, S, 0, 0, 0);
#pragma unroll
      for (int r = 0; r < 4; r++)
        wa[r] += __expf(S[r] * 0.125f + gv[r]) * smZ[h * 16 + lg * 4 + r];
    }
#pragma unroll
    for (int r = 0; r < 4; r++) {
      int q = q0 + lg * 4 + r;
      aw[((long)b * Ln + q) * Ln + k] = msk[r] ? wa[r] * (1.0f / 16.0f) : 0.0f;
    }
  }
}

extern "C" void kernel_launch(void* const* d_in, const int* in_sizes, int n_in,
                              void* d_out, int out_size, void* d_ws, size_t ws_size,
                              hipStream_t stream) {
  const float* z    = (const float*)d_in[0];
  const float* ps   = (const float*)d_in[1];
  const float* Wq   = (const float*)d_in[2];
  const float* bq   = (const float*)d_in[3];
  const float* Wk   = (const float*)d_in[4];
  const float* bk   = (const float*)d_in[5];
  const float* Wv   = (const float*)d_in[6];
  const float* bv   = (const float*)d_in[7];
  const float* Wc   = (const float*)d_in[8];
  const float* gamma= (const float*)d_in[9];
  const float* Wg1  = (const float*)d_in[10];
  const float* bg1  = (const float*)d_in[11];
  const float* Wg2  = (const float*)d_in[12];
  const float* bg2  = (const float*)d_in[13];

  char* w = (char*)d_ws;
  auto alloc = [&](long bytes) { void* p = (void*)w; w += (bytes + 255) & ~255L; return p; };
  short* zb   = (short*)alloc(BLD * 2);
  short* pb   = (short*)alloc(BLD * 2);
  short* Wqb  = (short*)alloc((long)Dn * Dn * 2);
  short* Wkb  = (short*)alloc((long)Dn * Dn * 2);
  short* Wvb  = (short*)alloc((long)Dn * Dn * 2);
  short* Wcb  = (short*)alloc((long)Dn * Dn * 2);
  short* Wg1b = (short*)alloc((long)HGn * Dn * 2);
  short* Qp   = (short*)alloc(BLD * 2);
  short* Kp   = (short*)alloc(BLD * 2);
  short* Vtb  = (short*)alloc(BLD * 2);   // V transposed: [b][h][d][L]
  short* Gk   = (short*)alloc(BLD * 2);
  float* Hf   = (float*)alloc((long)Bn * Ln * HGn * 4);
  float* gate = (float*)alloc((long)Bn * Ln * 4);
  float* ctf  = (float*)alloc((long)Ln * 512 * 4);
  float* stf  = (float*)alloc((long)Ln * 512 * 4);
  float* cts  = (float*)alloc((long)Ln * 512 * 4);
  float* sts  = (float*)alloc((long)Ln * 512 * 4);
  float* zv   = (float*)alloc((long)Bn * NH * Ln * 4);

  float* outp = (float*)d_out;
  float* aw   = outp + BLD;   // attn_w region; doubles as gb scratch before pass 2

  // 1) casts to bf16
  k_cast<<<(int)(BLD / 4 / 256), 256, 0, stream>>>(z,  zb, (int)BLD);
  k_cast<<<(int)(BLD / 4 / 256), 256, 0, stream>>>(ps, pb, (int)BLD);
  k_cast<<<Dn * Dn / 4 / 256, 256, 0, stream>>>(Wq, Wqb, Dn * Dn);
  k_cast<<<Dn * Dn / 4 / 256, 256, 0, stream>>>(Wk, Wkb, Dn * Dn);
  k_cast<<<Dn * Dn / 4 / 256, 256, 0, stream>>>(Wv, Wvb, Dn * Dn);
  k_cast<<<Dn * Dn / 4 / 256, 256, 0, stream>>>(Wc, Wcb, Dn * Dn);
  k_cast<<<HGn * Dn / 4 / 256, 256, 0, stream>>>(Wg1, Wg1b, HGn * Dn);

  // 2) projections (M=4096): Q,K (bias), V (bias, transposed out), gk, h (bias+gelu)
  dim3 pg(Dn / 128, (Bn * Ln) / 128, 1);
  k_gemm<true,  false, true,  false, false, false><<<pg, 256, 0, stream>>>(zb, Wqb, bq, nullptr, Qp, Dn, Dn, 0, 0, 0);
  k_gemm<true,  false, true,  false, false, false><<<pg, 256, 0, stream>>>(zb, Wkb, bk, nullptr, Kp, Dn, Dn, 0, 0, 0);
  k_gemm<true,  false, true,  false, false, true ><<<pg, 256, 0, stream>>>(zb, Wvb, bv, nullptr, Vtb, Dn, Dn, 0, 0, 0);
  k_gemm<false, false, true,  false, false, false><<<pg, 256, 0, stream>>>(pb, Wcb, nullptr, nullptr, Gk, Dn, Dn, 0, 0, 0);
  dim3 hg(HGn / 128, (Bn * Ln) / 128, 1);
  k_gemm<true,  true,  false, false, false, false><<<hg, 256, 0, stream>>>(pb, Wg1b, bg1, nullptr, Hf, HGn, Dn, 0, 0, 0);

  // 3) gb = tanh(gamma)/32 * gk . K_raw^T  (written into attn_w region, causal blocks only)
  dim3 gbg(Ln / 128, Ln / 128, Bn);
  k_gemm<false, false, false, true,  true , false><<<gbg, 256, 0, stream>>>(Gk, Kp, nullptr, gamma, aw, Ln, Dn,
                                                                            (long)Ln * Dn, (long)Ln * Dn, (long)Ln * Ln);

  // 4) RoPE tables, gate, in-place rotation of Q/K (K raw already consumed by gb)
  k_rope_tables<<<(Ln * 512) / 256, 256, 0, stream>>>(ctf, stf, cts, sts);
  k_gate<<<(Bn * Ln) / 4, 256, 0, stream>>>(Hf, Wg2, bg2, gate);
  k_rope<<<Bn * Ln, 256, 0, stream>>>(Qp, Kp, gate, ctf, stf, cts, sts);

  // 5) attention
  k_fill_upper<<<dim3(Ln, Bn), 256, 0, stream>>>(aw);
  k_attn1<<<dim3(Ln / 64, NH, Bn), 256, 0, stream>>>(Qp, Kp, Vtb, aw, outp, zv);
  k_attn2<<<dim3(Ln / 16, Bn), 256, 0, stream>>>(Qp, Kp, aw, zv, aw);
}

// Round 3
// 471.732 us; speedup vs baseline: 1.4627x; 1.1651x over previous
//
#include <hip/hip_runtime.h>
#include <hip/hip_bf16.h>

// Problem constants (B=2, L=2048, D=1024, NH=16, HD=64, H_GATE=256)
constexpr int Bn  = 2;
constexpr int Ln  = 2048;
constexpr int Dn  = 1024;
constexpr int NH  = 16;
constexpr int HGn = 256;
constexpr long BLD = (long)Bn * Ln * Dn;   // 4194304

typedef float f32x4 __attribute__((ext_vector_type(4)));
typedef float f32x2 __attribute__((ext_vector_type(2)));
typedef short s16x8 __attribute__((ext_vector_type(8)));
typedef short s16x4 __attribute__((ext_vector_type(4)));
typedef short s16x2 __attribute__((ext_vector_type(2)));

#define DEVI static __device__ __forceinline__

DEVI float bf2f(short u) {
  union { float f; unsigned int i; } v; v.i = ((unsigned int)(unsigned short)u) << 16; return v.f;
}
DEVI short f2bf(float f) {
  union { float f; unsigned int i; } v; v.f = f;
  unsigned int r = v.i + 0x7FFFu + ((v.i >> 16) & 1u);
  return (short)(r >> 16);
}
DEVI void gl_lds16(const void* g, void* l) {
  __builtin_amdgcn_global_load_lds((const __attribute__((address_space(1))) unsigned int*)g,
                                   (__attribute__((address_space(3))) unsigned int*)l, 16, 0, 0);
}

// ---------------- cast f32 -> bf16 ----------------
__global__ void k_cast(const float* __restrict__ s, short* __restrict__ d, int n) {
  int i = (blockIdx.x * 256 + threadIdx.x) * 4;
  if (i >= n) return;
  f32x4 v = *(const f32x4*)(s + i);
  s16x4 o; o[0] = f2bf(v[0]); o[1] = f2bf(v[1]); o[2] = f2bf(v[2]); o[3] = f2bf(v[3]);
  *(s16x4*)(d + i) = o;
}

// ---------------- GEMM: C[m,n] = act(alpha * sum_k A[m,k]*B[n,k] + bias[n]) ----------------
// A: (M,K) bf16 row-major, B: (N,K) bf16 row-major. 128x128 tile, BK=32, 4 waves.
// OUT_VT: write bf16 transposed as Vt[((b*NH+h)*64+dh)*Ln + l]  (row=b*Ln+l, col=h*64+dh)
template<bool HAS_BIAS, bool GELU, bool OUT_BF16, bool CAUSAL, bool SCALE, bool OUT_VT>
__global__ __launch_bounds__(256)
void k_gemm(const short* __restrict__ A, const short* __restrict__ B,
            const float* __restrict__ bias, const float* __restrict__ gamma,
            void* __restrict__ C, int N, int K, long sA, long sB, long sC) {
  int bz = blockIdx.z;
  const short* Ap = A + (long)bz * sA;
  const short* Bp = B + (long)bz * sB;
  int m0 = blockIdx.y * 128, n0 = blockIdx.x * 128;
  if (CAUSAL && n0 > m0 + 127) return;   // whole tile above diagonal: never read
  __shared__ short smA[128 * 32];
  __shared__ short smB[128 * 32];
  int tid = threadIdx.x;
  int lane = tid & 63, wid = tid >> 6;
  int wr = wid >> 1, wc = wid & 1;
  int lr = lane & 15, lg = lane >> 4;
  int r_in = lane >> 2, c_in = (lane & 3) * 8;
  f32x4 acc[4][4] = {};
  for (int k0 = 0; k0 < K; k0 += 32) {
#pragma unroll
    for (int i = 0; i < 2; ++i) {
      int row = wid * 32 + i * 16 + r_in;
      gl_lds16(Ap + (long)(m0 + row) * K + k0 + c_in, smA + row * 32 + c_in);
      gl_lds16(Bp + (long)(n0 + row) * K + k0 + c_in, smB + row * 32 + c_in);
    }
    __syncthreads();
    s16x8 af[4], bf[4];
#pragma unroll
    for (int m = 0; m < 4; m++) af[m] = *(const s16x8*)(smA + (wr * 64 + m * 16 + lr) * 32 + lg * 8);
#pragma unroll
    for (int n = 0; n < 4; n++) bf[n] = *(const s16x8*)(smB + (wc * 64 + n * 16 + lr) * 32 + lg * 8);
#pragma unroll
    for (int m = 0; m < 4; m++)
#pragma unroll
      for (int n = 0; n < 4; n++)
        acc[m][n] = __builtin_amdgcn_mfma_f32_16x16x32_bf16(af[m], bf[n], acc[m][n], 0, 0, 0);
    __syncthreads();
  }
  float alpha = 1.0f;
  if (SCALE) alpha = tanhf(gamma[0]) * 0.03125f;   // tanh(gamma) * d^-0.5
#pragma unroll
  for (int n = 0; n < 4; n++) {
    int col = n0 + wc * 64 + n * 16 + lr;
    float bv = HAS_BIAS ? bias[col] : 0.0f;
#pragma unroll
    for (int m = 0; m < 4; m++) {
#pragma unroll
      for (int r = 0; r < 4; r++) {
        long row = m0 + wr * 64 + m * 16 + lg * 4 + r;
        float v = acc[m][n][r] * alpha + bv;
        if (GELU) v = 0.5f * v * (1.0f + erff(v * 0.70710678118f));
        if (OUT_VT) {
          long off = (((row >> 11) * (long)NH + (col >> 6)) * 64 + (col & 63)) * Ln + (row & (Ln - 1));
          ((short*)C)[off] = f2bf(v);
        } else {
          long off = (long)bz * sC + row * (long)N + col;
          if (OUT_BF16) ((short*)C)[off] = f2bf(v);
          else          ((float*)C)[off] = v;
        }
      }
    }
  }
}

// ---------------- RoPE cos/sin tables: [L][512] for both bases ----------------
__global__ void k_rope_tables(float* __restrict__ ctf, float* __restrict__ stf,
                              float* __restrict__ cts, float* __restrict__ sts) {
  int idx = blockIdx.x * 256 + threadIdx.x;   // L*512 total
  int l = idx >> 9, j = idx & 511;
  float e = (float)j * (1.0f / 512.0f);
  float invf = powf(1.6180339887498949f, -e);
  float invs = powf(1618.0f, -e);
  float af = (float)l * invf, as = (float)l * invs;
  float sf, cf, ss, cs;
  sincosf(af, &sf, &cf);
  sincosf(as, &ss, &cs);
  ctf[idx] = cf; stf[idx] = sf; cts[idx] = cs; sts[idx] = ss;
}

// ---------------- gate = sigmoid(h . Wg2 + bg2), one wave per row ----------------
__global__ void k_gate(const float* __restrict__ Hf, const float* __restrict__ Wg2,
                       const float* __restrict__ bg2, float* __restrict__ gate) {
  int lane = threadIdx.x & 63, wid = threadIdx.x >> 6;
  int row = blockIdx.x * 4 + wid;
  f32x4 h = *(const f32x4*)(Hf + (long)row * HGn + lane * 4);
  f32x4 w = *(const f32x4*)(Wg2 + lane * 4);
  float s = h[0] * w[0] + h[1] * w[1] + h[2] * w[2] + h[3] * w[3];
#pragma unroll
  for (int m = 1; m < 64; m <<= 1) s += __shfl_xor(s, m);
  if (lane == 0) gate[row] = 1.0f / (1.0f + __expf(-(s + bg2[0])));
}

// ---------------- RoPE apply (in place, Q and K), one block per (b,l) ----------------
__global__ void k_rope(short* __restrict__ Q, short* __restrict__ Kx,
                       const float* __restrict__ gate,
                       const float* __restrict__ ctf, const float* __restrict__ stf,
                       const float* __restrict__ cts, const float* __restrict__ sts) {
  int bl = blockIdx.x;
  int l = bl & (Ln - 1);
  int t = threadIdx.x;
  float g = gate[bl];
  int j = t * 2;
  f32x2 vcf = *(const f32x2*)(ctf + l * 512 + j);
  f32x2 vsf = *(const f32x2*)(stf + l * 512 + j);
  f32x2 vcs = *(const f32x2*)(cts + l * 512 + j);
  f32x2 vss = *(const f32x2*)(sts + l * 512 + j);
  float c0 = g * vcf[0] + (1.f - g) * vcs[0];
  float c1 = g * vcf[1] + (1.f - g) * vcs[1];
  float s0 = g * vsf[0] + (1.f - g) * vss[0];
  float s1 = g * vsf[1] + (1.f - g) * vss[1];
  long base = (long)bl * Dn + j;
  {
    s16x2 xa = *(const s16x2*)(Q + base);
    s16x2 xb = *(const s16x2*)(Q + base + 512);
    float a0 = bf2f(xa[0]), a1 = bf2f(xa[1]), b0 = bf2f(xb[0]), b1 = bf2f(xb[1]);
    s16x2 o0, o1;
    o0[0] = f2bf(a0 * c0 - b0 * s0); o0[1] = f2bf(a1 * c1 - b1 * s1);
    o1[0] = f2bf(b0 * c0 + a0 * s0); o1[1] = f2bf(b1 * c1 + a1 * s1);
    *(s16x2*)(Q + base) = o0;
    *(s16x2*)(Q + base + 512) = o1;
  }
  {
    s16x2 xa = *(const s16x2*)(Kx + base);
    s16x2 xb = *(const s16x2*)(Kx + base + 512);
    float a0 = bf2f(xa[0]), a1 = bf2f(xa[1]), b0 = bf2f(xb[0]), b1 = bf2f(xb[1]);
    s16x2 o0, o1;
    o0[0] = f2bf(a0 * c0 - b0 * s0); o0[1] = f2bf(a1 * c1 - b1 * s1);
    o1[0] = f2bf(b0 * c0 + a0 * s0); o1[1] = f2bf(b1 * c1 + a1 * s1);
    *(s16x2*)(Kx + base) = o0;
    *(s16x2*)(Kx + base + 512) = o1;
  }
}

// ---------------- zero the strict upper triangle of attn_w ----------------
__global__ void k_fill_upper(float* __restrict__ aw) {
  int q = blockIdx.x, b = blockIdx.y;
  float* row = aw + ((long)b * Ln + q) * Ln;
  for (int k = q + 1 + threadIdx.x; k < Ln; k += 256) row[k] = 0.0f;
}

// ---------------- attention pass 1: 4 waves, 64 q-rows, one (b,h) per block ----------------
// K staged [64k][64d], Vt staged [64d][64k]; both via global_load_lds with
// source-pre-swizzled XOR layout: LDS(row, slot16B) holds logical chunk (slot ^ (row&7)).
__global__ __launch_bounds__(256)
void k_attn1(const short* __restrict__ Q, const short* __restrict__ Kx,
             const short* __restrict__ Vt, const float* __restrict__ gb,
             float* __restrict__ outp, float* __restrict__ zinv) {
  int qb = blockIdx.x, h = blockIdx.y, b = blockIdx.z;
  int tid = threadIdx.x;
  int lane = tid & 63, w = tid >> 6;
  int lr = lane & 15, lg = lane >> 4;
  int q0w = qb * 64 + w * 16;
  __shared__ short smK[64 * 64];
  __shared__ short smV[64 * 64];
  __shared__ short smP[4 * 16 * 64];
  short* pw = smP + w * 1024;
  // Q frags (16 q rows per wave, d = h*64 .. +63)
  const short* qbp = Q + ((long)(b * Ln) + q0w + lr) * Dn + h * 64 + lg * 8;
  s16x8 qf0 = *(const s16x8*)(qbp);
  s16x8 qf1 = *(const s16x8*)(qbp + 32);
  f32x4 acc[4] = {};
  float az[4] = {0.f, 0.f, 0.f, 0.f};
  // staging geometry (per lane)
  int r0 = w * 16 + (lane >> 3);                 // t=0 row in tile (0..63)
  int scol = ((lane & 7) ^ (lane >> 3)) * 8;     // pre-swizzled source col (elems)
  const short* Kg = Kx + (long)(b * Ln) * Dn + h * 64;
  const short* Vg = Vt + (long)(b * NH + h) * 64 * Ln;
  short* ldsK0 = smK + (w * 2 + 0) * 512;
  short* ldsK1 = smK + (w * 2 + 1) * 512;
  short* ldsV0 = smV + (w * 2 + 0) * 512;
  short* ldsV1 = smV + (w * 2 + 1) * 512;
  int sw = (lr & 7) << 3;                        // read-side XOR (elems)

  for (int k0 = 0; k0 <= qb * 64; k0 += 64) {
    gl_lds16(Kg + (long)(k0 + r0)     * Dn + scol, ldsK0);
    gl_lds16(Kg + (long)(k0 + r0 + 8) * Dn + scol, ldsK1);
    gl_lds16(Vg + (long)(r0)     * Ln + k0 + scol, ldsV0);
    gl_lds16(Vg + (long)(r0 + 8) * Ln + k0 + scol, ldsV1);
    __syncthreads();
    // ---- QK^T + exp into smP ----
#pragma unroll
    for (int kk = 0; kk < 4; ++kk) {
      int row = kk * 16 + lr;
      const short* kr = smK + row * 64;
      s16x8 kf0 = *(const s16x8*)(kr + ((lg * 8) ^ sw));
      s16x8 kf1 = *(const s16x8*)(kr + ((32 + lg * 8) ^ sw));
      f32x4 S = {};
      S = __builtin_amdgcn_mfma_f32_16x16x32_bf16(qf0, kf0, S, 0, 0, 0);
      S = __builtin_amdgcn_mfma_f32_16x16x32_bf16(qf1, kf1, S, 0, 0, 0);
      int k = k0 + kk * 16 + lr;
      int kp = kk * 16 + lr;
      const float* gbp = gb + ((long)b * Ln + q0w + lg * 4) * Ln + k;
#pragma unroll
      for (int r = 0; r < 4; r++) {
        int q = q0w + lg * 4 + r;
        float gv = gbp[(long)r * Ln];
        float arg = (k <= q) ? (S[r] * 0.125f + gv) : -80.0f;
        float p = __expf(arg);
        az[r] += p;
        int qq = lg * 4 + r;
        pw[qq * 64 + (kp ^ ((qq & 7) << 3))] = f2bf(p);
      }
    }
    // ---- P @ V ----
#pragma unroll
    for (int c = 0; c < 2; ++c) {
      s16x8 pf = *(const s16x8*)(pw + lr * 64 + ((c * 32 + lg * 8) ^ sw));
#pragma unroll
      for (int n = 0; n < 4; n++) {
        int row = n * 16 + lr;
        s16x8 vf = *(const s16x8*)(smV + row * 64 + ((c * 32 + lg * 8) ^ sw));
        acc[n] = __builtin_amdgcn_mfma_f32_16x16x32_bf16(pf, vf, acc[n], 0, 0, 0);
      }
    }
    __syncthreads();
  }
#pragma unroll
  for (int r = 0; r < 4; r++) {
    float z = az[r];
    z += __shfl_xor(z, 1); z += __shfl_xor(z, 2); z += __shfl_xor(z, 4); z += __shfl_xor(z, 8);
    az[r] = 1.0f / z;
  }
  if (lr == 0) {
#pragma unroll
    for (int r = 0; r < 4; r++)
      zinv[((long)(b * NH + h)) * Ln + q0w + lg * 4 + r] = az[r];
  }
#pragma unroll
  for (int n = 0; n < 4; n++) {
#pragma unroll
    for (int r = 0; r < 4; r++) {
      int q = q0w + lg * 4 + r;
      outp[((long)(b * Ln) + q) * Dn + h * 64 + n * 16 + lr] = acc[n][r] * az[r];
    }
  }
}

// ---------------- attention pass 2: attn_w = mean_h softmax over 64x64 causal tiles ----------------
// grid.x = 528 triangular tiles (qb>=kb), grid.y = B. gb and aw alias (disjoint per block).
__global__ __launch_bounds__(256)
void k_attn2(const short* __restrict__ Q, const short* __restrict__ Kx,
             const float* gb, const float* __restrict__ zinv, float* aw) {
  int b = blockIdx.y;
  int t = blockIdx.x;
  int qb = (int)((sqrtf(8.0f * (float)t + 1.0f) - 1.0f) * 0.5f);
  while ((qb + 1) * (qb + 2) / 2 <= t) ++qb;
  while (qb * (qb + 1) / 2 > t) --qb;
  int kb = t - qb * (qb + 1) / 2;
  int q0 = qb * 64, k0 = kb * 64;
  int tid = threadIdx.x, lane = tid & 63, w = tid >> 6;
  int lr = lane & 15, lg = lane >> 4;
  int q0w = q0 + w * 16;
  bool diag = (qb == kb);
  __shared__ float smZ[NH * 64];
  for (int i = tid; i < NH * 64; i += 256) {
    int h = i >> 6, qq = i & 63;
    smZ[i] = zinv[((long)(b * NH + h)) * Ln + q0 + qq];
  }
  // bias tile (masked region of gb is pre-zeroed; we mask the write anyway)
  float gv[4][4];
#pragma unroll
  for (int n = 0; n < 4; n++) {
    int k = k0 + n * 16 + lr;
#pragma unroll
    for (int r = 0; r < 4; r++) {
      int q = q0w + lg * 4 + r;
      gv[n][r] = gb[((long)b * Ln + q) * Ln + k];
    }
  }
  __syncthreads();
  float wa[4][4] = {{0.f}};
  for (int h = 0; h < NH; ++h) {
    const short* qbp = Q + ((long)(b * Ln) + q0w + lr) * Dn + h * 64 + lg * 8;
    s16x8 qf0 = *(const s16x8*)(qbp);
    s16x8 qf1 = *(const s16x8*)(qbp + 32);
    float zq[4];
#pragma unroll
    for (int r = 0; r < 4; r++) zq[r] = smZ[h * 64 + w * 16 + lg * 4 + r];
#pragma unroll
    for (int n = 0; n < 4; n++) {
      const short* kbp = Kx + ((long)(b * Ln) + k0 + n * 16 + lr) * Dn + h * 64 + lg * 8;
      s16x8 kf0 = *(const s16x8*)(kbp);
      s16x8 kf1 = *(const s16x8*)(kbp + 32);
      f32x4 S = {};
      S = __builtin_amdgcn_mfma_f32_16x16x32_bf16(qf0, kf0, S, 0, 0, 0);
      S = __builtin_amdgcn_mfma_f32_16x16x32_bf16(qf1, kf1, S, 0, 0, 0);
#pragma unroll
      for (int r = 0; r < 4; r++)
        wa[n][r] += __expf(S[r] * 0.125f + gv[n][r]) * zq[r];
    }
  }
#pragma unroll
  for (int n = 0; n < 4; n++) {
    int k = k0 + n * 16 + lr;
#pragma unroll
    for (int r = 0; r < 4; r++) {
      int q = q0w + lg * 4 + r;
      float v = wa[n][r] * (1.0f / 16.0f);
      if (diag && k > q) v = 0.0f;
      aw[((long)b * Ln + q) * Ln + k] = v;
    }
  }
}

extern "C" void kernel_launch(void* const* d_in, const int* in_sizes, int n_in,
                              void* d_out, int out_size, void* d_ws, size_t ws_size,
                              hipStream_t stream) {
  const float* z    = (const float*)d_in[0];
  const float* ps   = (const float*)d_in[1];
  const float* Wq   = (const float*)d_in[2];
  const float* bq   = (const float*)d_in[3];
  const float* Wk   = (const float*)d_in[4];
  const float* bk   = (const float*)d_in[5];
  const float* Wv   = (const float*)d_in[6];
  const float* bv   = (const float*)d_in[7];
  const float* Wc   = (const float*)d_in[8];
  const float* gamma= (const float*)d_in[9];
  const float* Wg1  = (const float*)d_in[10];
  const float* bg1  = (const float*)d_in[11];
  const float* Wg2  = (const float*)d_in[12];
  const float* bg2  = (const float*)d_in[13];

  char* w = (char*)d_ws;
  auto alloc = [&](long bytes) { void* p = (void*)w; w += (bytes + 255) & ~255L; return p; };
  short* zb   = (short*)alloc(BLD * 2);
  short* pb   = (short*)alloc(BLD * 2);
  short* Wqb  = (short*)alloc((long)Dn * Dn * 2);
  short* Wkb  = (short*)alloc((long)Dn * Dn * 2);
  short* Wvb  = (short*)alloc((long)Dn * Dn * 2);
  short* Wcb  = (short*)alloc((long)Dn * Dn * 2);
  short* Wg1b = (short*)alloc((long)HGn * Dn * 2);
  short* Qp   = (short*)alloc(BLD * 2);
  short* Kp   = (short*)alloc(BLD * 2);
  short* Vtb  = (short*)alloc(BLD * 2);   // V transposed: [b][h][d][L]
  short* Gk   = (short*)alloc(BLD * 2);
  float* Hf   = (float*)alloc((long)Bn * Ln * HGn * 4);
  float* gate = (float*)alloc((long)Bn * Ln * 4);
  float* ctf  = (float*)alloc((long)Ln * 512 * 4);
  float* stf  = (float*)alloc((long)Ln * 512 * 4);
  float* cts  = (float*)alloc((long)Ln * 512 * 4);
  float* sts  = (float*)alloc((long)Ln * 512 * 4);
  float* zv   = (float*)alloc((long)Bn * NH * Ln * 4);

  float* outp = (float*)d_out;
  float* aw   = outp + BLD;   // attn_w region; doubles as gb scratch before pass 2

  // 1) casts to bf16
  k_cast<<<(int)(BLD / 4 / 256), 256, 0, stream>>>(z,  zb, (int)BLD);
  k_cast<<<(int)(BLD / 4 / 256), 256, 0, stream>>>(ps, pb, (int)BLD);
  k_cast<<<Dn * Dn / 4 / 256, 256, 0, stream>>>(Wq, Wqb, Dn * Dn);
  k_cast<<<Dn * Dn / 4 / 256, 256, 0, stream>>>(Wk, Wkb, Dn * Dn);
  k_cast<<<Dn * Dn / 4 / 256, 256, 0, stream>>>(Wv, Wvb, Dn * Dn);
  k_cast<<<Dn * Dn / 4 / 256, 256, 0, stream>>>(Wc, Wcb, Dn * Dn);
  k_cast<<<HGn * Dn / 4 / 256, 256, 0, stream>>>(Wg1, Wg1b, HGn * Dn);

  // 2) projections (M=4096): Q,K (bias), V (bias, transposed out), gk, h (bias+gelu)
  dim3 pg(Dn / 128, (Bn * Ln) / 128, 1);
  k_gemm<true,  false, true,  false, false, false><<<pg, 256, 0, stream>>>(zb, Wqb, bq, nullptr, Qp, Dn, Dn, 0, 0, 0);
  k_gemm<true,  false, true,  false, false, false><<<pg, 256, 0, stream>>>(zb, Wkb, bk, nullptr, Kp, Dn, Dn, 0, 0, 0);
  k_gemm<true,  false, true,  false, false, true ><<<pg, 256, 0, stream>>>(zb, Wvb, bv, nullptr, Vtb, Dn, Dn, 0, 0, 0);
  k_gemm<false, false, true,  false, false, false><<<pg, 256, 0, stream>>>(pb, Wcb, nullptr, nullptr, Gk, Dn, Dn, 0, 0, 0);
  dim3 hg(HGn / 128, (Bn * Ln) / 128, 1);
  k_gemm<true,  true,  false, false, false, false><<<hg, 256, 0, stream>>>(pb, Wg1b, bg1, nullptr, Hf, HGn, Dn, 0, 0, 0);

  // 3) gb = tanh(gamma)/32 * gk . K_raw^T  (written into attn_w region, causal blocks only)
  dim3 gbg(Ln / 128, Ln / 128, Bn);
  k_gemm<false, false, false, true,  true , false><<<gbg, 256, 0, stream>>>(Gk, Kp, nullptr, gamma, aw, Ln, Dn,
                                                                            (long)Ln * Dn, (long)Ln * Dn, (long)Ln * Ln);

  // 4) RoPE tables, gate, in-place rotation of Q/K (K raw already consumed by gb)
  k_rope_tables<<<(Ln * 512) / 256, 256, 0, stream>>>(ctf, stf, cts, sts);
  k_gate<<<(Bn * Ln) / 4, 256, 0, stream>>>(Hf, Wg2, bg2, gate);
  k_rope<<<Bn * Ln, 256, 0, stream>>>(Qp, Kp, gate, ctf, stf, cts, sts);

  // 5) attention
  k_fill_upper<<<dim3(Ln, Bn), 256, 0, stream>>>(aw);
  k_attn1<<<dim3(Ln / 64, NH, Bn), 256, 0, stream>>>(Qp, Kp, Vtb, aw, outp, zv);
  k_attn2<<<dim3(32 * 33 / 2, Bn), 256, 0, stream>>>(Qp, Kp, aw, zv, aw);
}

// Round 4
// 405.449 us; speedup vs baseline: 1.7019x; 1.1635x over previous
//
#include <hip/hip_runtime.h>
#include <hip/hip_bf16.h>

// Problem constants (B=2, L=2048, D=1024, NH=16, HD=64, H_GATE=256)
constexpr int Bn  = 2;
constexpr int Ln  = 2048;
constexpr int Dn  = 1024;
constexpr int NH  = 16;
constexpr int HGn = 256;
constexpr long BLD = (long)Bn * Ln * Dn;   // 4194304

typedef float f32x4 __attribute__((ext_vector_type(4)));
typedef float f32x2 __attribute__((ext_vector_type(2)));
typedef short s16x8 __attribute__((ext_vector_type(8)));
typedef short s16x4 __attribute__((ext_vector_type(4)));
typedef short s16x2 __attribute__((ext_vector_type(2)));

#define DEVI static __device__ __forceinline__

DEVI float bf2f(short u) {
  union { float f; unsigned int i; } v; v.i = ((unsigned int)(unsigned short)u) << 16; return v.f;
}
DEVI short f2bf(float f) {
  union { float f; unsigned int i; } v; v.f = f;
  unsigned int r = v.i + 0x7FFFu + ((v.i >> 16) & 1u);
  return (short)(r >> 16);
}
DEVI void gl_lds16(const void* g, void* l) {
  __builtin_amdgcn_global_load_lds((const __attribute__((address_space(1))) unsigned int*)g,
                                   (__attribute__((address_space(3))) unsigned int*)l, 16, 0, 0);
}

// ---------------- cast f32 -> bf16 ----------------
__global__ void k_cast(const float* __restrict__ s, short* __restrict__ d, int n) {
  int i = (blockIdx.x * 256 + threadIdx.x) * 4;
  if (i >= n) return;
  f32x4 v = *(const f32x4*)(s + i);
  s16x4 o; o[0] = f2bf(v[0]); o[1] = f2bf(v[1]); o[2] = f2bf(v[2]); o[3] = f2bf(v[3]);
  *(s16x4*)(d + i) = o;
}

// ---------------- GEMM: C[m,n] = act(alpha * sum_k A[m,k]*B[n,k] + bias[n]) ----------------
template<bool HAS_BIAS, bool GELU, bool OUT_BF16, bool CAUSAL, bool SCALE, bool OUT_VT>
__global__ __launch_bounds__(256)
void k_gemm(const short* __restrict__ A, const short* __restrict__ B,
            const float* __restrict__ bias, const float* __restrict__ gamma,
            void* __restrict__ C, int N, int K, long sA, long sB, long sC) {
  int bz = blockIdx.z;
  const short* Ap = A + (long)bz * sA;
  const short* Bp = B + (long)bz * sB;
  int m0 = blockIdx.y * 128, n0 = blockIdx.x * 128;
  if (CAUSAL && n0 > m0 + 127) return;   // whole tile above diagonal: never read
  __shared__ short smA[128 * 32];
  __shared__ short smB[128 * 32];
  int tid = threadIdx.x;
  int lane = tid & 63, wid = tid >> 6;
  int wr = wid >> 1, wc = wid & 1;
  int lr = lane & 15, lg = lane >> 4;
  int r_in = lane >> 2, c_in = (lane & 3) * 8;
  f32x4 acc[4][4] = {};
  for (int k0 = 0; k0 < K; k0 += 32) {
#pragma unroll
    for (int i = 0; i < 2; ++i) {
      int row = wid * 32 + i * 16 + r_in;
      gl_lds16(Ap + (long)(m0 + row) * K + k0 + c_in, smA + row * 32 + c_in);
      gl_lds16(Bp + (long)(n0 + row) * K + k0 + c_in, smB + row * 32 + c_in);
    }
    __syncthreads();
    s16x8 af[4], bf[4];
#pragma unroll
    for (int m = 0; m < 4; m++) af[m] = *(const s16x8*)(smA + (wr * 64 + m * 16 + lr) * 32 + lg * 8);
#pragma unroll
    for (int n = 0; n < 4; n++) bf[n] = *(const s16x8*)(smB + (wc * 64 + n * 16 + lr) * 32 + lg * 8);
#pragma unroll
    for (int m = 0; m < 4; m++)
#pragma unroll
      for (int n = 0; n < 4; n++)
        acc[m][n] = __builtin_amdgcn_mfma_f32_16x16x32_bf16(af[m], bf[n], acc[m][n], 0, 0, 0);
    __syncthreads();
  }
  float alpha = 1.0f;
  if (SCALE) alpha = tanhf(gamma[0]) * 0.03125f;   // tanh(gamma) * d^-0.5
#pragma unroll
  for (int n = 0; n < 4; n++) {
    int col = n0 + wc * 64 + n * 16 + lr;
    float bv = HAS_BIAS ? bias[col] : 0.0f;
#pragma unroll
    for (int m = 0; m < 4; m++) {
#pragma unroll
      for (int r = 0; r < 4; r++) {
        long row = m0 + wr * 64 + m * 16 + lg * 4 + r;
        float v = acc[m][n][r] * alpha + bv;
        if (GELU) v = 0.5f * v * (1.0f + erff(v * 0.70710678118f));
        if (OUT_VT) {
          long off = (((row >> 11) * (long)NH + (col >> 6)) * 64 + (col & 63)) * Ln + (row & (Ln - 1));
          ((short*)C)[off] = f2bf(v);
        } else {
          long off = (long)bz * sC + row * (long)N + col;
          if (OUT_BF16) ((short*)C)[off] = f2bf(v);
          else          ((float*)C)[off] = v;
        }
      }
    }
  }
}

// ---------------- RoPE cos/sin tables: [L][512] for both bases ----------------
__global__ void k_rope_tables(float* __restrict__ ctf, float* __restrict__ stf,
                              float* __restrict__ cts, float* __restrict__ sts) {
  int idx = blockIdx.x * 256 + threadIdx.x;   // L*512 total
  int l = idx >> 9, j = idx & 511;
  float e = (float)j * (1.0f / 512.0f);
  float invf = powf(1.6180339887498949f, -e);
  float invs = powf(1618.0f, -e);
  float af = (float)l * invf, as = (float)l * invs;
  float sf, cf, ss, cs;
  sincosf(af, &sf, &cf);
  sincosf(as, &ss, &cs);
  ctf[idx] = cf; stf[idx] = sf; cts[idx] = cs; sts[idx] = ss;
}

// ---------------- gate = sigmoid(h . Wg2 + bg2), one wave per row ----------------
__global__ void k_gate(const float* __restrict__ Hf, const float* __restrict__ Wg2,
                       const float* __restrict__ bg2, float* __restrict__ gate) {
  int lane = threadIdx.x & 63, wid = threadIdx.x >> 6;
  int row = blockIdx.x * 4 + wid;
  f32x4 h = *(const f32x4*)(Hf + (long)row * HGn + lane * 4);
  f32x4 w = *(const f32x4*)(Wg2 + lane * 4);
  float s = h[0] * w[0] + h[1] * w[1] + h[2] * w[2] + h[3] * w[3];
#pragma unroll
  for (int m = 1; m < 64; m <<= 1) s += __shfl_xor(s, m);
  if (lane == 0) gate[row] = 1.0f / (1.0f + __expf(-(s + bg2[0])));
}

// ---------------- RoPE apply (in place, Q and K), one block per (b,l) ----------------
__global__ void k_rope(short* __restrict__ Q, short* __restrict__ Kx,
                       const float* __restrict__ gate,
                       const float* __restrict__ ctf, const float* __restrict__ stf,
                       const float* __restrict__ cts, const float* __restrict__ sts) {
  int bl = blockIdx.x;
  int l = bl & (Ln - 1);
  int t = threadIdx.x;
  float g = gate[bl];
  int j = t * 2;
  f32x2 vcf = *(const f32x2*)(ctf + l * 512 + j);
  f32x2 vsf = *(const f32x2*)(stf + l * 512 + j);
  f32x2 vcs = *(const f32x2*)(cts + l * 512 + j);
  f32x2 vss = *(const f32x2*)(sts + l * 512 + j);
  float c0 = g * vcf[0] + (1.f - g) * vcs[0];
  float c1 = g * vcf[1] + (1.f - g) * vcs[1];
  float s0 = g * vsf[0] + (1.f - g) * vss[0];
  float s1 = g * vsf[1] + (1.f - g) * vss[1];
  long base = (long)bl * Dn + j;
  {
    s16x2 xa = *(const s16x2*)(Q + base);
    s16x2 xb = *(const s16x2*)(Q + base + 512);
    float a0 = bf2f(xa[0]), a1 = bf2f(xa[1]), b0 = bf2f(xb[0]), b1 = bf2f(xb[1]);
    s16x2 o0, o1;
    o0[0] = f2bf(a0 * c0 - b0 * s0); o0[1] = f2bf(a1 * c1 - b1 * s1);
    o1[0] = f2bf(b0 * c0 + a0 * s0); o1[1] = f2bf(b1 * c1 + a1 * s1);
    *(s16x2*)(Q + base) = o0;
    *(s16x2*)(Q + base + 512) = o1;
  }
  {
    s16x2 xa = *(const s16x2*)(Kx + base);
    s16x2 xb = *(const s16x2*)(Kx + base + 512);
    float a0 = bf2f(xa[0]), a1 = bf2f(xa[1]), b0 = bf2f(xb[0]), b1 = bf2f(xb[1]);
    s16x2 o0, o1;
    o0[0] = f2bf(a0 * c0 - b0 * s0); o0[1] = f2bf(a1 * c1 - b1 * s1);
    o1[0] = f2bf(b0 * c0 + a0 * s0); o1[1] = f2bf(b1 * c1 + a1 * s1);
    *(s16x2*)(Kx + base) = o0;
    *(s16x2*)(Kx + base + 512) = o1;
  }
}

// ---------------- zero the strict upper triangle of attn_w ----------------
__global__ void k_fill_upper(float* __restrict__ aw) {
  int q = blockIdx.x, b = blockIdx.y;
  float* row = aw + ((long)b * Ln + q) * Ln;
  for (int k = q + 1 + threadIdx.x; k < Ln; k += 256) row[k] = 0.0f;
}

// ---------------- attention pass 1: balanced 1-D grid, double-buffered pipeline ----------------
// Tile map: bijective (lin) -> (qb,h,b) such that any 4-consecutive-id quad AND any
// stride-256 quad has constant total work (66 tile-units) -> per-CU balance under both
// sequential and round-robin block placement models.
__global__ __launch_bounds__(256)
void k_attn1(const short* __restrict__ Q, const short* __restrict__ Kx,
             const short* __restrict__ Vt, const float* __restrict__ gb,
             float* __restrict__ outp, float* __restrict__ zinv) {
  int lin = blockIdx.x;
  int u2 = ((lin & 3) + (lin >> 8)) & 3;
  int w5 = (lin >> 2) & 31;
  int w2 = (w5 + ((u2 >> 1) << 4)) & 31;
  int qb = (u2 & 1) ? (31 - w2) : w2;
  int hb = (((lin >> 7) & 7) << 2) | (lin & 3);
  int h = hb & 15, b = hb >> 4;

  int tid = threadIdx.x;
  int lane = tid & 63, w = tid >> 6;
  int lr = lane & 15, lg = lane >> 4;
  int q0w = qb * 64 + w * 16;
  __shared__ short smK[2][64 * 64];
  __shared__ short smV[2][64 * 64];
  __shared__ short smP[4 * 16 * 64];
  short* pw = smP + w * 1024;

  const short* qbp = Q + ((long)(b * Ln) + q0w + lr) * Dn + h * 64 + lg * 8;
  s16x8 qf0 = *(const s16x8*)(qbp);
  s16x8 qf1 = *(const s16x8*)(qbp + 32);
  f32x4 acc[4] = {};
  float az[4] = {0.f, 0.f, 0.f, 0.f};

  int r0 = w * 16 + (lane >> 3);                 // staged row in tile (0..63)
  int scol = ((lane & 7) ^ (lane >> 3)) * 8;     // pre-swizzled source col (elems)
  const short* Kg = Kx + (long)(b * Ln) * Dn + h * 64;
  const short* Vg = Vt + (long)(b * NH + h) * 64 * Ln;
  int sw = (lr & 7) << 3;                        // read-side XOR (elems)
  const float* gbase = gb + ((long)b * Ln + q0w + lg * 4) * Ln + lr;

  int nt = qb + 1;
  auto stage = [&](int buf, int t) {
    long k0 = (long)t * 64;
    short* bK = &smK[buf][w * 1024];
    short* bV = &smV[buf][w * 1024];
    gl_lds16(Kg + (k0 + r0) * Dn + scol,           bK);
    gl_lds16(Kg + (k0 + r0 + 8) * Dn + scol,       bK + 512);
    gl_lds16(Vg + (long)r0 * Ln + k0 + scol,       bV);
    gl_lds16(Vg + (long)(r0 + 8) * Ln + k0 + scol, bV + 512);
  };

  float gcur[4][4], gnxt[4][4];
  stage(0, 0);
  {
    const float* g0 = gbase;
#pragma unroll
    for (int kk = 0; kk < 4; ++kk)
#pragma unroll
      for (int r = 0; r < 4; ++r) gcur[kk][r] = g0[(long)r * Ln + kk * 16];
  }
  int cur = 0;
  for (int t = 0; t < nt; ++t) {
    bool pre = (t + 1 < nt);
    if (pre) {
      const float* g0 = gbase + (t + 1) * 64;
#pragma unroll
      for (int kk = 0; kk < 4; ++kk)
#pragma unroll
        for (int r = 0; r < 4; ++r) gnxt[kk][r] = g0[(long)r * Ln + kk * 16];
      stage(cur ^ 1, t + 1);
    }
    __builtin_amdgcn_sched_barrier(0);
    if (pre) asm volatile("s_waitcnt vmcnt(20)" ::: "memory");
    else     asm volatile("s_waitcnt vmcnt(0)" ::: "memory");
    __builtin_amdgcn_s_barrier();
    __builtin_amdgcn_sched_barrier(0);
    int k0 = t * 64;
    const short* Kc = smK[cur];
    const short* Vc = smV[cur];
    // ---- QK^T + exp into smP ----
#pragma unroll
    for (int kk = 0; kk < 4; ++kk) {
      const short* kr = Kc + (kk * 16 + lr) * 64;
      s16x8 kf0 = *(const s16x8*)(kr + ((lg * 8) ^ sw));
      s16x8 kf1 = *(const s16x8*)(kr + ((32 + lg * 8) ^ sw));
      f32x4 S = {};
      S = __builtin_amdgcn_mfma_f32_16x16x32_bf16(qf0, kf0, S, 0, 0, 0);
      S = __builtin_amdgcn_mfma_f32_16x16x32_bf16(qf1, kf1, S, 0, 0, 0);
      int k = k0 + kk * 16 + lr;
#pragma unroll
      for (int r = 0; r < 4; r++) {
        int q = q0w + lg * 4 + r;
        float arg = (k <= q) ? (S[r] * 0.125f + gcur[kk][r]) : -80.0f;
        float p = __expf(arg);
        az[r] += p;
        int qq = lg * 4 + r;
        pw[qq * 64 + ((kk * 16 + lr) ^ ((qq & 7) << 3))] = f2bf(p);
      }
    }
    // ---- P @ V ----
#pragma unroll
    for (int c = 0; c < 2; ++c) {
      s16x8 pf = *(const s16x8*)(pw + lr * 64 + ((c * 32 + lg * 8) ^ sw));
#pragma unroll
      for (int n = 0; n < 4; n++) {
        s16x8 vf = *(const s16x8*)(Vc + (n * 16 + lr) * 64 + ((c * 32 + lg * 8) ^ sw));
        acc[n] = __builtin_amdgcn_mfma_f32_16x16x32_bf16(pf, vf, acc[n], 0, 0, 0);
      }
    }
    __builtin_amdgcn_s_barrier();
    if (pre) {
#pragma unroll
      for (int kk = 0; kk < 4; ++kk)
#pragma unroll
        for (int r = 0; r < 4; ++r) gcur[kk][r] = gnxt[kk][r];
    }
    cur ^= 1;
  }
#pragma unroll
  for (int r = 0; r < 4; r++) {
    float z = az[r];
    z += __shfl_xor(z, 1); z += __shfl_xor(z, 2); z += __shfl_xor(z, 4); z += __shfl_xor(z, 8);
    az[r] = 1.0f / z;
  }
  if (lr == 0) {
#pragma unroll
    for (int r = 0; r < 4; r++)
      zinv[((long)(b * NH + h)) * Ln + q0w + lg * 4 + r] = az[r];
  }
#pragma unroll
  for (int n = 0; n < 4; n++) {
#pragma unroll
    for (int r = 0; r < 4; r++) {
      int q = q0w + lg * 4 + r;
      outp[((long)(b * Ln) + q) * Dn + h * 64 + n * 16 + lr] = acc[n][r] * az[r];
    }
  }
}

// ---------------- attention pass 2: attn_w = mean_h softmax over 64x64 causal tiles ----------------
__global__ __launch_bounds__(256)
void k_attn2(const short* __restrict__ Q, const short* __restrict__ Kx,
             const float* gb, const float* __restrict__ zinv, float* aw) {
  int b = blockIdx.y;
  int t = blockIdx.x;
  int qb = (int)((sqrtf(8.0f * (float)t + 1.0f) - 1.0f) * 0.5f);
  while ((qb + 1) * (qb + 2) / 2 <= t) ++qb;
  while (qb * (qb + 1) / 2 > t) --qb;
  int kb = t - qb * (qb + 1) / 2;
  int q0 = qb * 64, k0 = kb * 64;
  int tid = threadIdx.x, lane = tid & 63, w = tid >> 6;
  int lr = lane & 15, lg = lane >> 4;
  int q0w = q0 + w * 16;
  bool diag = (qb == kb);
  __shared__ float smZ[NH * 64];
  for (int i = tid; i < NH * 64; i += 256) {
    int h = i >> 6, qq = i & 63;
    smZ[i] = zinv[((long)(b * NH + h)) * Ln + q0 + qq];
  }
  float gv[4][4];
#pragma unroll
  for (int n = 0; n < 4; n++) {
    int k = k0 + n * 16 + lr;
#pragma unroll
    for (int r = 0; r < 4; r++) {
      int q = q0w + lg * 4 + r;
      gv[n][r] = gb[((long)b * Ln + q) * Ln + k];
    }
  }
  __syncthreads();
  float wa[4][4] = {{0.f}};
  for (int h = 0; h < NH; ++h) {
    const short* qbp = Q + ((long)(b * Ln) + q0w + lr) * Dn + h * 64 + lg * 8;
    s16x8 qf0 = *(const s16x8*)(qbp);
    s16x8 qf1 = *(const s16x8*)(qbp + 32);
    float zq[4];
#pragma unroll
    for (int r = 0; r < 4; r++) zq[r] = smZ[h * 64 + w * 16 + lg * 4 + r];
#pragma unroll
    for (int n = 0; n < 4; n++) {
      const short* kbp = Kx + ((long)(b * Ln) + k0 + n * 16 + lr) * Dn + h * 64 + lg * 8;
      s16x8 kf0 = *(const s16x8*)(kbp);
      s16x8 kf1 = *(const s16x8*)(kbp + 32);
      f32x4 S = {};
      S = __builtin_amdgcn_mfma_f32_16x16x32_bf16(qf0, kf0, S, 0, 0, 0);
      S = __builtin_amdgcn_mfma_f32_16x16x32_bf16(qf1, kf1, S, 0, 0, 0);
#pragma unroll
      for (int r = 0; r < 4; r++)
        wa[n][r] += __expf(S[r] * 0.125f + gv[n][r]) * zq[r];
    }
  }
#pragma unroll
  for (int n = 0; n < 4; n++) {
    int k = k0 + n * 16 + lr;
#pragma unroll
    for (int r = 0; r < 4; r++) {
      int q = q0w + lg * 4 + r;
      float v = wa[n][r] * (1.0f / 16.0f);
      if (diag && k > q) v = 0.0f;
      aw[((long)b * Ln + q) * Ln + k] = v;
    }
  }
}

extern "C" void kernel_launch(void* const* d_in, const int* in_sizes, int n_in,
                              void* d_out, int out_size, void* d_ws, size_t ws_size,
                              hipStream_t stream) {
  const float* z    = (const float*)d_in[0];
  const float* ps   = (const float*)d_in[1];
  const float* Wq   = (const float*)d_in[2];
  const float* bq   = (const float*)d_in[3];
  const float* Wk   = (const float*)d_in[4];
  const float* bk   = (const float*)d_in[5];
  const float* Wv   = (const float*)d_in[6];
  const float* bv   = (const float*)d_in[7];
  const float* Wc   = (const float*)d_in[8];
  const float* gamma= (const float*)d_in[9];
  const float* Wg1  = (const float*)d_in[10];
  const float* bg1  = (const float*)d_in[11];
  const float* Wg2  = (const float*)d_in[12];
  const float* bg2  = (const float*)d_in[13];

  char* w = (char*)d_ws;
  auto alloc = [&](long bytes) { void* p = (void*)w; w += (bytes + 255) & ~255L; return p; };
  short* zb   = (short*)alloc(BLD * 2);
  short* pb   = (short*)alloc(BLD * 2);
  short* Wqb  = (short*)alloc((long)Dn * Dn * 2);
  short* Wkb  = (short*)alloc((long)Dn * Dn * 2);
  short* Wvb  = (short*)alloc((long)Dn * Dn * 2);
  short* Wcb  = (short*)alloc((long)Dn * Dn * 2);
  short* Wg1b = (short*)alloc((long)HGn * Dn * 2);
  short* Qp   = (short*)alloc(BLD * 2);
  short* Kp   = (short*)alloc(BLD * 2);
  short* Vtb  = (short*)alloc(BLD * 2);   // V transposed: [b][h][d][L]
  short* Gk   = (short*)alloc(BLD * 2);
  float* Hf   = (float*)alloc((long)Bn * Ln * HGn * 4);
  float* gate = (float*)alloc((long)Bn * Ln * 4);
  float* ctf  = (float*)alloc((long)Ln * 512 * 4);
  float* stf  = (float*)alloc((long)Ln * 512 * 4);
  float* cts  = (float*)alloc((long)Ln * 512 * 4);
  float* sts  = (float*)alloc((long)Ln * 512 * 4);
  float* zv   = (float*)alloc((long)Bn * NH * Ln * 4);

  float* outp = (float*)d_out;
  float* aw   = outp + BLD;   // attn_w region; doubles as gb scratch before pass 2

  // 1) casts to bf16
  k_cast<<<(int)(BLD / 4 / 256), 256, 0, stream>>>(z,  zb, (int)BLD);
  k_cast<<<(int)(BLD / 4 / 256), 256, 0, stream>>>(ps, pb, (int)BLD);
  k_cast<<<Dn * Dn / 4 / 256, 256, 0, stream>>>(Wq, Wqb, Dn * Dn);
  k_cast<<<Dn * Dn / 4 / 256, 256, 0, stream>>>(Wk, Wkb, Dn * Dn);
  k_cast<<<Dn * Dn / 4 / 256, 256, 0, stream>>>(Wv, Wvb, Dn * Dn);
  k_cast<<<Dn * Dn / 4 / 256, 256, 0, stream>>>(Wc, Wcb, Dn * Dn);
  k_cast<<<HGn * Dn / 4 / 256, 256, 0, stream>>>(Wg1, Wg1b, HGn * Dn);

  // 2) projections (M=4096): Q,K (bias), V (bias, transposed out), gk, h (bias+gelu)
  dim3 pg(Dn / 128, (Bn * Ln) / 128, 1);
  k_gemm<true,  false, true,  false, false, false><<<pg, 256, 0, stream>>>(zb, Wqb, bq, nullptr, Qp, Dn, Dn, 0, 0, 0);
  k_gemm<true,  false, true,  false, false, false><<<pg, 256, 0, stream>>>(zb, Wkb, bk, nullptr, Kp, Dn, Dn, 0, 0, 0);
  k_gemm<true,  false, true,  false, false, true ><<<pg, 256, 0, stream>>>(zb, Wvb, bv, nullptr, Vtb, Dn, Dn, 0, 0, 0);
  k_gemm<false, false, true,  false, false, false><<<pg, 256, 0, stream>>>(pb, Wcb, nullptr, nullptr, Gk, Dn, Dn, 0, 0, 0);
  dim3 hg(HGn / 128, (Bn * Ln) / 128, 1);
  k_gemm<true,  true,  false, false, false, false><<<hg, 256, 0, stream>>>(pb, Wg1b, bg1, nullptr, Hf, HGn, Dn, 0, 0, 0);

  // 3) gb = tanh(gamma)/32 * gk . K_raw^T  (written into attn_w region, causal blocks only)
  dim3 gbg(Ln / 128, Ln / 128, Bn);
  k_gemm<false, false, false, true,  true , false><<<gbg, 256, 0, stream>>>(Gk, Kp, nullptr, gamma, aw, Ln, Dn,
                                                                            (long)Ln * Dn, (long)Ln * Dn, (long)Ln * Ln);

  // 4) RoPE tables, gate, in-place rotation of Q/K (K raw already consumed by gb)
  k_rope_tables<<<(Ln * 512) / 256, 256, 0, stream>>>(ctf, stf, cts, sts);
  k_gate<<<(Bn * Ln) / 4, 256, 0, stream>>>(Hf, Wg2, bg2, gate);
  k_rope<<<Bn * Ln, 256, 0, stream>>>(Qp, Kp, gate, ctf, stf, cts, sts);

  // 5) attention
  k_fill_upper<<<dim3(Ln, Bn), 256, 0, stream>>>(aw);
  k_attn1<<<1024, 256, 0, stream>>>(Qp, Kp, Vtb, aw, outp, zv);
  k_attn2<<<dim3(32 * 33 / 2, Bn), 256, 0, stream>>>(Qp, Kp, aw, zv, aw);
}

// Round 5
// 335.024 us; speedup vs baseline: 2.0596x; 1.2102x over previous
//
#include <hip/hip_runtime.h>
#include <hip/hip_bf16.h>

// Problem constants (B=2, L=2048, D=1024, NH=16, HD=64, H_GATE=256)
constexpr int Bn  = 2;
constexpr int Ln  = 2048;
constexpr int Dn  = 1024;
constexpr int NH  = 16;
constexpr int HGn = 256;
constexpr long BLD = (long)Bn * Ln * Dn;   // 4194304

typedef float f32x4 __attribute__((ext_vector_type(4)));
typedef float f32x2 __attribute__((ext_vector_type(2)));
typedef short s16x8 __attribute__((ext_vector_type(8)));
typedef short s16x4 __attribute__((ext_vector_type(4)));
typedef short s16x2 __attribute__((ext_vector_type(2)));

#define DEVI static __device__ __forceinline__

DEVI float bf2f(short u) {
  union { float f; unsigned int i; } v; v.i = ((unsigned int)(unsigned short)u) << 16; return v.f;
}
DEVI short f2bf(float f) {
  union { float f; unsigned int i; } v; v.f = f;
  unsigned int r = v.i + 0x7FFFu + ((v.i >> 16) & 1u);
  return (short)(r >> 16);
}
DEVI void gl_lds16(const void* g, void* l) {
  __builtin_amdgcn_global_load_lds((const __attribute__((address_space(1))) unsigned int*)g,
                                   (__attribute__((address_space(3))) unsigned int*)l, 16, 0, 0);
}

// ---------------- cast f32 -> bf16 ----------------
__global__ void k_cast(const float* __restrict__ s, short* __restrict__ d, int n) {
  int i = (blockIdx.x * 256 + threadIdx.x) * 4;
  if (i >= n) return;
  f32x4 v = *(const f32x4*)(s + i);
  s16x4 o; o[0] = f2bf(v[0]); o[1] = f2bf(v[1]); o[2] = f2bf(v[2]); o[3] = f2bf(v[3]);
  *(s16x4*)(d + i) = o;
}

// ---------------- GEMM: C[m,n] = act(alpha * sum_k A[m,k]*B[n,k] + bias[n]) ----------------
template<bool HAS_BIAS, bool GELU, bool OUT_BF16, bool CAUSAL, bool SCALE, bool OUT_VT>
__global__ __launch_bounds__(256)
void k_gemm(const short* __restrict__ A, const short* __restrict__ B,
            const float* __restrict__ bias, const float* __restrict__ gamma,
            void* __restrict__ C, int N, int K, long sA, long sB, long sC) {
  int bz = blockIdx.z;
  const short* Ap = A + (long)bz * sA;
  const short* Bp = B + (long)bz * sB;
  int m0 = blockIdx.y * 128, n0 = blockIdx.x * 128;
  if (CAUSAL && n0 > m0 + 127) return;   // whole tile above diagonal: never read
  __shared__ short smA[128 * 32];
  __shared__ short smB[128 * 32];
  int tid = threadIdx.x;
  int lane = tid & 63, wid = tid >> 6;
  int wr = wid >> 1, wc = wid & 1;
  int lr = lane & 15, lg = lane >> 4;
  int r_in = lane >> 2, c_in = (lane & 3) * 8;
  f32x4 acc[4][4] = {};
  for (int k0 = 0; k0 < K; k0 += 32) {
#pragma unroll
    for (int i = 0; i < 2; ++i) {
      int row = wid * 32 + i * 16 + r_in;
      gl_lds16(Ap + (long)(m0 + row) * K + k0 + c_in, smA + row * 32 + c_in);
      gl_lds16(Bp + (long)(n0 + row) * K + k0 + c_in, smB + row * 32 + c_in);
    }
    __syncthreads();
    s16x8 af[4], bf[4];
#pragma unroll
    for (int m = 0; m < 4; m++) af[m] = *(const s16x8*)(smA + (wr * 64 + m * 16 + lr) * 32 + lg * 8);
#pragma unroll
    for (int n = 0; n < 4; n++) bf[n] = *(const s16x8*)(smB + (wc * 64 + n * 16 + lr) * 32 + lg * 8);
#pragma unroll
    for (int m = 0; m < 4; m++)
#pragma unroll
      for (int n = 0; n < 4; n++)
        acc[m][n] = __builtin_amdgcn_mfma_f32_16x16x32_bf16(af[m], bf[n], acc[m][n], 0, 0, 0);
    __syncthreads();
  }
  float alpha = 1.0f;
  if (SCALE) alpha = tanhf(gamma[0]) * 0.03125f;   // tanh(gamma) * d^-0.5
#pragma unroll
  for (int n = 0; n < 4; n++) {
    int col = n0 + wc * 64 + n * 16 + lr;
    float bv = HAS_BIAS ? bias[col] : 0.0f;
#pragma unroll
    for (int m = 0; m < 4; m++) {
#pragma unroll
      for (int r = 0; r < 4; r++) {
        long row = m0 + wr * 64 + m * 16 + lg * 4 + r;
        float v = acc[m][n][r] * alpha + bv;
        if (GELU) v = 0.5f * v * (1.0f + erff(v * 0.70710678118f));
        if (OUT_VT) {
          long off = (((row >> 11) * (long)NH + (col >> 6)) * 64 + (col & 63)) * Ln + (row & (Ln - 1));
          ((short*)C)[off] = f2bf(v);
        } else {
          long off = (long)bz * sC + row * (long)N + col;
          if (OUT_BF16) ((short*)C)[off] = f2bf(v);
          else          ((float*)C)[off] = v;
        }
      }
    }
  }
}

// ---------------- RoPE cos/sin tables: [L][512] for both bases ----------------
__global__ void k_rope_tables(float* __restrict__ ctf, float* __restrict__ stf,
                              float* __restrict__ cts, float* __restrict__ sts) {
  int idx = blockIdx.x * 256 + threadIdx.x;   // L*512 total
  int l = idx >> 9, j = idx & 511;
  float e = (float)j * (1.0f / 512.0f);
  float invf = powf(1.6180339887498949f, -e);
  float invs = powf(1618.0f, -e);
  float af = (float)l * invf, as = (float)l * invs;
  float sf, cf, ss, cs;
  sincosf(af, &sf, &cf);
  sincosf(as, &ss, &cs);
  ctf[idx] = cf; stf[idx] = sf; cts[idx] = cs; sts[idx] = ss;
}

// ---------------- gate = sigmoid(h . Wg2 + bg2), one wave per row ----------------
__global__ void k_gate(const float* __restrict__ Hf, const float* __restrict__ Wg2,
                       const float* __restrict__ bg2, float* __restrict__ gate) {
  int lane = threadIdx.x & 63, wid = threadIdx.x >> 6;
  int row = blockIdx.x * 4 + wid;
  f32x4 h = *(const f32x4*)(Hf + (long)row * HGn + lane * 4);
  f32x4 w = *(const f32x4*)(Wg2 + lane * 4);
  float s = h[0] * w[0] + h[1] * w[1] + h[2] * w[2] + h[3] * w[3];
#pragma unroll
  for (int m = 1; m < 64; m <<= 1) s += __shfl_xor(s, m);
  if (lane == 0) gate[row] = 1.0f / (1.0f + __expf(-(s + bg2[0])));
}

// ---------------- RoPE apply (in place, Q and K), one block per (b,l) ----------------
__global__ void k_rope(short* __restrict__ Q, short* __restrict__ Kx,
                       const float* __restrict__ gate,
                       const float* __restrict__ ctf, const float* __restrict__ stf,
                       const float* __restrict__ cts, const float* __restrict__ sts) {
  int bl = blockIdx.x;
  int l = bl & (Ln - 1);
  int t = threadIdx.x;
  float g = gate[bl];
  int j = t * 2;
  f32x2 vcf = *(const f32x2*)(ctf + l * 512 + j);
  f32x2 vsf = *(const f32x2*)(stf + l * 512 + j);
  f32x2 vcs = *(const f32x2*)(cts + l * 512 + j);
  f32x2 vss = *(const f32x2*)(sts + l * 512 + j);
  float c0 = g * vcf[0] + (1.f - g) * vcs[0];
  float c1 = g * vcf[1] + (1.f - g) * vcs[1];
  float s0 = g * vsf[0] + (1.f - g) * vss[0];
  float s1 = g * vsf[1] + (1.f - g) * vss[1];
  long base = (long)bl * Dn + j;
  {
    s16x2 xa = *(const s16x2*)(Q + base);
    s16x2 xb = *(const s16x2*)(Q + base + 512);
    float a0 = bf2f(xa[0]), a1 = bf2f(xa[1]), b0 = bf2f(xb[0]), b1 = bf2f(xb[1]);
    s16x2 o0, o1;
    o0[0] = f2bf(a0 * c0 - b0 * s0); o0[1] = f2bf(a1 * c1 - b1 * s1);
    o1[0] = f2bf(b0 * c0 + a0 * s0); o1[1] = f2bf(b1 * c1 + a1 * s1);
    *(s16x2*)(Q + base) = o0;
    *(s16x2*)(Q + base + 512) = o1;
  }
  {
    s16x2 xa = *(const s16x2*)(Kx + base);
    s16x2 xb = *(const s16x2*)(Kx + base + 512);
    float a0 = bf2f(xa[0]), a1 = bf2f(xa[1]), b0 = bf2f(xb[0]), b1 = bf2f(xb[1]);
    s16x2 o0, o1;
    o0[0] = f2bf(a0 * c0 - b0 * s0); o0[1] = f2bf(a1 * c1 - b1 * s1);
    o1[0] = f2bf(b0 * c0 + a0 * s0); o1[1] = f2bf(b1 * c1 + a1 * s1);
    *(s16x2*)(Kx + base) = o0;
    *(s16x2*)(Kx + base + 512) = o1;
  }
}

// ---------------- zero the strict upper triangle of attn_w ----------------
__global__ void k_fill_upper(float* __restrict__ aw) {
  int q = blockIdx.x, b = blockIdx.y;
  float* row = aw + ((long)b * Ln + q) * Ln;
  for (int k = q + 1 + threadIdx.x; k < Ln; k += 256) row[k] = 0.0f;
}

// ---------------- attention pass 1: balanced 1-D grid, double-buffered pipeline ----------------
__global__ __launch_bounds__(256)
void k_attn1(const short* __restrict__ Q, const short* __restrict__ Kx,
             const short* __restrict__ Vt, const float* __restrict__ gb,
             float* __restrict__ outp, float* __restrict__ zinv) {
  int lin = blockIdx.x;
  int u2 = ((lin & 3) + (lin >> 8)) & 3;
  int w5 = (lin >> 2) & 31;
  int w2 = (w5 + ((u2 >> 1) << 4)) & 31;
  int qb = (u2 & 1) ? (31 - w2) : w2;
  int hb = (((lin >> 7) & 7) << 2) | (lin & 3);
  int h = hb & 15, b = hb >> 4;

  int tid = threadIdx.x;
  int lane = tid & 63, w = tid >> 6;
  int lr = lane & 15, lg = lane >> 4;
  int q0w = qb * 64 + w * 16;
  __shared__ short smK[2][64 * 64];
  __shared__ short smV[2][64 * 64];
  __shared__ short smP[4 * 16 * 64];
  short* pw = smP + w * 1024;

  const short* qbp = Q + ((long)(b * Ln) + q0w + lr) * Dn + h * 64 + lg * 8;
  s16x8 qf0 = *(const s16x8*)(qbp);
  s16x8 qf1 = *(const s16x8*)(qbp + 32);
  f32x4 acc[4] = {};
  float az[4] = {0.f, 0.f, 0.f, 0.f};

  int r0 = w * 16 + (lane >> 3);                 // staged row in tile (0..63)
  int scol = ((lane & 7) ^ (lane >> 3)) * 8;     // pre-swizzled source col (elems)
  const short* Kg = Kx + (long)(b * Ln) * Dn + h * 64;
  const short* Vg = Vt + (long)(b * NH + h) * 64 * Ln;
  int sw = (lr & 7) << 3;                        // read-side XOR (elems)
  const float* gbase = gb + ((long)b * Ln + q0w + lg * 4) * Ln + lr;

  int nt = qb + 1;
  auto stage = [&](int buf, int t) {
    long k0 = (long)t * 64;
    short* bK = &smK[buf][w * 1024];
    short* bV = &smV[buf][w * 1024];
    gl_lds16(Kg + (k0 + r0) * Dn + scol,           bK);
    gl_lds16(Kg + (k0 + r0 + 8) * Dn + scol,       bK + 512);
    gl_lds16(Vg + (long)r0 * Ln + k0 + scol,       bV);
    gl_lds16(Vg + (long)(r0 + 8) * Ln + k0 + scol, bV + 512);
  };

  float gcur[4][4], gnxt[4][4];
  stage(0, 0);
  {
    const float* g0 = gbase;
#pragma unroll
    for (int kk = 0; kk < 4; ++kk)
#pragma unroll
      for (int r = 0; r < 4; ++r) gcur[kk][r] = g0[(long)r * Ln + kk * 16];
  }
  int cur = 0;
  for (int t = 0; t < nt; ++t) {
    bool pre = (t + 1 < nt);
    if (pre) {
      const float* g0 = gbase + (t + 1) * 64;
#pragma unroll
      for (int kk = 0; kk < 4; ++kk)
#pragma unroll
        for (int r = 0; r < 4; ++r) gnxt[kk][r] = g0[(long)r * Ln + kk * 16];
      stage(cur ^ 1, t + 1);
    }
    __builtin_amdgcn_sched_barrier(0);
    if (pre) asm volatile("s_waitcnt vmcnt(20)" ::: "memory");
    else     asm volatile("s_waitcnt vmcnt(0)" ::: "memory");
    __builtin_amdgcn_s_barrier();
    __builtin_amdgcn_sched_barrier(0);
    int k0 = t * 64;
    const short* Kc = smK[cur];
    const short* Vc = smV[cur];
    // ---- QK^T + exp into smP ----
#pragma unroll
    for (int kk = 0; kk < 4; ++kk) {
      const short* kr = Kc + (kk * 16 + lr) * 64;
      s16x8 kf0 = *(const s16x8*)(kr + ((lg * 8) ^ sw));
      s16x8 kf1 = *(const s16x8*)(kr + ((32 + lg * 8) ^ sw));
      f32x4 S = {};
      S = __builtin_amdgcn_mfma_f32_16x16x32_bf16(qf0, kf0, S, 0, 0, 0);
      S = __builtin_amdgcn_mfma_f32_16x16x32_bf16(qf1, kf1, S, 0, 0, 0);
      int k = k0 + kk * 16 + lr;
#pragma unroll
      for (int r = 0; r < 4; r++) {
        int q = q0w + lg * 4 + r;
        float arg = (k <= q) ? (S[r] * 0.125f + gcur[kk][r]) : -80.0f;
        float p = __expf(arg);
        az[r] += p;
        int qq = lg * 4 + r;
        pw[qq * 64 + ((kk * 16 + lr) ^ ((qq & 7) << 3))] = f2bf(p);
      }
    }
    // ---- P @ V ----
#pragma unroll
    for (int c = 0; c < 2; ++c) {
      s16x8 pf = *(const s16x8*)(pw + lr * 64 + ((c * 32 + lg * 8) ^ sw));
#pragma unroll
      for (int n = 0; n < 4; n++) {
        s16x8 vf = *(const s16x8*)(Vc + (n * 16 + lr) * 64 + ((c * 32 + lg * 8) ^ sw));
        acc[n] = __builtin_amdgcn_mfma_f32_16x16x32_bf16(pf, vf, acc[n], 0, 0, 0);
      }
    }
    __builtin_amdgcn_s_barrier();
    if (pre) {
#pragma unroll
      for (int kk = 0; kk < 4; ++kk)
#pragma unroll
        for (int r = 0; r < 4; ++r) gcur[kk][r] = gnxt[kk][r];
    }
    cur ^= 1;
  }
#pragma unroll
  for (int r = 0; r < 4; r++) {
    float z = az[r];
    z += __shfl_xor(z, 1); z += __shfl_xor(z, 2); z += __shfl_xor(z, 4); z += __shfl_xor(z, 8);
    az[r] = 1.0f / z;
  }
  if (lr == 0) {
#pragma unroll
    for (int r = 0; r < 4; r++)
      zinv[((long)(b * NH + h)) * Ln + q0w + lg * 4 + r] = az[r];
  }
#pragma unroll
  for (int n = 0; n < 4; n++) {
#pragma unroll
    for (int r = 0; r < 4; r++) {
      int q = q0w + lg * 4 + r;
      outp[((long)(b * Ln) + q) * Dn + h * 64 + n * 16 + lr] = acc[n][r] * az[r];
    }
  }
}

// ---------------- attention pass 2: attn_w = mean_h softmax over 64x64 causal tiles ----------------
// LDS-staged Q/K tiles per head, double-buffered across heads, counted vmcnt (never 0 mid-loop).
__global__ __launch_bounds__(256)
void k_attn2(const short* __restrict__ Qm, const short* __restrict__ Kx,
             const float* gb, const float* __restrict__ zinv, float* aw) {
  int b = blockIdx.y;
  int t = blockIdx.x;
  int qb = (int)((sqrtf(8.0f * (float)t + 1.0f) - 1.0f) * 0.5f);
  while ((qb + 1) * (qb + 2) / 2 <= t) ++qb;
  while (qb * (qb + 1) / 2 > t) --qb;
  int kb = t - qb * (qb + 1) / 2;
  int q0 = qb * 64, k0 = kb * 64;
  int tid = threadIdx.x, lane = tid & 63, w = tid >> 6;
  int lr = lane & 15, lg = lane >> 4;
  int q0w = q0 + w * 16;
  bool diag = (qb == kb);
  __shared__ short smK[2][64 * 64];
  __shared__ short smQ[2][64 * 64];
  __shared__ float smZ[NH * 64];
  for (int i = tid; i < NH * 64; i += 256) {
    int h = i >> 6, qq = i & 63;
    smZ[i] = zinv[((long)(b * NH + h)) * Ln + q0 + qq];
  }
  __syncthreads();
  // bias tile in regs (masked region of gb holds finite garbage; write is masked)
  float gv[4][4];
#pragma unroll
  for (int n = 0; n < 4; n++) {
    int k = k0 + n * 16 + lr;
#pragma unroll
    for (int r = 0; r < 4; r++)
      gv[n][r] = gb[((long)b * Ln + q0w + lg * 4 + r) * Ln + k];
  }
  int r0 = w * 16 + (lane >> 3);
  int scol = ((lane & 7) ^ (lane >> 3)) * 8;
  int sw = (lr & 7) << 3;
  auto stage = [&](int buf, int h) {
    short* bK = &smK[buf][w * 1024];
    short* bQ = &smQ[buf][w * 1024];
    const short* Kg = Kx + ((long)(b * Ln) + k0 + r0) * Dn + h * 64 + scol;
    gl_lds16(Kg, bK);
    gl_lds16(Kg + 8 * Dn, bK + 512);
    const short* Qg = Qm + ((long)(b * Ln) + q0 + r0) * Dn + h * 64 + scol;
    gl_lds16(Qg, bQ);
    gl_lds16(Qg + 8 * Dn, bQ + 512);
  };
  float wa[4][4] = {{0.f}};
  stage(0, 0);
  int cur = 0;
  for (int h = 0; h < NH; ++h) {
    bool pre = (h + 1 < NH);
    if (pre) stage(cur ^ 1, h + 1);
    __builtin_amdgcn_sched_barrier(0);
    if (pre) asm volatile("s_waitcnt vmcnt(4)" ::: "memory");
    else     asm volatile("s_waitcnt vmcnt(0)" ::: "memory");
    __builtin_amdgcn_s_barrier();
    __builtin_amdgcn_sched_barrier(0);
    const short* Kc = smK[cur];
    const short* Qc = smQ[cur];
    s16x8 qf0 = *(const s16x8*)(Qc + (w * 16 + lr) * 64 + ((lg * 8) ^ sw));
    s16x8 qf1 = *(const s16x8*)(Qc + (w * 16 + lr) * 64 + ((32 + lg * 8) ^ sw));
    float zq[4];
#pragma unroll
    for (int r = 0; r < 4; r++) zq[r] = smZ[h * 64 + w * 16 + lg * 4 + r];
#pragma unroll
    for (int n = 0; n < 4; n++) {
      const short* kr = Kc + (n * 16 + lr) * 64;
      s16x8 kf0 = *(const s16x8*)(kr + ((lg * 8) ^ sw));
      s16x8 kf1 = *(const s16x8*)(kr + ((32 + lg * 8) ^ sw));
      f32x4 S = {};
      S = __builtin_amdgcn_mfma_f32_16x16x32_bf16(qf0, kf0, S, 0, 0, 0);
      S = __builtin_amdgcn_mfma_f32_16x16x32_bf16(qf1, kf1, S, 0, 0, 0);
#pragma unroll
      for (int r = 0; r < 4; r++)
        wa[n][r] += __expf(S[r] * 0.125f + gv[n][r]) * zq[r];
    }
    __builtin_amdgcn_s_barrier();
    cur ^= 1;
  }
#pragma unroll
  for (int n = 0; n < 4; n++) {
    int k = k0 + n * 16 + lr;
#pragma unroll
    for (int r = 0; r < 4; r++) {
      int q = q0w + lg * 4 + r;
      float v = wa[n][r] * (1.0f / 16.0f);
      if (diag && k > q) v = 0.0f;
      aw[((long)b * Ln + q) * Ln + k] = v;
    }
  }
}

extern "C" void kernel_launch(void* const* d_in, const int* in_sizes, int n_in,
                              void* d_out, int out_size, void* d_ws, size_t ws_size,
                              hipStream_t stream) {
  const float* z    = (const float*)d_in[0];
  const float* ps   = (const float*)d_in[1];
  const float* Wq   = (const float*)d_in[2];
  const float* bq   = (const float*)d_in[3];
  const float* Wk   = (const float*)d_in[4];
  const float* bk   = (const float*)d_in[5];
  const float* Wv   = (const float*)d_in[6];
  const float* bv   = (const float*)d_in[7];
  const float* Wc   = (const float*)d_in[8];
  const float* gamma= (const float*)d_in[9];
  const float* Wg1  = (const float*)d_in[10];
  const float* bg1  = (const float*)d_in[11];
  const float* Wg2  = (const float*)d_in[12];
  const float* bg2  = (const float*)d_in[13];

  char* w = (char*)d_ws;
  auto alloc = [&](long bytes) { void* p = (void*)w; w += (bytes + 255) & ~255L; return p; };
  short* zb   = (short*)alloc(BLD * 2);
  short* pb   = (short*)alloc(BLD * 2);
  short* Wqb  = (short*)alloc((long)Dn * Dn * 2);
  short* Wkb  = (short*)alloc((long)Dn * Dn * 2);
  short* Wvb  = (short*)alloc((long)Dn * Dn * 2);
  short* Wcb  = (short*)alloc((long)Dn * Dn * 2);
  short* Wg1b = (short*)alloc((long)HGn * Dn * 2);
  short* Qp   = (short*)alloc(BLD * 2);
  short* Kp   = (short*)alloc(BLD * 2);
  short* Vtb  = (short*)alloc(BLD * 2);   // V transposed: [b][h][d][L]
  short* Gk   = (short*)alloc(BLD * 2);
  float* Hf   = (float*)alloc((long)Bn * Ln * HGn * 4);
  float* gate = (float*)alloc((long)Bn * Ln * 4);
  float* ctf  = (float*)alloc((long)Ln * 512 * 4);
  float* stf  = (float*)alloc((long)Ln * 512 * 4);
  float* cts  = (float*)alloc((long)Ln * 512 * 4);
  float* sts  = (float*)alloc((long)Ln * 512 * 4);
  float* zv   = (float*)alloc((long)Bn * NH * Ln * 4);

  float* outp = (float*)d_out;
  float* aw   = outp + BLD;   // attn_w region; doubles as gb scratch before pass 2

  // 1) casts to bf16
  k_cast<<<(int)(BLD / 4 / 256), 256, 0, stream>>>(z,  zb, (int)BLD);
  k_cast<<<(int)(BLD / 4 / 256), 256, 0, stream>>>(ps, pb, (int)BLD);
  k_cast<<<Dn * Dn / 4 / 256, 256, 0, stream>>>(Wq, Wqb, Dn * Dn);
  k_cast<<<Dn * Dn / 4 / 256, 256, 0, stream>>>(Wk, Wkb, Dn * Dn);
  k_cast<<<Dn * Dn / 4 / 256, 256, 0, stream>>>(Wv, Wvb, Dn * Dn);
  k_cast<<<Dn * Dn / 4 / 256, 256, 0, stream>>>(Wc, Wcb, Dn * Dn);
  k_cast<<<HGn * Dn / 4 / 256, 256, 0, stream>>>(Wg1, Wg1b, HGn * Dn);

  // 2) projections (M=4096): Q,K (bias), V (bias, transposed out), gk, h (bias+gelu)
  dim3 pg(Dn / 128, (Bn * Ln) / 128, 1);
  k_gemm<true,  false, true,  false, false, false><<<pg, 256, 0, stream>>>(zb, Wqb, bq, nullptr, Qp, Dn, Dn, 0, 0, 0);
  k_gemm<true,  false, true,  false, false, false><<<pg, 256, 0, stream>>>(zb, Wkb, bk, nullptr, Kp, Dn, Dn, 0, 0, 0);
  k_gemm<true,  false, true,  false, false, true ><<<pg, 256, 0, stream>>>(zb, Wvb, bv, nullptr, Vtb, Dn, Dn, 0, 0, 0);
  k_gemm<false, false, true,  false, false, false><<<pg, 256, 0, stream>>>(pb, Wcb, nullptr, nullptr, Gk, Dn, Dn, 0, 0, 0);
  dim3 hg(HGn / 128, (Bn * Ln) / 128, 1);
  k_gemm<true,  true,  false, false, false, false><<<hg, 256, 0, stream>>>(pb, Wg1b, bg1, nullptr, Hf, HGn, Dn, 0, 0, 0);

  // 3) gb = tanh(gamma)/32 * gk . K_raw^T  (written into attn_w region, causal blocks only)
  dim3 gbg(Ln / 128, Ln / 128, Bn);
  k_gemm<false, false, false, true,  true , false><<<gbg, 256, 0, stream>>>(Gk, Kp, nullptr, gamma, aw, Ln, Dn,
                                                                            (long)Ln * Dn, (long)Ln * Dn, (long)Ln * Ln);

  // 4) RoPE tables, gate, in-place rotation of Q/K (K raw already consumed by gb)
  k_rope_tables<<<(Ln * 512) / 256, 256, 0, stream>>>(ctf, stf, cts, sts);
  k_gate<<<(Bn * Ln) / 4, 256, 0, stream>>>(Hf, Wg2, bg2, gate);
  k_rope<<<Bn * Ln, 256, 0, stream>>>(Qp, Kp, gate, ctf, stf, cts, sts);

  // 5) attention
  k_fill_upper<<<dim3(Ln, Bn), 256, 0, stream>>>(aw);
  k_attn1<<<1024, 256, 0, stream>>>(Qp, Kp, Vtb, aw, outp, zv);
  k_attn2<<<dim3(32 * 33 / 2, Bn), 256, 0, stream>>>(Qp, Kp, aw, zv, aw);
}

// Round 6
// 251.482 us; speedup vs baseline: 2.7438x; 1.3322x over previous
//
#include <hip/hip_runtime.h>
#include <hip/hip_bf16.h>

// Problem constants (B=2, L=2048, D=1024, NH=16, HD=64, H_GATE=256)
constexpr int Bn  = 2;
constexpr int Ln  = 2048;
constexpr int Dn  = 1024;
constexpr int NH  = 16;
constexpr int HGn = 256;
constexpr long BLD = (long)Bn * Ln * Dn;   // 4194304

typedef float f32x4 __attribute__((ext_vector_type(4)));
typedef float f32x2 __attribute__((ext_vector_type(2)));
typedef short s16x8 __attribute__((ext_vector_type(8)));
typedef short s16x4 __attribute__((ext_vector_type(4)));
typedef short s16x2 __attribute__((ext_vector_type(2)));

#define DEVI static __device__ __forceinline__

DEVI float bf2f(short u) {
  union { float f; unsigned int i; } v; v.i = ((unsigned int)(unsigned short)u) << 16; return v.f;
}
DEVI short f2bf(float f) {
  union { float f; unsigned int i; } v; v.f = f;
  unsigned int r = v.i + 0x7FFFu + ((v.i >> 16) & 1u);
  return (short)(r >> 16);
}
DEVI void gl_lds16(const void* g, void* l) {
  __builtin_amdgcn_global_load_lds((const __attribute__((address_space(1))) unsigned int*)g,
                                   (__attribute__((address_space(3))) unsigned int*)l, 16, 0, 0);
}

// ---------------- fused 7-segment cast f32 -> bf16 (dst segments contiguous) ----------------
struct CastDesc { const float* src[7]; long cum[8]; };
__global__ void k_cast7(CastDesc d, short* __restrict__ dst) {
  long gi = ((long)blockIdx.x * 256 + threadIdx.x) * 4;
  int s = 0;
#pragma unroll
  for (int i = 1; i < 7; ++i) if (gi >= d.cum[i]) s = i;
  const float* sp = d.src[s] + (gi - d.cum[s]);
  f32x4 v = *(const f32x4*)sp;
  s16x4 o; o[0] = f2bf(v[0]); o[1] = f2bf(v[1]); o[2] = f2bf(v[2]); o[3] = f2bf(v[3]);
  *(s16x4*)(dst + gi) = o;
}

// ---------------- merged projection GEMM: [Q|K|V|gk|h] = [z|z|z|ps|ps] @ Wcat^T ----------------
// Wcat rows: [0,1024)=Wq [1024,2048)=Wk [2048,3072)=Wv [3072,4096)=Wc [4096,4352)=Wg1
__global__ __launch_bounds__(256)
void k_gemm_mega(const short* __restrict__ zb, const short* __restrict__ pb,
                 const short* __restrict__ Wcat,
                 const float* __restrict__ bq, const float* __restrict__ bk,
                 const float* __restrict__ bv, const float* __restrict__ bg1,
                 short* __restrict__ Qp, short* __restrict__ Kp,
                 short* __restrict__ Vtb, short* __restrict__ Gk,
                 float* __restrict__ Hf) {
  int m0 = blockIdx.y * 128, n0 = blockIdx.x * 128;
  const short* Ap = (n0 < 3072) ? zb : pb;
  __shared__ short smA[128 * 32];
  __shared__ short smB[128 * 32];
  int tid = threadIdx.x;
  int lane = tid & 63, wid = tid >> 6;
  int wr = wid >> 1, wc = wid & 1;
  int lr = lane & 15, lg = lane >> 4;
  int r_in = lane >> 2, c_in = (lane & 3) * 8;
  f32x4 acc[4][4] = {};
  for (int k0 = 0; k0 < Dn; k0 += 32) {
#pragma unroll
    for (int i = 0; i < 2; ++i) {
      int row = wid * 32 + i * 16 + r_in;
      gl_lds16(Ap + (long)(m0 + row) * Dn + k0 + c_in, smA + row * 32 + c_in);
      gl_lds16(Wcat + (long)(n0 + row) * Dn + k0 + c_in, smB + row * 32 + c_in);
    }
    __syncthreads();
    s16x8 af[4], bf[4];
#pragma unroll
    for (int m = 0; m < 4; m++) af[m] = *(const s16x8*)(smA + (wr * 64 + m * 16 + lr) * 32 + lg * 8);
#pragma unroll
    for (int n = 0; n < 4; n++) bf[n] = *(const s16x8*)(smB + (wc * 64 + n * 16 + lr) * 32 + lg * 8);
#pragma unroll
    for (int m = 0; m < 4; m++)
#pragma unroll
      for (int n = 0; n < 4; n++)
        acc[m][n] = __builtin_amdgcn_mfma_f32_16x16x32_bf16(af[m], bf[n], acc[m][n], 0, 0, 0);
    __syncthreads();
  }
  int slice = n0 >> 10;   // 0..4 (4352 cols)
#pragma unroll
  for (int n = 0; n < 4; n++) {
    int col = n0 + wc * 64 + n * 16 + lr;
    int c = col - (slice << 10);
    float bias = (slice == 0) ? bq[c] : (slice == 1) ? bk[c] : (slice == 2) ? bv[c]
               : (slice == 3) ? 0.0f : bg1[c];
#pragma unroll
    for (int m = 0; m < 4; m++) {
#pragma unroll
      for (int r = 0; r < 4; r++) {
        long row = m0 + wr * 64 + m * 16 + lg * 4 + r;
        float v = acc[m][n][r] + bias;
        if (slice == 4) {
          v = 0.5f * v * (1.0f + erff(v * 0.70710678118f));
          Hf[row * HGn + c] = v;
        } else if (slice == 2) {
          long off = (((row >> 11) * (long)NH + (c >> 6)) * 64 + (c & 63)) * Ln + (row & (Ln - 1));
          Vtb[off] = f2bf(v);
        } else {
          short* dst = (slice == 0) ? Qp : (slice == 1) ? Kp : Gk;
          dst[row * (long)Dn + c] = f2bf(v);
        }
      }
    }
  }
}

// ---------------- gb GEMM: Gb[b,q,k] = bf16( tanh(gamma)/32 * gk[q].K_raw[k] ), causal tiles ----------------
__global__ __launch_bounds__(256)
void k_gemm_gb(const short* __restrict__ A, const short* __restrict__ B,
               const float* __restrict__ gamma, short* __restrict__ C) {
  int bz = blockIdx.z;
  const short* Ap = A + (long)bz * Ln * Dn;
  const short* Bp = B + (long)bz * Ln * Dn;
  int m0 = blockIdx.y * 128, n0 = blockIdx.x * 128;
  if (n0 > m0 + 127) return;
  __shared__ short smA[128 * 32];
  __shared__ short smB[128 * 32];
  int tid = threadIdx.x;
  int lane = tid & 63, wid = tid >> 6;
  int wr = wid >> 1, wc = wid & 1;
  int lr = lane & 15, lg = lane >> 4;
  int r_in = lane >> 2, c_in = (lane & 3) * 8;
  f32x4 acc[4][4] = {};
  for (int k0 = 0; k0 < Dn; k0 += 32) {
#pragma unroll
    for (int i = 0; i < 2; ++i) {
      int row = wid * 32 + i * 16 + r_in;
      gl_lds16(Ap + (long)(m0 + row) * Dn + k0 + c_in, smA + row * 32 + c_in);
      gl_lds16(Bp + (long)(n0 + row) * Dn + k0 + c_in, smB + row * 32 + c_in);
    }
    __syncthreads();
    s16x8 af[4], bf[4];
#pragma unroll
    for (int m = 0; m < 4; m++) af[m] = *(const s16x8*)(smA + (wr * 64 + m * 16 + lr) * 32 + lg * 8);
#pragma unroll
    for (int n = 0; n < 4; n++) bf[n] = *(const s16x8*)(smB + (wc * 64 + n * 16 + lr) * 32 + lg * 8);
#pragma unroll
    for (int m = 0; m < 4; m++)
#pragma unroll
      for (int n = 0; n < 4; n++)
        acc[m][n] = __builtin_amdgcn_mfma_f32_16x16x32_bf16(af[m], bf[n], acc[m][n], 0, 0, 0);
    __syncthreads();
  }
  float alpha = tanhf(gamma[0]) * 0.03125f;
#pragma unroll
  for (int n = 0; n < 4; n++) {
    int col = n0 + wc * 64 + n * 16 + lr;
#pragma unroll
    for (int m = 0; m < 4; m++) {
#pragma unroll
      for (int r = 0; r < 4; r++) {
        long row = m0 + wr * 64 + m * 16 + lg * 4 + r;
        C[(long)bz * Ln * Ln + row * Ln + col] = f2bf(acc[m][n][r] * alpha);
      }
    }
  }
}

// ---------------- RoPE cos/sin tables: [L][512] for both bases ----------------
__global__ void k_rope_tables(float* __restrict__ ctf, float* __restrict__ stf,
                              float* __restrict__ cts, float* __restrict__ sts) {
  int idx = blockIdx.x * 256 + threadIdx.x;   // L*512 total
  int l = idx >> 9, j = idx & 511;
  float e = (float)j * (1.0f / 512.0f);
  float invf = powf(1.6180339887498949f, -e);
  float invs = powf(1618.0f, -e);
  float af = (float)l * invf, as = (float)l * invs;
  float sf, cf, ss, cs;
  sincosf(af, &sf, &cf);
  sincosf(as, &ss, &cs);
  ctf[idx] = cf; stf[idx] = sf; cts[idx] = cs; sts[idx] = ss;
}

// ---------------- gate = sigmoid(h . Wg2 + bg2), one wave per row ----------------
__global__ void k_gate(const float* __restrict__ Hf, const float* __restrict__ Wg2,
                       const float* __restrict__ bg2, float* __restrict__ gate) {
  int lane = threadIdx.x & 63, wid = threadIdx.x >> 6;
  int row = blockIdx.x * 4 + wid;
  f32x4 h = *(const f32x4*)(Hf + (long)row * HGn + lane * 4);
  f32x4 w = *(const f32x4*)(Wg2 + lane * 4);
  float s = h[0] * w[0] + h[1] * w[1] + h[2] * w[2] + h[3] * w[3];
#pragma unroll
  for (int m = 1; m < 64; m <<= 1) s += __shfl_xor(s, m);
  if (lane == 0) gate[row] = 1.0f / (1.0f + __expf(-(s + bg2[0])));
}

// ---------------- RoPE apply (in place, Q and K), one block per (b,l) ----------------
__global__ void k_rope(short* __restrict__ Q, short* __restrict__ Kx,
                       const float* __restrict__ gate,
                       const float* __restrict__ ctf, const float* __restrict__ stf,
                       const float* __restrict__ cts, const float* __restrict__ sts) {
  int bl = blockIdx.x;
  int l = bl & (Ln - 1);
  int t = threadIdx.x;
  float g = gate[bl];
  int j = t * 2;
  f32x2 vcf = *(const f32x2*)(ctf + l * 512 + j);
  f32x2 vsf = *(const f32x2*)(stf + l * 512 + j);
  f32x2 vcs = *(const f32x2*)(cts + l * 512 + j);
  f32x2 vss = *(const f32x2*)(sts + l * 512 + j);
  float c0 = g * vcf[0] + (1.f - g) * vcs[0];
  float c1 = g * vcf[1] + (1.f - g) * vcs[1];
  float s0 = g * vsf[0] + (1.f - g) * vss[0];
  float s1 = g * vsf[1] + (1.f - g) * vss[1];
  long base = (long)bl * Dn + j;
  {
    s16x2 xa = *(const s16x2*)(Q + base);
    s16x2 xb = *(const s16x2*)(Q + base + 512);
    float a0 = bf2f(xa[0]), a1 = bf2f(xa[1]), b0 = bf2f(xb[0]), b1 = bf2f(xb[1]);
    s16x2 o0, o1;
    o0[0] = f2bf(a0 * c0 - b0 * s0); o0[1] = f2bf(a1 * c1 - b1 * s1);
    o1[0] = f2bf(b0 * c0 + a0 * s0); o1[1] = f2bf(b1 * c1 + a1 * s1);
    *(s16x2*)(Q + base) = o0;
    *(s16x2*)(Q + base + 512) = o1;
  }
  {
    s16x2 xa = *(const s16x2*)(Kx + base);
    s16x2 xb = *(const s16x2*)(Kx + base + 512);
    float a0 = bf2f(xa[0]), a1 = bf2f(xa[1]), b0 = bf2f(xb[0]), b1 = bf2f(xb[1]);
    s16x2 o0, o1;
    o0[0] = f2bf(a0 * c0 - b0 * s0); o0[1] = f2bf(a1 * c1 - b1 * s1);
    o1[0] = f2bf(b0 * c0 + a0 * s0); o1[1] = f2bf(b1 * c1 + a1 * s1);
    *(s16x2*)(Kx + base) = o0;
    *(s16x2*)(Kx + base + 512) = o1;
  }
}

// ---------------- attention pass 1: uniform-work pairs (qb, 31-qb), XCD-grouped ----------------
__global__ __launch_bounds__(256)
void k_attn1(const short* __restrict__ Q, const short* __restrict__ Kx,
             const short* __restrict__ Vt, const short* __restrict__ Gb,
             float* __restrict__ outp, float* __restrict__ zinv) {
  // wgid -> (b,h,pair) with same (b,h) on one XCD (wgid%8 = XCD model)
  int wg = blockIdx.x;              // 0..511
  int xcd = wg & 7, slot = wg >> 3; // slot 0..63
  int p = slot & 15, gh = slot >> 4;
  int g = gh * 8 + xcd;             // 0..31 (b,h) group
  int b = g >> 4, h = g & 15;

  int tid = threadIdx.x;
  int lane = tid & 63, w = tid >> 6;
  int lr = lane & 15, lg = lane >> 4;
  __shared__ short smK[2][64 * 64];
  __shared__ short smV[2][64 * 64];
  __shared__ short smP[4 * 16 * 64];
  short* pw = smP + w * 1024;

  int r0 = w * 16 + (lane >> 3);                 // staged row in tile (0..63)
  int scol = ((lane & 7) ^ (lane >> 3)) * 8;     // pre-swizzled source col (elems)
  const short* Kg = Kx + (long)(b * Ln) * Dn + h * 64;
  const short* Vg = Vt + (long)(b * NH + h) * 64 * Ln;
  int sw = (lr & 7) << 3;                        // read-side XOR (elems)

  for (int seg = 0; seg < 2; ++seg) {
    int qb = seg ? (31 - p) : p;
    int q0w = qb * 64 + w * 16;
    const short* qbp = Q + ((long)(b * Ln) + q0w + lr) * Dn + h * 64 + lg * 8;
    s16x8 qf0 = *(const s16x8*)(qbp);
    s16x8 qf1 = *(const s16x8*)(qbp + 32);
    f32x4 acc[4] = {};
    float az[4] = {0.f, 0.f, 0.f, 0.f};
    const short* gbase = Gb + ((long)b * Ln + q0w + lg * 4) * Ln + lr;

    int nt = qb + 1;
    auto stage = [&](int buf, int t) {
      long k0 = (long)t * 64;
      short* bK = &smK[buf][w * 1024];
      short* bV = &smV[buf][w * 1024];
      gl_lds16(Kg + (k0 + r0) * Dn + scol,           bK);
      gl_lds16(Kg + (k0 + r0 + 8) * Dn + scol,       bK + 512);
      gl_lds16(Vg + (long)r0 * Ln + k0 + scol,       bV);
      gl_lds16(Vg + (long)(r0 + 8) * Ln + k0 + scol, bV + 512);
    };

    float gcur[4][4], gnxt[4][4];
    stage(0, 0);
    {
      const short* g0 = gbase;
#pragma unroll
      for (int kk = 0; kk < 4; ++kk)
#pragma unroll
        for (int r = 0; r < 4; ++r) gcur[kk][r] = bf2f(g0[(long)r * Ln + kk * 16]);
    }
    int cur = 0;
    for (int t = 0; t < nt; ++t) {
      bool pre = (t + 1 < nt);
      if (pre) {
        const short* g0 = gbase + (t + 1) * 64;
#pragma unroll
        for (int kk = 0; kk < 4; ++kk)
#pragma unroll
          for (int r = 0; r < 4; ++r) gnxt[kk][r] = bf2f(g0[(long)r * Ln + kk * 16]);
        stage(cur ^ 1, t + 1);
      }
      __builtin_amdgcn_sched_barrier(0);
      if (pre) asm volatile("s_waitcnt vmcnt(20)" ::: "memory");
      else     asm volatile("s_waitcnt vmcnt(0)" ::: "memory");
      __builtin_amdgcn_s_barrier();
      __builtin_amdgcn_sched_barrier(0);
      int k0 = t * 64;
      const short* Kc = smK[cur];
      const short* Vc = smV[cur];
      // ---- QK^T + exp into smP ----
#pragma unroll
      for (int kk = 0; kk < 4; ++kk) {
        const short* kr = Kc + (kk * 16 + lr) * 64;
        s16x8 kf0 = *(const s16x8*)(kr + ((lg * 8) ^ sw));
        s16x8 kf1 = *(const s16x8*)(kr + ((32 + lg * 8) ^ sw));
        f32x4 S = {};
        S = __builtin_amdgcn_mfma_f32_16x16x32_bf16(qf0, kf0, S, 0, 0, 0);
        S = __builtin_amdgcn_mfma_f32_16x16x32_bf16(qf1, kf1, S, 0, 0, 0);
        int k = k0 + kk * 16 + lr;
#pragma unroll
        for (int r = 0; r < 4; r++) {
          int q = q0w + lg * 4 + r;
          float arg = (k <= q) ? (S[r] * 0.125f + gcur[kk][r]) : -80.0f;
          float pv = __expf(arg);
          az[r] += pv;
          int qq = lg * 4 + r;
          pw[qq * 64 + ((kk * 16 + lr) ^ ((qq & 7) << 3))] = f2bf(pv);
        }
      }
      // ---- P @ V ----
#pragma unroll
      for (int c = 0; c < 2; ++c) {
        s16x8 pf = *(const s16x8*)(pw + lr * 64 + ((c * 32 + lg * 8) ^ sw));
#pragma unroll
        for (int n = 0; n < 4; n++) {
          s16x8 vf = *(const s16x8*)(Vc + (n * 16 + lr) * 64 + ((c * 32 + lg * 8) ^ sw));
          acc[n] = __builtin_amdgcn_mfma_f32_16x16x32_bf16(pf, vf, acc[n], 0, 0, 0);
        }
      }
      __builtin_amdgcn_s_barrier();
      if (pre) {
#pragma unroll
        for (int kk = 0; kk < 4; ++kk)
#pragma unroll
          for (int r = 0; r < 4; ++r) gcur[kk][r] = gnxt[kk][r];
      }
      cur ^= 1;
    }
#pragma unroll
    for (int r = 0; r < 4; r++) {
      float z = az[r];
      z += __shfl_xor(z, 1); z += __shfl_xor(z, 2); z += __shfl_xor(z, 4); z += __shfl_xor(z, 8);
      az[r] = 1.0f / z;
    }
    if (lr == 0) {
#pragma unroll
      for (int r = 0; r < 4; r++)
        zinv[((long)(b * NH + h)) * Ln + q0w + lg * 4 + r] = az[r];
    }
#pragma unroll
    for (int n = 0; n < 4; n++) {
#pragma unroll
      for (int r = 0; r < 4; r++) {
        int q = q0w + lg * 4 + r;
        outp[((long)(b * Ln) + q) * Dn + h * 64 + n * 16 + lr] = acc[n][r] * az[r];
      }
    }
  }
}

// ---------------- attention pass 2: full 64x64 tile grid; upper tiles write zeros ----------------
__global__ __launch_bounds__(256)
void k_attn2(const short* __restrict__ Qm, const short* __restrict__ Kx,
             const short* __restrict__ Gb, const float* __restrict__ zinv, float* __restrict__ aw) {
  int b = blockIdx.y;
  int t = blockIdx.x;
  int qb = t >> 5, kb = t & 31;
  int q0 = qb * 64, k0 = kb * 64;
  int tid = threadIdx.x;
  if (kb > qb) {   // strict upper tile: zero-fill
    int row = tid >> 2, c4 = (tid & 3) << 4;
    float* basep = aw + ((long)b * Ln + q0 + row) * Ln + k0 + c4;
    f32x4 z = {};
    *(f32x4*)(basep) = z; *(f32x4*)(basep + 4) = z;
    *(f32x4*)(basep + 8) = z; *(f32x4*)(basep + 12) = z;
    return;
  }
  int lane = tid & 63, w = tid >> 6;
  int lr = lane & 15, lg = lane >> 4;
  int q0w = q0 + w * 16;
  bool diag = (qb == kb);
  __shared__ short smK[2][64 * 64];
  __shared__ short smQ[2][64 * 64];
  __shared__ float smZ[NH * 64];
  for (int i = tid; i < NH * 64; i += 256) {
    int h = i >> 6, qq = i & 63;
    smZ[i] = zinv[((long)(b * NH + h)) * Ln + q0 + qq];
  }
  __syncthreads();
  float gv[4][4];
#pragma unroll
  for (int n = 0; n < 4; n++) {
    int k = k0 + n * 16 + lr;
#pragma unroll
    for (int r = 0; r < 4; r++)
      gv[n][r] = bf2f(Gb[((long)b * Ln + q0w + lg * 4 + r) * Ln + k]);
  }
  int r0 = w * 16 + (lane >> 3);
  int scol = ((lane & 7) ^ (lane >> 3)) * 8;
  int sw = (lr & 7) << 3;
  auto stage = [&](int buf, int h) {
    short* bK = &smK[buf][w * 1024];
    short* bQ = &smQ[buf][w * 1024];
    const short* Kg = Kx + ((long)(b * Ln) + k0 + r0) * Dn + h * 64 + scol;
    gl_lds16(Kg, bK);
    gl_lds16(Kg + 8 * Dn, bK + 512);
    const short* Qg = Qm + ((long)(b * Ln) + q0 + r0) * Dn + h * 64 + scol;
    gl_lds16(Qg, bQ);
    gl_lds16(Qg + 8 * Dn, bQ + 512);
  };
  float wa[4][4] = {{0.f}};
  stage(0, 0);
  int cur = 0;
  for (int h = 0; h < NH; ++h) {
    bool pre = (h + 1 < NH);
    if (pre) stage(cur ^ 1, h + 1);
    __builtin_amdgcn_sched_barrier(0);
    if (pre) asm volatile("s_waitcnt vmcnt(4)" ::: "memory");
    else     asm volatile("s_waitcnt vmcnt(0)" ::: "memory");
    __builtin_amdgcn_s_barrier();
    __builtin_amdgcn_sched_barrier(0);
    const short* Kc = smK[cur];
    const short* Qc = smQ[cur];
    s16x8 qf0 = *(const s16x8*)(Qc + (w * 16 + lr) * 64 + ((lg * 8) ^ sw));
    s16x8 qf1 = *(const s16x8*)(Qc + (w * 16 + lr) * 64 + ((32 + lg * 8) ^ sw));
    float zq[4];
#pragma unroll
    for (int r = 0; r < 4; r++) zq[r] = smZ[h * 64 + w * 16 + lg * 4 + r];
#pragma unroll
    for (int n = 0; n < 4; n++) {
      const short* kr = Kc + (n * 16 + lr) * 64;
      s16x8 kf0 = *(const s16x8*)(kr + ((lg * 8) ^ sw));
      s16x8 kf1 = *(const s16x8*)(kr + ((32 + lg * 8) ^ sw));
      f32x4 S = {};
      S = __builtin_amdgcn_mfma_f32_16x16x32_bf16(qf0, kf0, S, 0, 0, 0);
      S = __builtin_amdgcn_mfma_f32_16x16x32_bf16(qf1, kf1, S, 0, 0, 0);
#pragma unroll
      for (int r = 0; r < 4; r++)
        wa[n][r] += __expf(S[r] * 0.125f + gv[n][r]) * zq[r];
    }
    __builtin_amdgcn_s_barrier();
    cur ^= 1;
  }
#pragma unroll
  for (int n = 0; n < 4; n++) {
    int k = k0 + n * 16 + lr;
#pragma unroll
    for (int r = 0; r < 4; r++) {
      int q = q0w + lg * 4 + r;
      float v = wa[n][r] * (1.0f / 16.0f);
      if (diag && k > q) v = 0.0f;
      aw[((long)b * Ln + q) * Ln + k] = v;
    }
  }
}

extern "C" void kernel_launch(void* const* d_in, const int* in_sizes, int n_in,
                              void* d_out, int out_size, void* d_ws, size_t ws_size,
                              hipStream_t stream) {
  const float* z    = (const float*)d_in[0];
  const float* ps   = (const float*)d_in[1];
  const float* Wq   = (const float*)d_in[2];
  const float* bq   = (const float*)d_in[3];
  const float* Wk   = (const float*)d_in[4];
  const float* bk   = (const float*)d_in[5];
  const float* Wv   = (const float*)d_in[6];
  const float* bv   = (const float*)d_in[7];
  const float* Wc   = (const float*)d_in[8];
  const float* gamma= (const float*)d_in[9];
  const float* Wg1  = (const float*)d_in[10];
  const float* bg1  = (const float*)d_in[11];
  const float* Wg2  = (const float*)d_in[12];
  const float* bg2  = (const float*)d_in[13];

  char* w = (char*)d_ws;
  auto alloc = [&](long bytes) { void* p = (void*)w; w += (bytes + 255) & ~255L; return p; };
  short* zb   = (short*)alloc(BLD * 2);                   // dead after mega GEMM
  short* pb   = (short*)alloc(BLD * 2);                   // dead after mega GEMM
  short* Wcat = (short*)alloc((long)(4 * Dn + HGn) * Dn * 2);
  short* Qp   = (short*)alloc(BLD * 2);
  short* Kp   = (short*)alloc(BLD * 2);
  short* Vtb  = (short*)alloc(BLD * 2);                   // V transposed: [b][h][d][L]
  short* Gk   = (short*)alloc(BLD * 2);
  float* Hf   = (float*)alloc((long)Bn * Ln * HGn * 4);
  float* gate = (float*)alloc((long)Bn * Ln * 4);
  float* ctf  = (float*)alloc((long)Ln * 512 * 4);
  float* stf  = (float*)alloc((long)Ln * 512 * 4);
  float* cts  = (float*)alloc((long)Ln * 512 * 4);
  float* sts  = (float*)alloc((long)Ln * 512 * 4);
  float* zv   = (float*)alloc((long)Bn * NH * Ln * 4);
  short* Gb   = (short*)zb;   // 16.8MB bias slab aliases zb+pb (dead by then)

  float* outp = (float*)d_out;
  float* aw   = outp + BLD;

  // 1) fused casts (dst = zb|pb|Wcat contiguous)
  CastDesc cd;
  cd.src[0] = z;  cd.src[1] = ps; cd.src[2] = Wq; cd.src[3] = Wk;
  cd.src[4] = Wv; cd.src[5] = Wc; cd.src[6] = Wg1;
  long c0 = 0;
  cd.cum[0] = 0;
  cd.cum[1] = (c0 += BLD);
  cd.cum[2] = (c0 += BLD);
  cd.cum[3] = (c0 += (long)Dn * Dn);
  cd.cum[4] = (c0 += (long)Dn * Dn);
  cd.cum[5] = (c0 += (long)Dn * Dn);
  cd.cum[6] = (c0 += (long)Dn * Dn);
  cd.cum[7] = (c0 += (long)HGn * Dn);
  k_cast7<<<(int)(c0 / 1024), 256, 0, stream>>>(cd, zb);

  // 2) merged projections: Q,K,V(transposed),gk,h(GELU)
  k_gemm_mega<<<dim3((4 * Dn + HGn) / 128, (Bn * Ln) / 128), 256, 0, stream>>>(
      zb, pb, Wcat, bq, bk, bv, bg1, Qp, Kp, Vtb, Gk, Hf);

  // 3) gb (bf16, causal tiles only) -> aliased slab
  k_gemm_gb<<<dim3(Ln / 128, Ln / 128, Bn), 256, 0, stream>>>(Gk, Kp, gamma, Gb);

  // 4) RoPE tables, gate, in-place rotation of Q/K (K raw already consumed by gb)
  k_rope_tables<<<(Ln * 512) / 256, 256, 0, stream>>>(ctf, stf, cts, sts);
  k_gate<<<(Bn * Ln) / 4, 256, 0, stream>>>(Hf, Wg2, bg2, gate);
  k_rope<<<Bn * Ln, 256, 0, stream>>>(Qp, Kp, gate, ctf, stf, cts, sts);

  // 5) attention
  k_attn1<<<512, 256, 0, stream>>>(Qp, Kp, Vtb, Gb, outp, zv);
  k_attn2<<<dim3(32 * 32, Bn), 256, 0, stream>>>(Qp, Kp, Gb, zv, aw);
}

// Round 7
// 249.021 us; speedup vs baseline: 2.7709x; 1.0099x over previous
//
#include <hip/hip_runtime.h>
#include <hip/hip_bf16.h>

// Problem constants (B=2, L=2048, D=1024, NH=16, HD=64, H_GATE=256)
constexpr int Bn  = 2;
constexpr int Ln  = 2048;
constexpr int Dn  = 1024;
constexpr int NH  = 16;
constexpr int HGn = 256;
constexpr long BLD = (long)Bn * Ln * Dn;   // 4194304

typedef float f32x4 __attribute__((ext_vector_type(4)));
typedef float f32x2 __attribute__((ext_vector_type(2)));
typedef short s16x8 __attribute__((ext_vector_type(8)));
typedef short s16x4 __attribute__((ext_vector_type(4)));
typedef short s16x2 __attribute__((ext_vector_type(2)));

#define DEVI static __device__ __forceinline__

DEVI float bf2f(short u) {
  union { float f; unsigned int i; } v; v.i = ((unsigned int)(unsigned short)u) << 16; return v.f;
}
DEVI short f2bf(float f) {
  union { float f; unsigned int i; } v; v.f = f;
  unsigned int r = v.i + 0x7FFFu + ((v.i >> 16) & 1u);
  return (short)(r >> 16);
}
DEVI void gl_lds16(const void* g, void* l) {
  __builtin_amdgcn_global_load_lds((const __attribute__((address_space(1))) unsigned int*)g,
                                   (__attribute__((address_space(3))) unsigned int*)l, 16, 0, 0);
}

// ---------------- fused 7-segment cast f32 -> bf16 (dst segments contiguous) ----------------
struct CastDesc { const float* src[7]; long cum[8]; };
__global__ void k_cast7(CastDesc d, short* __restrict__ dst) {
  long gi = ((long)blockIdx.x * 256 + threadIdx.x) * 4;
  int s = 0;
#pragma unroll
  for (int i = 1; i < 7; ++i) if (gi >= d.cum[i]) s = i;
  const float* sp = d.src[s] + (gi - d.cum[s]);
  f32x4 v = *(const f32x4*)sp;
  s16x4 o; o[0] = f2bf(v[0]); o[1] = f2bf(v[1]); o[2] = f2bf(v[2]); o[3] = f2bf(v[3]);
  *(s16x4*)(dst + gi) = o;
}

// ---------------- merged projection GEMM: [Q|K|V|gk|h] = [z|z|z|ps|ps] @ Wcat^T ----------------
// Double-buffered LDS + counted vmcnt + chunk-XOR swizzle + XCD-chunked block swizzle.
__global__ __launch_bounds__(256)
void k_gemm_mega(const short* __restrict__ zb, const short* __restrict__ pb,
                 const short* __restrict__ Wcat,
                 const float* __restrict__ bq, const float* __restrict__ bk,
                 const float* __restrict__ bv, const float* __restrict__ bg1,
                 short* __restrict__ Qp, short* __restrict__ Kp,
                 short* __restrict__ Vtb, short* __restrict__ Gk,
                 float* __restrict__ Hf) {
  // 1088 blocks = 8 XCDs * 136; contiguous chunk per XCD, n-fastest (A-panel reuse)
  int lin = blockIdx.y * 34 + blockIdx.x;
  int id2 = (lin & 7) * 136 + (lin >> 3);
  int n0 = (id2 % 34) * 128, m0 = (id2 / 34) * 128;
  const short* Ap = (n0 < 3072) ? zb : pb;
  __shared__ short smA[2][128 * 32];
  __shared__ short smB[2][128 * 32];
  int tid = threadIdx.x;
  int lane = tid & 63, wid = tid >> 6;
  int wr = wid >> 1, wc = wid & 1;
  int lr = lane & 15, lg = lane >> 4;
  int r_in = lane >> 2;
  int slot = (lane & 3) * 8;                          // linear LDS chunk slot (elems)
  int scol = ((lane & 3) ^ ((lane >> 3) & 3)) * 8;    // pre-swizzled source chunk (elems)
  int rsw = (lr >> 1) & 3;                            // read-side XOR (chunks)
  f32x4 acc[4][4] = {};
  auto stage = [&](int buf, int k0) {
    int rowA = wid * 32 + r_in;
    gl_lds16(Ap   + (long)(m0 + rowA)      * Dn + k0 + scol, &smA[buf][rowA * 32 + slot]);
    gl_lds16(Ap   + (long)(m0 + rowA + 16) * Dn + k0 + scol, &smA[buf][(rowA + 16) * 32 + slot]);
    gl_lds16(Wcat + (long)(n0 + rowA)      * Dn + k0 + scol, &smB[buf][rowA * 32 + slot]);
    gl_lds16(Wcat + (long)(n0 + rowA + 16) * Dn + k0 + scol, &smB[buf][(rowA + 16) * 32 + slot]);
  };
  stage(0, 0);
  int cur = 0;
  for (int k0 = 0; k0 < Dn; k0 += 32) {
    bool pre = (k0 + 32 < Dn);
    if (pre) stage(cur ^ 1, k0 + 32);
    __builtin_amdgcn_sched_barrier(0);
    if (pre) asm volatile("s_waitcnt vmcnt(4)" ::: "memory");
    else     asm volatile("s_waitcnt vmcnt(0)" ::: "memory");
    __builtin_amdgcn_s_barrier();
    __builtin_amdgcn_sched_barrier(0);
    s16x8 af[4], bf[4];
#pragma unroll
    for (int m = 0; m < 4; m++)
      af[m] = *(const s16x8*)(&smA[cur][(wr * 64 + m * 16 + lr) * 32 + ((lg ^ rsw) * 8)]);
#pragma unroll
    for (int n = 0; n < 4; n++)
      bf[n] = *(const s16x8*)(&smB[cur][(wc * 64 + n * 16 + lr) * 32 + ((lg ^ rsw) * 8)]);
#pragma unroll
    for (int m = 0; m < 4; m++)
#pragma unroll
      for (int n = 0; n < 4; n++)
        acc[m][n] = __builtin_amdgcn_mfma_f32_16x16x32_bf16(af[m], bf[n], acc[m][n], 0, 0, 0);
    __builtin_amdgcn_s_barrier();
    cur ^= 1;
  }
  int slice = n0 >> 10;   // 0..4 (4352 cols)
#pragma unroll
  for (int n = 0; n < 4; n++) {
    int col = n0 + wc * 64 + n * 16 + lr;
    int c = col - (slice << 10);
    float bias = (slice == 0) ? bq[c] : (slice == 1) ? bk[c] : (slice == 2) ? bv[c]
               : (slice == 3) ? 0.0f : bg1[c];
#pragma unroll
    for (int m = 0; m < 4; m++) {
#pragma unroll
      for (int r = 0; r < 4; r++) {
        long row = m0 + wr * 64 + m * 16 + lg * 4 + r;
        float v = acc[m][n][r] + bias;
        if (slice == 4) {
          v = 0.5f * v * (1.0f + erff(v * 0.70710678118f));
          Hf[row * HGn + c] = v;
        } else if (slice == 2) {
          long off = (((row >> 11) * (long)NH + (c >> 6)) * 64 + (c & 63)) * Ln + (row & (Ln - 1));
          Vtb[off] = f2bf(v);
        } else {
          short* dst = (slice == 0) ? Qp : (slice == 1) ? Kp : Gk;
          dst[row * (long)Dn + c] = f2bf(v);
        }
      }
    }
  }
}

// ---------------- gb GEMM: Gb[b,q,k] = bf16( tanh(gamma)/32 * gk[q].K_raw[k] ), triangular grid ----------------
__global__ __launch_bounds__(256)
void k_gemm_gb(const short* __restrict__ A, const short* __restrict__ B,
               const float* __restrict__ gamma, short* __restrict__ C) {
  int bz = blockIdx.y;
  int t = blockIdx.x;
  int qb = (int)((sqrtf(8.0f * (float)t + 1.0f) - 1.0f) * 0.5f);
  while ((qb + 1) * (qb + 2) / 2 <= t) ++qb;
  while (qb * (qb + 1) / 2 > t) --qb;
  int kb = t - qb * (qb + 1) / 2;
  int m0 = qb * 128, n0 = kb * 128;
  const short* Ap = A + (long)bz * Ln * Dn;
  const short* Bp = B + (long)bz * Ln * Dn;
  __shared__ short smA[2][128 * 32];
  __shared__ short smB[2][128 * 32];
  int tid = threadIdx.x;
  int lane = tid & 63, wid = tid >> 6;
  int wr = wid >> 1, wc = wid & 1;
  int lr = lane & 15, lg = lane >> 4;
  int r_in = lane >> 2;
  int slot = (lane & 3) * 8;
  int scol = ((lane & 3) ^ ((lane >> 3) & 3)) * 8;
  int rsw = (lr >> 1) & 3;
  f32x4 acc[4][4] = {};
  auto stage = [&](int buf, int k0) {
    int rowA = wid * 32 + r_in;
    gl_lds16(Ap + (long)(m0 + rowA)      * Dn + k0 + scol, &smA[buf][rowA * 32 + slot]);
    gl_lds16(Ap + (long)(m0 + rowA + 16) * Dn + k0 + scol, &smA[buf][(rowA + 16) * 32 + slot]);
    gl_lds16(Bp + (long)(n0 + rowA)      * Dn + k0 + scol, &smB[buf][rowA * 32 + slot]);
    gl_lds16(Bp + (long)(n0 + rowA + 16) * Dn + k0 + scol, &smB[buf][(rowA + 16) * 32 + slot]);
  };
  stage(0, 0);
  int cur = 0;
  for (int k0 = 0; k0 < Dn; k0 += 32) {
    bool pre = (k0 + 32 < Dn);
    if (pre) stage(cur ^ 1, k0 + 32);
    __builtin_amdgcn_sched_barrier(0);
    if (pre) asm volatile("s_waitcnt vmcnt(4)" ::: "memory");
    else     asm volatile("s_waitcnt vmcnt(0)" ::: "memory");
    __builtin_amdgcn_s_barrier();
    __builtin_amdgcn_sched_barrier(0);
    s16x8 af[4], bf[4];
#pragma unroll
    for (int m = 0; m < 4; m++)
      af[m] = *(const s16x8*)(&smA[cur][(wr * 64 + m * 16 + lr) * 32 + ((lg ^ rsw) * 8)]);
#pragma unroll
    for (int n = 0; n < 4; n++)
      bf[n] = *(const s16x8*)(&smB[cur][(wc * 64 + n * 16 + lr) * 32 + ((lg ^ rsw) * 8)]);
#pragma unroll
    for (int m = 0; m < 4; m++)
#pragma unroll
      for (int n = 0; n < 4; n++)
        acc[m][n] = __builtin_amdgcn_mfma_f32_16x16x32_bf16(af[m], bf[n], acc[m][n], 0, 0, 0);
    __builtin_amdgcn_s_barrier();
    cur ^= 1;
  }
  float alpha = tanhf(gamma[0]) * 0.03125f;
#pragma unroll
  for (int n = 0; n < 4; n++) {
    int col = n0 + wc * 64 + n * 16 + lr;
#pragma unroll
    for (int m = 0; m < 4; m++) {
#pragma unroll
      for (int r = 0; r < 4; r++) {
        long row = m0 + wr * 64 + m * 16 + lg * 4 + r;
        C[(long)bz * Ln * Ln + row * Ln + col] = f2bf(acc[m][n][r] * alpha);
      }
    }
  }
}

// ---------------- RoPE cos/sin tables: [L][512] for both bases ----------------
__global__ void k_rope_tables(float* __restrict__ ctf, float* __restrict__ stf,
                              float* __restrict__ cts, float* __restrict__ sts) {
  int idx = blockIdx.x * 256 + threadIdx.x;   // L*512 total
  int l = idx >> 9, j = idx & 511;
  float e = (float)j * (1.0f / 512.0f);
  float invf = powf(1.6180339887498949f, -e);
  float invs = powf(1618.0f, -e);
  float af = (float)l * invf, as = (float)l * invs;
  float sf, cf, ss, cs;
  sincosf(af, &sf, &cf);
  sincosf(as, &ss, &cs);
  ctf[idx] = cf; stf[idx] = sf; cts[idx] = cs; sts[idx] = ss;
}

// ---------------- gate = sigmoid(h . Wg2 + bg2), one wave per row ----------------
__global__ void k_gate(const float* __restrict__ Hf, const float* __restrict__ Wg2,
                       const float* __restrict__ bg2, float* __restrict__ gate) {
  int lane = threadIdx.x & 63, wid = threadIdx.x >> 6;
  int row = blockIdx.x * 4 + wid;
  f32x4 h = *(const f32x4*)(Hf + (long)row * HGn + lane * 4);
  f32x4 w = *(const f32x4*)(Wg2 + lane * 4);
  float s = h[0] * w[0] + h[1] * w[1] + h[2] * w[2] + h[3] * w[3];
#pragma unroll
  for (int m = 1; m < 64; m <<= 1) s += __shfl_xor(s, m);
  if (lane == 0) gate[row] = 1.0f / (1.0f + __expf(-(s + bg2[0])));
}

// ---------------- RoPE apply (in place, Q and K), one block per (b,l) ----------------
__global__ void k_rope(short* __restrict__ Q, short* __restrict__ Kx,
                       const float* __restrict__ gate,
                       const float* __restrict__ ctf, const float* __restrict__ stf,
                       const float* __restrict__ cts, const float* __restrict__ sts) {
  int bl = blockIdx.x;
  int l = bl & (Ln - 1);
  int t = threadIdx.x;
  float g = gate[bl];
  int j = t * 2;
  f32x2 vcf = *(const f32x2*)(ctf + l * 512 + j);
  f32x2 vsf = *(const f32x2*)(stf + l * 512 + j);
  f32x2 vcs = *(const f32x2*)(cts + l * 512 + j);
  f32x2 vss = *(const f32x2*)(sts + l * 512 + j);
  float c0 = g * vcf[0] + (1.f - g) * vcs[0];
  float c1 = g * vcf[1] + (1.f - g) * vcs[1];
  float s0 = g * vsf[0] + (1.f - g) * vss[0];
  float s1 = g * vsf[1] + (1.f - g) * vss[1];
  long base = (long)bl * Dn + j;
  {
    s16x2 xa = *(const s16x2*)(Q + base);
    s16x2 xb = *(const s16x2*)(Q + base + 512);
    float a0 = bf2f(xa[0]), a1 = bf2f(xa[1]), b0 = bf2f(xb[0]), b1 = bf2f(xb[1]);
    s16x2 o0, o1;
    o0[0] = f2bf(a0 * c0 - b0 * s0); o0[1] = f2bf(a1 * c1 - b1 * s1);
    o1[0] = f2bf(b0 * c0 + a0 * s0); o1[1] = f2bf(b1 * c1 + a1 * s1);
    *(s16x2*)(Q + base) = o0;
    *(s16x2*)(Q + base + 512) = o1;
  }
  {
    s16x2 xa = *(const s16x2*)(Kx + base);
    s16x2 xb = *(const s16x2*)(Kx + base + 512);
    float a0 = bf2f(xa[0]), a1 = bf2f(xa[1]), b0 = bf2f(xb[0]), b1 = bf2f(xb[1]);
    s16x2 o0, o1;
    o0[0] = f2bf(a0 * c0 - b0 * s0); o0[1] = f2bf(a1 * c1 - b1 * s1);
    o1[0] = f2bf(b0 * c0 + a0 * s0); o1[1] = f2bf(b1 * c1 + a1 * s1);
    *(s16x2*)(Kx + base) = o0;
    *(s16x2*)(Kx + base + 512) = o1;
  }
}

// ---------------- attention pass 1: uniform-work pairs (qb, 31-qb), XCD-grouped ----------------
__global__ __launch_bounds__(256)
void k_attn1(const short* __restrict__ Q, const short* __restrict__ Kx,
             const short* __restrict__ Vt, const short* __restrict__ Gb,
             float* __restrict__ outp, float* __restrict__ zinv) {
  int wg = blockIdx.x;              // 0..511
  int xcd = wg & 7, slot = wg >> 3; // slot 0..63
  int p = slot & 15, gh = slot >> 4;
  int g = gh * 8 + xcd;             // 0..31 (b,h) group
  int b = g >> 4, h = g & 15;

  int tid = threadIdx.x;
  int lane = tid & 63, w = tid >> 6;
  int lr = lane & 15, lg = lane >> 4;
  __shared__ short smK[2][64 * 64];
  __shared__ short smV[2][64 * 64];
  __shared__ short smP[4 * 16 * 64];
  short* pw = smP + w * 1024;

  int r0 = w * 16 + (lane >> 3);                 // staged row in tile (0..63)
  int scol = ((lane & 7) ^ (lane >> 3)) * 8;     // pre-swizzled source col (elems)
  const short* Kg = Kx + (long)(b * Ln) * Dn + h * 64;
  const short* Vg = Vt + (long)(b * NH + h) * 64 * Ln;
  int sw = (lr & 7) << 3;                        // read-side XOR (elems)

  for (int seg = 0; seg < 2; ++seg) {
    int qb = seg ? (31 - p) : p;
    int q0w = qb * 64 + w * 16;
    const short* qbp = Q + ((long)(b * Ln) + q0w + lr) * Dn + h * 64 + lg * 8;
    s16x8 qf0 = *(const s16x8*)(qbp);
    s16x8 qf1 = *(const s16x8*)(qbp + 32);
    f32x4 acc[4] = {};
    float az[4] = {0.f, 0.f, 0.f, 0.f};
    const short* gbase = Gb + ((long)b * Ln + q0w + lg * 4) * Ln + lr;

    int nt = qb + 1;
    auto stage = [&](int buf, int t) {
      long k0 = (long)t * 64;
      short* bK = &smK[buf][w * 1024];
      short* bV = &smV[buf][w * 1024];
      gl_lds16(Kg + (k0 + r0) * Dn + scol,           bK);
      gl_lds16(Kg + (k0 + r0 + 8) * Dn + scol,       bK + 512);
      gl_lds16(Vg + (long)r0 * Ln + k0 + scol,       bV);
      gl_lds16(Vg + (long)(r0 + 8) * Ln + k0 + scol, bV + 512);
    };

    float gcur[4][4], gnxt[4][4];
    stage(0, 0);
    {
      const short* g0 = gbase;
#pragma unroll
      for (int kk = 0; kk < 4; ++kk)
#pragma unroll
        for (int r = 0; r < 4; ++r) gcur[kk][r] = bf2f(g0[(long)r * Ln + kk * 16]);
    }
    int cur = 0;
    for (int t = 0; t < nt; ++t) {
      bool pre = (t + 1 < nt);
      if (pre) {
        const short* g0 = gbase + (t + 1) * 64;
#pragma unroll
        for (int kk = 0; kk < 4; ++kk)
#pragma unroll
          for (int r = 0; r < 4; ++r) gnxt[kk][r] = bf2f(g0[(long)r * Ln + kk * 16]);
        stage(cur ^ 1, t + 1);
      }
      __builtin_amdgcn_sched_barrier(0);
      if (pre) asm volatile("s_waitcnt vmcnt(20)" ::: "memory");
      else     asm volatile("s_waitcnt vmcnt(0)" ::: "memory");
      __builtin_amdgcn_s_barrier();
      __builtin_amdgcn_sched_barrier(0);
      int k0 = t * 64;
      const short* Kc = smK[cur];
      const short* Vc = smV[cur];
#pragma unroll
      for (int kk = 0; kk < 4; ++kk) {
        const short* kr = Kc + (kk * 16 + lr) * 64;
        s16x8 kf0 = *(const s16x8*)(kr + ((lg * 8) ^ sw));
        s16x8 kf1 = *(const s16x8*)(kr + ((32 + lg * 8) ^ sw));
        f32x4 S = {};
        S = __builtin_amdgcn_mfma_f32_16x16x32_bf16(qf0, kf0, S, 0, 0, 0);
        S = __builtin_amdgcn_mfma_f32_16x16x32_bf16(qf1, kf1, S, 0, 0, 0);
        int k = k0 + kk * 16 + lr;
#pragma unroll
        for (int r = 0; r < 4; r++) {
          int q = q0w + lg * 4 + r;
          float arg = (k <= q) ? (S[r] * 0.125f + gcur[kk][r]) : -80.0f;
          float pv = __expf(arg);
          az[r] += pv;
          int qq = lg * 4 + r;
          pw[qq * 64 + ((kk * 16 + lr) ^ ((qq & 7) << 3))] = f2bf(pv);
        }
      }
#pragma unroll
      for (int c = 0; c < 2; ++c) {
        s16x8 pf = *(const s16x8*)(pw + lr * 64 + ((c * 32 + lg * 8) ^ sw));
#pragma unroll
        for (int n = 0; n < 4; n++) {
          s16x8 vf = *(const s16x8*)(Vc + (n * 16 + lr) * 64 + ((c * 32 + lg * 8) ^ sw));
          acc[n] = __builtin_amdgcn_mfma_f32_16x16x32_bf16(pf, vf, acc[n], 0, 0, 0);
        }
      }
      __builtin_amdgcn_s_barrier();
      if (pre) {
#pragma unroll
        for (int kk = 0; kk < 4; ++kk)
#pragma unroll
          for (int r = 0; r < 4; ++r) gcur[kk][r] = gnxt[kk][r];
      }
      cur ^= 1;
    }
#pragma unroll
    for (int r = 0; r < 4; r++) {
      float z = az[r];
      z += __shfl_xor(z, 1); z += __shfl_xor(z, 2); z += __shfl_xor(z, 4); z += __shfl_xor(z, 8);
      az[r] = 1.0f / z;
    }
    if (lr == 0) {
#pragma unroll
      for (int r = 0; r < 4; r++)
        zinv[((long)(b * NH + h)) * Ln + q0w + lg * 4 + r] = az[r];
    }
#pragma unroll
    for (int n = 0; n < 4; n++) {
#pragma unroll
      for (int r = 0; r < 4; r++) {
        int q = q0w + lg * 4 + r;
        outp[((long)(b * Ln) + q) * Dn + h * 64 + n * 16 + lr] = acc[n][r] * az[r];
      }
    }
  }
}

// ---------------- attention pass 2: full 64x64 tile grid; upper tiles write zeros ----------------
__global__ __launch_bounds__(256)
void k_attn2(const short* __restrict__ Qm, const short* __restrict__ Kx,
             const short* __restrict__ Gb, const float* __restrict__ zinv, float* __restrict__ aw) {
  int b = blockIdx.y;
  int t = blockIdx.x;
  int qb = t >> 5, kb = t & 31;
  int q0 = qb * 64, k0 = kb * 64;
  int tid = threadIdx.x;
  if (kb > qb) {   // strict upper tile: zero-fill
    int row = tid >> 2, c4 = (tid & 3) << 4;
    float* basep = aw + ((long)b * Ln + q0 + row) * Ln + k0 + c4;
    f32x4 z = {};
    *(f32x4*)(basep) = z; *(f32x4*)(basep + 4) = z;
    *(f32x4*)(basep + 8) = z; *(f32x4*)(basep + 12) = z;
    return;
  }
  int lane = tid & 63, w = tid >> 6;
  int lr = lane & 15, lg = lane >> 4;
  int q0w = q0 + w * 16;
  bool diag = (qb == kb);
  __shared__ short smK[2][64 * 64];
  __shared__ short smQ[2][64 * 64];
  __shared__ float smZ[NH * 64];
  for (int i = tid; i < NH * 64; i += 256) {
    int h = i >> 6, qq = i & 63;
    smZ[i] = zinv[((long)(b * NH + h)) * Ln + q0 + qq];
  }
  __syncthreads();
  float gv[4][4];
#pragma unroll
  for (int n = 0; n < 4; n++) {
    int k = k0 + n * 16 + lr;
#pragma unroll
    for (int r = 0; r < 4; r++)
      gv[n][r] = bf2f(Gb[((long)b * Ln + q0w + lg * 4 + r) * Ln + k]);
  }
  int r0 = w * 16 + (lane >> 3);
  int scol = ((lane & 7) ^ (lane >> 3)) * 8;
  int sw = (lr & 7) << 3;
  auto stage = [&](int buf, int h) {
    short* bK = &smK[buf][w * 1024];
    short* bQ = &smQ[buf][w * 1024];
    const short* Kg = Kx + ((long)(b * Ln) + k0 + r0) * Dn + h * 64 + scol;
    gl_lds16(Kg, bK);
    gl_lds16(Kg + 8 * Dn, bK + 512);
    const short* Qg = Qm + ((long)(b * Ln) + q0 + r0) * Dn + h * 64 + scol;
    gl_lds16(Qg, bQ);
    gl_lds16(Qg + 8 * Dn, bQ + 512);
  };
  float wa[4][4] = {{0.f}};
  stage(0, 0);
  int cur = 0;
  for (int h = 0; h < NH; ++h) {
    bool pre = (h + 1 < NH);
    if (pre) stage(cur ^ 1, h + 1);
    __builtin_amdgcn_sched_barrier(0);
    if (pre) asm volatile("s_waitcnt vmcnt(4)" ::: "memory");
    else     asm volatile("s_waitcnt vmcnt(0)" ::: "memory");
    __builtin_amdgcn_s_barrier();
    __builtin_amdgcn_sched_barrier(0);
    const short* Kc = smK[cur];
    const short* Qc = smQ[cur];
    s16x8 qf0 = *(const s16x8*)(Qc + (w * 16 + lr) * 64 + ((lg * 8) ^ sw));
    s16x8 qf1 = *(const s16x8*)(Qc + (w * 16 + lr) * 64 + ((32 + lg * 8) ^ sw));
    float zq[4];
#pragma unroll
    for (int r = 0; r < 4; r++) zq[r] = smZ[h * 64 + w * 16 + lg * 4 + r];
#pragma unroll
    for (int n = 0; n < 4; n++) {
      const short* kr = Kc + (n * 16 + lr) * 64;
      s16x8 kf0 = *(const s16x8*)(kr + ((lg * 8) ^ sw));
      s16x8 kf1 = *(const s16x8*)(kr + ((32 + lg * 8) ^ sw));
      f32x4 S = {};
      S = __builtin_amdgcn_mfma_f32_16x16x32_bf16(qf0, kf0, S, 0, 0, 0);
      S = __builtin_amdgcn_mfma_f32_16x16x32_bf16(qf1, kf1, S, 0, 0, 0);
#pragma unroll
      for (int r = 0; r < 4; r++)
        wa[n][r] += __expf(S[r] * 0.125f + gv[n][r]) * zq[r];
    }
    __builtin_amdgcn_s_barrier();
    cur ^= 1;
  }
#pragma unroll
  for (int n = 0; n < 4; n++) {
    int k = k0 + n * 16 + lr;
#pragma unroll
    for (int r = 0; r < 4; r++) {
      int q = q0w + lg * 4 + r;
      float v = wa[n][r] * (1.0f / 16.0f);
      if (diag && k > q) v = 0.0f;
      aw[((long)b * Ln + q) * Ln + k] = v;
    }
  }
}

extern "C" void kernel_launch(void* const* d_in, const int* in_sizes, int n_in,
                              void* d_out, int out_size, void* d_ws, size_t ws_size,
                              hipStream_t stream) {
  const float* z    = (const float*)d_in[0];
  const float* ps   = (const float*)d_in[1];
  const float* Wq   = (const float*)d_in[2];
  const float* bq   = (const float*)d_in[3];
  const float* Wk   = (const float*)d_in[4];
  const float* bk   = (const float*)d_in[5];
  const float* Wv   = (const float*)d_in[6];
  const float* bv   = (const float*)d_in[7];
  const float* Wc   = (const float*)d_in[8];
  const float* gamma= (const float*)d_in[9];
  const float* Wg1  = (const float*)d_in[10];
  const float* bg1  = (const float*)d_in[11];
  const float* Wg2  = (const float*)d_in[12];
  const float* bg2  = (const float*)d_in[13];

  char* w = (char*)d_ws;
  auto alloc = [&](long bytes) { void* p = (void*)w; w += (bytes + 255) & ~255L; return p; };
  short* zb   = (short*)alloc(BLD * 2);                   // dead after mega GEMM
  short* pb   = (short*)alloc(BLD * 2);                   // dead after mega GEMM
  short* Wcat = (short*)alloc((long)(4 * Dn + HGn) * Dn * 2);
  short* Qp   = (short*)alloc(BLD * 2);
  short* Kp   = (short*)alloc(BLD * 2);
  short* Vtb  = (short*)alloc(BLD * 2);                   // V transposed: [b][h][d][L]
  short* Gk   = (short*)alloc(BLD * 2);
  float* Hf   = (float*)alloc((long)Bn * Ln * HGn * 4);
  float* gate = (float*)alloc((long)Bn * Ln * 4);
  float* ctf  = (float*)alloc((long)Ln * 512 * 4);
  float* stf  = (float*)alloc((long)Ln * 512 * 4);
  float* cts  = (float*)alloc((long)Ln * 512 * 4);
  float* sts  = (float*)alloc((long)Ln * 512 * 4);
  float* zv   = (float*)alloc((long)Bn * NH * Ln * 4);
  short* Gb   = (short*)zb;   // 16.8MB bias slab aliases zb+pb (dead by then)

  float* outp = (float*)d_out;
  float* aw   = outp + BLD;

  // 1) fused casts (dst = zb|pb|Wcat contiguous)
  CastDesc cd;
  cd.src[0] = z;  cd.src[1] = ps; cd.src[2] = Wq; cd.src[3] = Wk;
  cd.src[4] = Wv; cd.src[5] = Wc; cd.src[6] = Wg1;
  long c0 = 0;
  cd.cum[0] = 0;
  cd.cum[1] = (c0 += BLD);
  cd.cum[2] = (c0 += BLD);
  cd.cum[3] = (c0 += (long)Dn * Dn);
  cd.cum[4] = (c0 += (long)Dn * Dn);
  cd.cum[5] = (c0 += (long)Dn * Dn);
  cd.cum[6] = (c0 += (long)Dn * Dn);
  cd.cum[7] = (c0 += (long)HGn * Dn);
  k_cast7<<<(int)(c0 / 1024), 256, 0, stream>>>(cd, zb);

  // 2) merged projections: Q,K,V(transposed),gk,h(GELU)
  k_gemm_mega<<<dim3((4 * Dn + HGn) / 128, (Bn * Ln) / 128), 256, 0, stream>>>(
      zb, pb, Wcat, bq, bk, bv, bg1, Qp, Kp, Vtb, Gk, Hf);

  // 3) gb (bf16, causal tiles only) -> aliased slab
  k_gemm_gb<<<dim3(16 * 17 / 2, Bn), 256, 0, stream>>>(Gk, Kp, gamma, Gb);

  // 4) RoPE tables, gate, in-place rotation of Q/K (K raw already consumed by gb)
  k_rope_tables<<<(Ln * 512) / 256, 256, 0, stream>>>(ctf, stf, cts, sts);
  k_gate<<<(Bn * Ln) / 4, 256, 0, stream>>>(Hf, Wg2, bg2, gate);
  k_rope<<<Bn * Ln, 256, 0, stream>>>(Qp, Kp, gate, ctf, stf, cts, sts);

  // 5) attention
  k_attn1<<<512, 256, 0, stream>>>(Qp, Kp, Vtb, Gb, outp, zv);
  k_attn2<<<dim3(32 * 32, Bn), 256, 0, stream>>>(Qp, Kp, Gb, zv, aw);
}

// Round 8
// 245.118 us; speedup vs baseline: 2.8151x; 1.0159x over previous
//
#include <hip/hip_runtime.h>
#include <hip/hip_bf16.h>

// Problem constants (B=2, L=2048, D=1024, NH=16, HD=64, H_GATE=256)
constexpr int Bn  = 2;
constexpr int Ln  = 2048;
constexpr int Dn  = 1024;
constexpr int NH  = 16;
constexpr int HGn = 256;
constexpr long BLD = (long)Bn * Ln * Dn;   // 4194304

typedef float f32x4 __attribute__((ext_vector_type(4)));
typedef float f32x2 __attribute__((ext_vector_type(2)));
typedef short s16x8 __attribute__((ext_vector_type(8)));
typedef short s16x4 __attribute__((ext_vector_type(4)));
typedef short s16x2 __attribute__((ext_vector_type(2)));

#define DEVI static __device__ __forceinline__

DEVI float bf2f(short u) {
  union { float f; unsigned int i; } v; v.i = ((unsigned int)(unsigned short)u) << 16; return v.f;
}
DEVI short f2bf(float f) {
  union { float f; unsigned int i; } v; v.f = f;
  unsigned int r = v.i + 0x7FFFu + ((v.i >> 16) & 1u);
  return (short)(r >> 16);
}
DEVI void gl_lds16(const void* g, void* l) {
  __builtin_amdgcn_global_load_lds((const __attribute__((address_space(1))) unsigned int*)g,
                                   (__attribute__((address_space(3))) unsigned int*)l, 16, 0, 0);
}

// ---------------- fused 7-segment cast f32 -> bf16 (dst segments contiguous) ----------------
struct CastDesc { const float* src[7]; long cum[8]; };
__global__ void k_cast7(CastDesc d, short* __restrict__ dst) {
  long gi = ((long)blockIdx.x * 256 + threadIdx.x) * 4;
  int s = 0;
#pragma unroll
  for (int i = 1; i < 7; ++i) if (gi >= d.cum[i]) s = i;
  const float* sp = d.src[s] + (gi - d.cum[s]);
  f32x4 v = *(const f32x4*)sp;
  s16x4 o; o[0] = f2bf(v[0]); o[1] = f2bf(v[1]); o[2] = f2bf(v[2]); o[3] = f2bf(v[3]);
  *(s16x4*)(dst + gi) = o;
}

// ---------------- merged projection GEMM: [Q|K|V|gk|h] = [z|z|z|ps|ps] @ Wcat^T ----------------
// XCD-local A-panels (m-set per XCD), n-outer/m-inner order for B-panel L2 reuse,
// 3-stage LDS pipeline with counted vmcnt (8/4/0).
__global__ __launch_bounds__(256)
void k_gemm_mega(const short* __restrict__ zb, const short* __restrict__ pb,
                 const short* __restrict__ Wcat,
                 const float* __restrict__ bq, const float* __restrict__ bk,
                 const float* __restrict__ bv, const float* __restrict__ bg1,
                 short* __restrict__ Qp, short* __restrict__ Kp,
                 short* __restrict__ Vtb, short* __restrict__ Gk,
                 float* __restrict__ Hf) {
  // 1088 blocks; xcd = wgid&7 owns m-panels {4*xcd .. 4*xcd+3}; within XCD n-outer, m-inner.
  int wgid = blockIdx.x;
  int xcd = wgid & 7, idx = wgid >> 3;      // idx 0..135
  int n0 = (idx >> 2) * 128;                // 0..33 n-panels
  int m0 = (xcd * 4 + (idx & 3)) * 128;     // 4 m-panels per XCD
  const short* Ap = (n0 < 3072) ? zb : pb;
  __shared__ short smA[3][128 * 32];
  __shared__ short smB[3][128 * 32];
  int tid = threadIdx.x;
  int lane = tid & 63, wid = tid >> 6;
  int wr = wid >> 1, wc = wid & 1;
  int lr = lane & 15, lg = lane >> 4;
  int r_in = lane >> 2;
  int slot = (lane & 3) * 8;                          // linear LDS chunk slot (elems)
  int scol = ((lane & 3) ^ ((lane >> 3) & 3)) * 8;    // pre-swizzled source chunk (elems)
  int rsw = (lr >> 1) & 3;                            // read-side XOR (chunks)
  f32x4 acc[4][4] = {};
  auto stage = [&](int buf, int k0) {
    int rowA = wid * 32 + r_in;
    gl_lds16(Ap   + (long)(m0 + rowA)      * Dn + k0 + scol, &smA[buf][rowA * 32 + slot]);
    gl_lds16(Ap   + (long)(m0 + rowA + 16) * Dn + k0 + scol, &smA[buf][(rowA + 16) * 32 + slot]);
    gl_lds16(Wcat + (long)(n0 + rowA)      * Dn + k0 + scol, &smB[buf][rowA * 32 + slot]);
    gl_lds16(Wcat + (long)(n0 + rowA + 16) * Dn + k0 + scol, &smB[buf][(rowA + 16) * 32 + slot]);
  };
  stage(0, 0);
  stage(1, 32);
  int cur = 0, sb = 2;
  for (int t = 0; t < 32; ++t) {
    if (t + 2 < 32) stage(sb, (t + 2) * 32);
    __builtin_amdgcn_sched_barrier(0);
    int rem = 31 - t;
    if (rem >= 2)      asm volatile("s_waitcnt vmcnt(8)" ::: "memory");
    else if (rem == 1) asm volatile("s_waitcnt vmcnt(4)" ::: "memory");
    else               asm volatile("s_waitcnt vmcnt(0)" ::: "memory");
    __builtin_amdgcn_s_barrier();
    __builtin_amdgcn_sched_barrier(0);
    s16x8 af[4], bf[4];
#pragma unroll
    for (int m = 0; m < 4; m++)
      af[m] = *(const s16x8*)(&smA[cur][(wr * 64 + m * 16 + lr) * 32 + ((lg ^ rsw) * 8)]);
#pragma unroll
    for (int n = 0; n < 4; n++)
      bf[n] = *(const s16x8*)(&smB[cur][(wc * 64 + n * 16 + lr) * 32 + ((lg ^ rsw) * 8)]);
#pragma unroll
    for (int m = 0; m < 4; m++)
#pragma unroll
      for (int n = 0; n < 4; n++)
        acc[m][n] = __builtin_amdgcn_mfma_f32_16x16x32_bf16(af[m], bf[n], acc[m][n], 0, 0, 0);
    __builtin_amdgcn_s_barrier();
    cur = (cur == 2) ? 0 : cur + 1;
    sb  = (sb == 2) ? 0 : sb + 1;
  }
  int slice = n0 >> 10;   // 0..4 (4352 cols)
#pragma unroll
  for (int n = 0; n < 4; n++) {
    int col = n0 + wc * 64 + n * 16 + lr;
    int c = col - (slice << 10);
    float bias = (slice == 0) ? bq[c] : (slice == 1) ? bk[c] : (slice == 2) ? bv[c]
               : (slice == 3) ? 0.0f : bg1[c];
#pragma unroll
    for (int m = 0; m < 4; m++) {
#pragma unroll
      for (int r = 0; r < 4; r++) {
        long row = m0 + wr * 64 + m * 16 + lg * 4 + r;
        float v = acc[m][n][r] + bias;
        if (slice == 4) {
          v = 0.5f * v * (1.0f + erff(v * 0.70710678118f));
          Hf[row * HGn + c] = v;
        } else if (slice == 2) {
          long off = (((row >> 11) * (long)NH + (c >> 6)) * 64 + (c & 63)) * Ln + (row & (Ln - 1));
          Vtb[off] = f2bf(v);
        } else {
          short* dst = (slice == 0) ? Qp : (slice == 1) ? Kp : Gk;
          dst[row * (long)Dn + c] = f2bf(v);
        }
      }
    }
  }
}

// ---------------- gb GEMM: Gb[b,q,k] = bf16( tanh(gamma)/32 * gk[q].K_raw[k] ), triangular grid ----------------
__global__ __launch_bounds__(256)
void k_gemm_gb(const short* __restrict__ A, const short* __restrict__ B,
               const float* __restrict__ gamma, short* __restrict__ C) {
  int bz = blockIdx.y;
  int t0 = blockIdx.x;
  int qb = (int)((sqrtf(8.0f * (float)t0 + 1.0f) - 1.0f) * 0.5f);
  while ((qb + 1) * (qb + 2) / 2 <= t0) ++qb;
  while (qb * (qb + 1) / 2 > t0) --qb;
  int kb = t0 - qb * (qb + 1) / 2;
  int m0 = qb * 128, n0 = kb * 128;
  const short* Ap = A + (long)bz * Ln * Dn;
  const short* Bp = B + (long)bz * Ln * Dn;
  __shared__ short smA[3][128 * 32];
  __shared__ short smB[3][128 * 32];
  int tid = threadIdx.x;
  int lane = tid & 63, wid = tid >> 6;
  int wr = wid >> 1, wc = wid & 1;
  int lr = lane & 15, lg = lane >> 4;
  int r_in = lane >> 2;
  int slot = (lane & 3) * 8;
  int scol = ((lane & 3) ^ ((lane >> 3) & 3)) * 8;
  int rsw = (lr >> 1) & 3;
  f32x4 acc[4][4] = {};
  auto stage = [&](int buf, int k0) {
    int rowA = wid * 32 + r_in;
    gl_lds16(Ap + (long)(m0 + rowA)      * Dn + k0 + scol, &smA[buf][rowA * 32 + slot]);
    gl_lds16(Ap + (long)(m0 + rowA + 16) * Dn + k0 + scol, &smA[buf][(rowA + 16) * 32 + slot]);
    gl_lds16(Bp + (long)(n0 + rowA)      * Dn + k0 + scol, &smB[buf][rowA * 32 + slot]);
    gl_lds16(Bp + (long)(n0 + rowA + 16) * Dn + k0 + scol, &smB[buf][(rowA + 16) * 32 + slot]);
  };
  stage(0, 0);
  stage(1, 32);
  int cur = 0, sb = 2;
  for (int t = 0; t < 32; ++t) {
    if (t + 2 < 32) stage(sb, (t + 2) * 32);
    __builtin_amdgcn_sched_barrier(0);
    int rem = 31 - t;
    if (rem >= 2)      asm volatile("s_waitcnt vmcnt(8)" ::: "memory");
    else if (rem == 1) asm volatile("s_waitcnt vmcnt(4)" ::: "memory");
    else               asm volatile("s_waitcnt vmcnt(0)" ::: "memory");
    __builtin_amdgcn_s_barrier();
    __builtin_amdgcn_sched_barrier(0);
    s16x8 af[4], bf[4];
#pragma unroll
    for (int m = 0; m < 4; m++)
      af[m] = *(const s16x8*)(&smA[cur][(wr * 64 + m * 16 + lr) * 32 + ((lg ^ rsw) * 8)]);
#pragma unroll
    for (int n = 0; n < 4; n++)
      bf[n] = *(const s16x8*)(&smB[cur][(wc * 64 + n * 16 + lr) * 32 + ((lg ^ rsw) * 8)]);
#pragma unroll
    for (int m = 0; m < 4; m++)
#pragma unroll
      for (int n = 0; n < 4; n++)
        acc[m][n] = __builtin_amdgcn_mfma_f32_16x16x32_bf16(af[m], bf[n], acc[m][n], 0, 0, 0);
    __builtin_amdgcn_s_barrier();
    cur = (cur == 2) ? 0 : cur + 1;
    sb  = (sb == 2) ? 0 : sb + 1;
  }
  float alpha = tanhf(gamma[0]) * 0.03125f;
#pragma unroll
  for (int n = 0; n < 4; n++) {
    int col = n0 + wc * 64 + n * 16 + lr;
#pragma unroll
    for (int m = 0; m < 4; m++) {
#pragma unroll
      for (int r = 0; r < 4; r++) {
        long row = m0 + wr * 64 + m * 16 + lg * 4 + r;
        C[(long)bz * Ln * Ln + row * Ln + col] = f2bf(acc[m][n][r] * alpha);
      }
    }
  }
}

// ---------------- RoPE cos/sin tables: [L][512] for both bases ----------------
__global__ void k_rope_tables(float* __restrict__ ctf, float* __restrict__ stf,
                              float* __restrict__ cts, float* __restrict__ sts) {
  int idx = blockIdx.x * 256 + threadIdx.x;   // L*512 total
  int l = idx >> 9, j = idx & 511;
  float e = (float)j * (1.0f / 512.0f);
  float invf = powf(1.6180339887498949f, -e);
  float invs = powf(1618.0f, -e);
  float af = (float)l * invf, as = (float)l * invs;
  float sf, cf, ss, cs;
  sincosf(af, &sf, &cf);
  sincosf(as, &ss, &cs);
  ctf[idx] = cf; stf[idx] = sf; cts[idx] = cs; sts[idx] = ss;
}

// ---------------- gate = sigmoid(h . Wg2 + bg2), one wave per row ----------------
__global__ void k_gate(const float* __restrict__ Hf, const float* __restrict__ Wg2,
                       const float* __restrict__ bg2, float* __restrict__ gate) {
  int lane = threadIdx.x & 63, wid = threadIdx.x >> 6;
  int row = blockIdx.x * 4 + wid;
  f32x4 h = *(const f32x4*)(Hf + (long)row * HGn + lane * 4);
  f32x4 w = *(const f32x4*)(Wg2 + lane * 4);
  float s = h[0] * w[0] + h[1] * w[1] + h[2] * w[2] + h[3] * w[3];
#pragma unroll
  for (int m = 1; m < 64; m <<= 1) s += __shfl_xor(s, m);
  if (lane == 0) gate[row] = 1.0f / (1.0f + __expf(-(s + bg2[0])));
}

// ---------------- RoPE apply (in place, Q and K), one block per (b,l) ----------------
__global__ void k_rope(short* __restrict__ Q, short* __restrict__ Kx,
                       const float* __restrict__ gate,
                       const float* __restrict__ ctf, const float* __restrict__ stf,
                       const float* __restrict__ cts, const float* __restrict__ sts) {
  int bl = blockIdx.x;
  int l = bl & (Ln - 1);
  int t = threadIdx.x;
  float g = gate[bl];
  int j = t * 2;
  f32x2 vcf = *(const f32x2*)(ctf + l * 512 + j);
  f32x2 vsf = *(const f32x2*)(stf + l * 512 + j);
  f32x2 vcs = *(const f32x2*)(cts + l * 512 + j);
  f32x2 vss = *(const f32x2*)(sts + l * 512 + j);
  float c0 = g * vcf[0] + (1.f - g) * vcs[0];
  float c1 = g * vcf[1] + (1.f - g) * vcs[1];
  float s0 = g * vsf[0] + (1.f - g) * vss[0];
  float s1 = g * vsf[1] + (1.f - g) * vss[1];
  long base = (long)bl * Dn + j;
  {
    s16x2 xa = *(const s16x2*)(Q + base);
    s16x2 xb = *(const s16x2*)(Q + base + 512);
    float a0 = bf2f(xa[0]), a1 = bf2f(xa[1]), b0 = bf2f(xb[0]), b1 = bf2f(xb[1]);
    s16x2 o0, o1;
    o0[0] = f2bf(a0 * c0 - b0 * s0); o0[1] = f2bf(a1 * c1 - b1 * s1);
    o1[0] = f2bf(b0 * c0 + a0 * s0); o1[1] = f2bf(b1 * c1 + a1 * s1);
    *(s16x2*)(Q + base) = o0;
    *(s16x2*)(Q + base + 512) = o1;
  }
  {
    s16x2 xa = *(const s16x2*)(Kx + base);
    s16x2 xb = *(const s16x2*)(Kx + base + 512);
    float a0 = bf2f(xa[0]), a1 = bf2f(xa[1]), b0 = bf2f(xb[0]), b1 = bf2f(xb[1]);
    s16x2 o0, o1;
    o0[0] = f2bf(a0 * c0 - b0 * s0); o0[1] = f2bf(a1 * c1 - b1 * s1);
    o1[0] = f2bf(b0 * c0 + a0 * s0); o1[1] = f2bf(b1 * c1 + a1 * s1);
    *(s16x2*)(Kx + base) = o0;
    *(s16x2*)(Kx + base + 512) = o1;
  }
}

// ---------------- attention pass 1: uniform-work pairs (qb, 31-qb), XCD-grouped ----------------
__global__ __launch_bounds__(256)
void k_attn1(const short* __restrict__ Q, const short* __restrict__ Kx,
             const short* __restrict__ Vt, const short* __restrict__ Gb,
             float* __restrict__ outp, float* __restrict__ zinv) {
  int wg = blockIdx.x;              // 0..511
  int xcd = wg & 7, slot = wg >> 3; // slot 0..63
  int p = slot & 15, gh = slot >> 4;
  int g = gh * 8 + xcd;             // 0..31 (b,h) group
  int b = g >> 4, h = g & 15;

  int tid = threadIdx.x;
  int lane = tid & 63, w = tid >> 6;
  int lr = lane & 15, lg = lane >> 4;
  __shared__ short smK[2][64 * 64];
  __shared__ short smV[2][64 * 64];
  __shared__ short smP[4 * 16 * 64];
  short* pw = smP + w * 1024;

  int r0 = w * 16 + (lane >> 3);                 // staged row in tile (0..63)
  int scol = ((lane & 7) ^ (lane >> 3)) * 8;     // pre-swizzled source col (elems)
  const short* Kg = Kx + (long)(b * Ln) * Dn + h * 64;
  const short* Vg = Vt + (long)(b * NH + h) * 64 * Ln;
  int sw = (lr & 7) << 3;                        // read-side XOR (elems)

  for (int seg = 0; seg < 2; ++seg) {
    int qb = seg ? (31 - p) : p;
    int q0w = qb * 64 + w * 16;
    const short* qbp = Q + ((long)(b * Ln) + q0w + lr) * Dn + h * 64 + lg * 8;
    s16x8 qf0 = *(const s16x8*)(qbp);
    s16x8 qf1 = *(const s16x8*)(qbp + 32);
    f32x4 acc[4] = {};
    float az[4] = {0.f, 0.f, 0.f, 0.f};
    const short* gbase = Gb + ((long)b * Ln + q0w + lg * 4) * Ln + lr;

    int nt = qb + 1;
    auto stage = [&](int buf, int t) {
      long k0 = (long)t * 64;
      short* bK = &smK[buf][w * 1024];
      short* bV = &smV[buf][w * 1024];
      gl_lds16(Kg + (k0 + r0) * Dn + scol,           bK);
      gl_lds16(Kg + (k0 + r0 + 8) * Dn + scol,       bK + 512);
      gl_lds16(Vg + (long)r0 * Ln + k0 + scol,       bV);
      gl_lds16(Vg + (long)(r0 + 8) * Ln + k0 + scol, bV + 512);
    };

    float gcur[4][4], gnxt[4][4];
    stage(0, 0);
    {
      const short* g0 = gbase;
#pragma unroll
      for (int kk = 0; kk < 4; ++kk)
#pragma unroll
        for (int r = 0; r < 4; ++r) gcur[kk][r] = bf2f(g0[(long)r * Ln + kk * 16]);
    }
    int cur = 0;
    for (int t = 0; t < nt; ++t) {
      bool pre = (t + 1 < nt);
      if (pre) {
        const short* g0 = gbase + (t + 1) * 64;
#pragma unroll
        for (int kk = 0; kk < 4; ++kk)
#pragma unroll
          for (int r = 0; r < 4; ++r) gnxt[kk][r] = bf2f(g0[(long)r * Ln + kk * 16]);
        stage(cur ^ 1, t + 1);
      }
      __builtin_amdgcn_sched_barrier(0);
      if (pre) asm volatile("s_waitcnt vmcnt(20)" ::: "memory");
      else     asm volatile("s_waitcnt vmcnt(0)" ::: "memory");
      __builtin_amdgcn_s_barrier();
      __builtin_amdgcn_sched_barrier(0);
      int k0 = t * 64;
      const short* Kc = smK[cur];
      const short* Vc = smV[cur];
#pragma unroll
      for (int kk = 0; kk < 4; ++kk) {
        const short* kr = Kc + (kk * 16 + lr) * 64;
        s16x8 kf0 = *(const s16x8*)(kr + ((lg * 8) ^ sw));
        s16x8 kf1 = *(const s16x8*)(kr + ((32 + lg * 8) ^ sw));
        f32x4 S = {};
        S = __builtin_amdgcn_mfma_f32_16x16x32_bf16(qf0, kf0, S, 0, 0, 0);
        S = __builtin_amdgcn_mfma_f32_16x16x32_bf16(qf1, kf1, S, 0, 0, 0);
        int k = k0 + kk * 16 + lr;
#pragma unroll
        for (int r = 0; r < 4; r++) {
          int q = q0w + lg * 4 + r;
          float arg = (k <= q) ? (S[r] * 0.125f + gcur[kk][r]) : -80.0f;
          float pv = __expf(arg);
          az[r] += pv;
          int qq = lg * 4 + r;
          pw[qq * 64 + ((kk * 16 + lr) ^ ((qq & 7) << 3))] = f2bf(pv);
        }
      }
#pragma unroll
      for (int c = 0; c < 2; ++c) {
        s16x8 pf = *(const s16x8*)(pw + lr * 64 + ((c * 32 + lg * 8) ^ sw));
#pragma unroll
        for (int n = 0; n < 4; n++) {
          s16x8 vf = *(const s16x8*)(Vc + (n * 16 + lr) * 64 + ((c * 32 + lg * 8) ^ sw));
          acc[n] = __builtin_amdgcn_mfma_f32_16x16x32_bf16(pf, vf, acc[n], 0, 0, 0);
        }
      }
      __builtin_amdgcn_s_barrier();
      if (pre) {
#pragma unroll
        for (int kk = 0; kk < 4; ++kk)
#pragma unroll
          for (int r = 0; r < 4; ++r) gcur[kk][r] = gnxt[kk][r];
      }
      cur ^= 1;
    }
#pragma unroll
    for (int r = 0; r < 4; r++) {
      float z = az[r];
      z += __shfl_xor(z, 1); z += __shfl_xor(z, 2); z += __shfl_xor(z, 4); z += __shfl_xor(z, 8);
      az[r] = 1.0f / z;
    }
    if (lr == 0) {
#pragma unroll
      for (int r = 0; r < 4; r++)
        zinv[((long)(b * NH + h)) * Ln + q0w + lg * 4 + r] = az[r];
    }
#pragma unroll
    for (int n = 0; n < 4; n++) {
#pragma unroll
      for (int r = 0; r < 4; r++) {
        int q = q0w + lg * 4 + r;
        outp[((long)(b * Ln) + q) * Dn + h * 64 + n * 16 + lr] = acc[n][r] * az[r];
      }
    }
  }
}

// ---------------- attention pass 2: full 64x64 tile grid; upper tiles write zeros ----------------
__global__ __launch_bounds__(256)
void k_attn2(const short* __restrict__ Qm, const short* __restrict__ Kx,
             const short* __restrict__ Gb, const float* __restrict__ zinv, float* __restrict__ aw) {
  int b = blockIdx.y;
  int t = blockIdx.x;
  int qb = t >> 5, kb = t & 31;
  int q0 = qb * 64, k0 = kb * 64;
  int tid = threadIdx.x;
  if (kb > qb) {   // strict upper tile: zero-fill
    int row = tid >> 2, c4 = (tid & 3) << 4;
    float* basep = aw + ((long)b * Ln + q0 + row) * Ln + k0 + c4;
    f32x4 z = {};
    *(f32x4*)(basep) = z; *(f32x4*)(basep + 4) = z;
    *(f32x4*)(basep + 8) = z; *(f32x4*)(basep + 12) = z;
    return;
  }
  int lane = tid & 63, w = tid >> 6;
  int lr = lane & 15, lg = lane >> 4;
  int q0w = q0 + w * 16;
  bool diag = (qb == kb);
  __shared__ short smK[2][64 * 64];
  __shared__ short smQ[2][64 * 64];
  __shared__ float smZ[NH * 64];
  for (int i = tid; i < NH * 64; i += 256) {
    int h = i >> 6, qq = i & 63;
    smZ[i] = zinv[((long)(b * NH + h)) * Ln + q0 + qq];
  }
  __syncthreads();
  float gv[4][4];
#pragma unroll
  for (int n = 0; n < 4; n++) {
    int k = k0 + n * 16 + lr;
#pragma unroll
    for (int r = 0; r < 4; r++)
      gv[n][r] = bf2f(Gb[((long)b * Ln + q0w + lg * 4 + r) * Ln + k]);
  }
  int r0 = w * 16 + (lane >> 3);
  int scol = ((lane & 7) ^ (lane >> 3)) * 8;
  int sw = (lr & 7) << 3;
  auto stage = [&](int buf, int h) {
    short* bK = &smK[buf][w * 1024];
    short* bQ = &smQ[buf][w * 1024];
    const short* Kg = Kx + ((long)(b * Ln) + k0 + r0) * Dn + h * 64 + scol;
    gl_lds16(Kg, bK);
    gl_lds16(Kg + 8 * Dn, bK + 512);
    const short* Qg = Qm + ((long)(b * Ln) + q0 + r0) * Dn + h * 64 + scol;
    gl_lds16(Qg, bQ);
    gl_lds16(Qg + 8 * Dn, bQ + 512);
  };
  float wa[4][4] = {{0.f}};
  stage(0, 0);
  int cur = 0;
  for (int h = 0; h < NH; ++h) {
    bool pre = (h + 1 < NH);
    if (pre) stage(cur ^ 1, h + 1);
    __builtin_amdgcn_sched_barrier(0);
    if (pre) asm volatile("s_waitcnt vmcnt(4)" ::: "memory");
    else     asm volatile("s_waitcnt vmcnt(0)" ::: "memory");
    __builtin_amdgcn_s_barrier();
    __builtin_amdgcn_sched_barrier(0);
    const short* Kc = smK[cur];
    const short* Qc = smQ[cur];
    s16x8 qf0 = *(const s16x8*)(Qc + (w * 16 + lr) * 64 + ((lg * 8) ^ sw));
    s16x8 qf1 = *(const s16x8*)(Qc + (w * 16 + lr) * 64 + ((32 + lg * 8) ^ sw));
    float zq[4];
#pragma unroll
    for (int r = 0; r < 4; r++) zq[r] = smZ[h * 64 + w * 16 + lg * 4 + r];
#pragma unroll
    for (int n = 0; n < 4; n++) {
      const short* kr = Kc + (n * 16 + lr) * 64;
      s16x8 kf0 = *(const s16x8*)(kr + ((lg * 8) ^ sw));
      s16x8 kf1 = *(const s16x8*)(kr + ((32 + lg * 8) ^ sw));
      f32x4 S = {};
      S = __builtin_amdgcn_mfma_f32_16x16x32_bf16(qf0, kf0, S, 0, 0, 0);
      S = __builtin_amdgcn_mfma_f32_16x16x32_bf16(qf1, kf1, S, 0, 0, 0);
#pragma unroll
      for (int r = 0; r < 4; r++)
        wa[n][r] += __expf(S[r] * 0.125f + gv[n][r]) * zq[r];
    }
    __builtin_amdgcn_s_barrier();
    cur ^= 1;
  }
#pragma unroll
  for (int n = 0; n < 4; n++) {
    int k = k0 + n * 16 + lr;
#pragma unroll
    for (int r = 0; r < 4; r++) {
      int q = q0w + lg * 4 + r;
      float v = wa[n][r] * (1.0f / 16.0f);
      if (diag && k > q) v = 0.0f;
      aw[((long)b * Ln + q) * Ln + k] = v;
    }
  }
}

extern "C" void kernel_launch(void* const* d_in, const int* in_sizes, int n_in,
                              void* d_out, int out_size, void* d_ws, size_t ws_size,
                              hipStream_t stream) {
  const float* z    = (const float*)d_in[0];
  const float* ps   = (const float*)d_in[1];
  const float* Wq   = (const float*)d_in[2];
  const float* bq   = (const float*)d_in[3];
  const float* Wk   = (const float*)d_in[4];
  const float* bk   = (const float*)d_in[5];
  const float* Wv   = (const float*)d_in[6];
  const float* bv   = (const float*)d_in[7];
  const float* Wc   = (const float*)d_in[8];
  const float* gamma= (const float*)d_in[9];
  const float* Wg1  = (const float*)d_in[10];
  const float* bg1  = (const float*)d_in[11];
  const float* Wg2  = (const float*)d_in[12];
  const float* bg2  = (const float*)d_in[13];

  char* w = (char*)d_ws;
  auto alloc = [&](long bytes) { void* p = (void*)w; w += (bytes + 255) & ~255L; return p; };
  short* zb   = (short*)alloc(BLD * 2);                   // dead after mega GEMM
  short* pb   = (short*)alloc(BLD * 2);                   // dead after mega GEMM
  short* Wcat = (short*)alloc((long)(4 * Dn + HGn) * Dn * 2);
  short* Qp   = (short*)alloc(BLD * 2);
  short* Kp   = (short*)alloc(BLD * 2);
  short* Vtb  = (short*)alloc(BLD * 2);                   // V transposed: [b][h][d][L]
  short* Gk   = (short*)alloc(BLD * 2);
  float* Hf   = (float*)alloc((long)Bn * Ln * HGn * 4);
  float* gate = (float*)alloc((long)Bn * Ln * 4);
  float* ctf  = (float*)alloc((long)Ln * 512 * 4);
  float* stf  = (float*)alloc((long)Ln * 512 * 4);
  float* cts  = (float*)alloc((long)Ln * 512 * 4);
  float* sts  = (float*)alloc((long)Ln * 512 * 4);
  float* zv   = (float*)alloc((long)Bn * NH * Ln * 4);
  short* Gb   = (short*)zb;   // 16.8MB bias slab aliases zb+pb (dead by then)

  float* outp = (float*)d_out;
  float* aw   = outp + BLD;

  // 1) fused casts (dst = zb|pb|Wcat contiguous)
  CastDesc cd;
  cd.src[0] = z;  cd.src[1] = ps; cd.src[2] = Wq; cd.src[3] = Wk;
  cd.src[4] = Wv; cd.src[5] = Wc; cd.src[6] = Wg1;
  long c0 = 0;
  cd.cum[0] = 0;
  cd.cum[1] = (c0 += BLD);
  cd.cum[2] = (c0 += BLD);
  cd.cum[3] = (c0 += (long)Dn * Dn);
  cd.cum[4] = (c0 += (long)Dn * Dn);
  cd.cum[5] = (c0 += (long)Dn * Dn);
  cd.cum[6] = (c0 += (long)Dn * Dn);
  cd.cum[7] = (c0 += (long)HGn * Dn);
  k_cast7<<<(int)(c0 / 1024), 256, 0, stream>>>(cd, zb);

  // 2) merged projections: Q,K,V(transposed),gk,h(GELU)
  k_gemm_mega<<<(4 * Dn + HGn) / 128 * ((Bn * Ln) / 128), 256, 0, stream>>>(
      zb, pb, Wcat, bq, bk, bv, bg1, Qp, Kp, Vtb, Gk, Hf);

  // 3) gb (bf16, causal tiles only) -> aliased slab
  k_gemm_gb<<<dim3(16 * 17 / 2, Bn), 256, 0, stream>>>(Gk, Kp, gamma, Gb);

  // 4) RoPE tables, gate, in-place rotation of Q/K (K raw already consumed by gb)
  k_rope_tables<<<(Ln * 512) / 256, 256, 0, stream>>>(ctf, stf, cts, sts);
  k_gate<<<(Bn * Ln) / 4, 256, 0, stream>>>(Hf, Wg2, bg2, gate);
  k_rope<<<Bn * Ln, 256, 0, stream>>>(Qp, Kp, gate, ctf, stf, cts, sts);

  // 5) attention
  k_attn1<<<512, 256, 0, stream>>>(Qp, Kp, Vtb, Gb, outp, zv);
  k_attn2<<<dim3(32 * 32, Bn), 256, 0, stream>>>(Qp, Kp, Gb, zv, aw);
}